// Round 6
// baseline (8576.830 us; speedup 1.0000x reference)
//
#include <hip/hip_runtime.h>
#include <hip/hip_bf16.h>
#include <cstdint>

#define T_LEN 512
#define BATCH 128
#define EMBD 256
#define NCLS 25
#define PADTOK 1

#define N_EMB (32000*256)
#define N_WPP (2*8*4*2*2*8*64*8)   /* 2,097,152 elems: [d][hs][w][v][nt][kt][l][e] */
#define N_WE (2*2*8*64*8)          /* 16384: [d][nt][kt][l][e] */
#define N_BIAS (2*1024)

// LDS: 4 waves * 32 KB weights + 16 KB W_e = 144 KB
#define LDS_BYTES (4*32768 + 16384)

typedef float f32x4 __attribute__((ext_vector_type(4)));
typedef short s16x8 __attribute__((ext_vector_type(8)));
typedef unsigned int u32x4 __attribute__((ext_vector_type(4)));
typedef unsigned long long u64x2 __attribute__((ext_vector_type(2)));

__device__ __forceinline__ unsigned short f2bf(float f) {
  unsigned int u = __builtin_bit_cast(unsigned int, f);
  unsigned int r = (u + 0x7FFFu + ((u >> 16) & 1u)) >> 16;
  return (unsigned short)r;
}
__device__ __forceinline__ void gll16(const void* g, void* l) {
  __builtin_amdgcn_global_load_lds(
      (const __attribute__((address_space(1))) unsigned int*)g,
      (__attribute__((address_space(3))) unsigned int*)l, 16, 0, 0);
}

// ---------------- prep: emb->bf16, weight permutes to frag order, bias sum --
__global__ void prep_kernel(const float* emb,
                            const float* wih_f, const float* whh_f,
                            const float* bih_f, const float* bhh_f,
                            const float* wih_b, const float* whh_b,
                            const float* bih_b, const float* bhh_b,
                            const float* W_e,
                            unsigned short* emb_bf, unsigned short* wpp,
                            unsigned short* wepp, float* bias)
{
  long total = (long)N_EMB + N_WPP + N_WE + N_BIAS;
  for (long i = (long)blockIdx.x*blockDim.x + threadIdx.x; i < total;
       i += (long)gridDim.x*blockDim.x) {
    long j = i;
    if (j < N_EMB) { emb_bf[j] = f2bf(emb[j]); continue; }
    j -= N_EMB;
    if (j < N_WPP) {
      int o = (int)j;
      int e = o&7, l = (o>>3)&63, kt = (o>>9)&7, nt = (o>>12)&1, v = (o>>13)&1;
      int w = (o>>14)&3, hs = (o>>16)&7, d = (o>>19)&1;
      int lm = l & 15, lg = l >> 4;
      int g = nt*2 + (lm>>3), jj = lm & 7;
      int n = g*256 + hs*32 + w*8 + jj;
      int k = kt*32 + lg*8 + e;
      const float* src = v ? (d ? whh_b : whh_f) : (d ? wih_b : wih_f);
      wpp[o] = f2bf(src[n*256 + k]);
      continue;
    }
    j -= N_WPP;
    if (j < N_WE) {
      int o = (int)j;
      int e = o&7, l = (o>>3)&63, kt = (o>>9)&7, nt = (o>>12)&1, d = (o>>13)&1;
      int lm = l & 15, lg = l >> 4;
      int cc = nt*16 + lm;
      int k = kt*32 + lg*8 + e;
      wepp[o] = (cc < NCLS) ? f2bf(W_e[cc*512 + d*256 + k]) : (unsigned short)0;
      continue;
    }
    j -= N_WE;
    { int o = (int)j; int d = o>>10; int g = o & 1023;
      bias[o] = d ? (bih_b[g]+bhh_b[g]) : (bih_f[g]+bhh_f[g]); }
  }
}

// ------- x frag images: xfrag[t][bg][mt*8+kt][l*16] = emb_bf[tok][k-slice] ---
__global__ __launch_bounds__(256) void xfrag_kernel(const int* sent,
    const unsigned short* emb_bf, unsigned short* xfrag)
{
  int b2 = blockIdx.x;           // 2048: t*4+bg
  int t = b2 >> 2, bg = b2 & 3;
  int w2 = threadIdx.x >> 6, l = threadIdx.x & 63, lg = l >> 4, lm = l & 15;
  char* dst = (char*)xfrag + ((long)b2 << 14);
  #pragma unroll
  for (int i = 0; i < 4; ++i) {
    int f = w2*4 + i, mt = f >> 3, kt = f & 7;
    int tok = sent[t*BATCH + bg*32 + mt*16 + lm];
    u32x4 v = *(const u32x4*)(emb_bf + (long)tok*256 + kt*32 + lg*8);
    *(u32x4*)(dst + (f<<10) + (l<<4)) = v;
  }
}

// ---------------- LSTM: one launch, 64 co-resident blocks -------------------
// block = (d, bg, hs): 32 batch rows x 32 hidden units (all 4 gates).
// Weights LDS-resident. h exchanged via device-scope atomics + flags.
__global__ __launch_bounds__(256, 1) void lstm_kernel(
    const unsigned short* wpp, const unsigned short* wepp, const float* bias,
    const unsigned short* xfrag, unsigned short* hx, unsigned int* flags,
    float* emis_f, float* emis_b)
{
  extern __shared__ char smem[];
  int id = blockIdx.x;
  int d = id >> 5, bg = (id >> 3) & 3, hs = id & 7;
  int w = threadIdx.x >> 6, l = threadIdx.x & 63, lg = l >> 4, lm = l & 15;
  char* wlds = smem + w*32768;          // [v][nt][kt] 1KB frags, own wave only
  char* welds = smem + 131072;          // [nt][kt] (hs==0 blocks)
  float* emis = d ? emis_b : emis_f;
  int fl_base = (d*4 + bg) * 32;

  // stage weights (per-wave region -> no barrier needed)
  const char* wsrc = (const char*)wpp + ((long)((d*8 + hs)*4 + w) << 15);
  #pragma unroll
  for (int f = 0; f < 32; ++f)
    gll16(wsrc + (f<<10) + (l<<4), wlds + (f<<10));
  if (hs == 0) {
    int nte = w >> 1;
    const char* wesrc = (const char*)wepp + (d<<14) + (nte<<13);
    #pragma unroll
    for (int f = 0; f < 8; ++f)
      gll16(wesrc + (f<<10) + (l<<4), welds + ((nte*8 + f)<<10));
  }
  int jg = hs*32 + w*8 + (lm & 7);
  float biasv[2];
  biasv[0] = bias[d*1024 + ((lm>>3))*256 + jg];
  biasv[1] = bias[d*1024 + (2 + (lm>>3))*256 + jg];
  asm volatile("s_waitcnt vmcnt(0)" ::: "memory");
  __builtin_amdgcn_sched_barrier(0);

  float c[2][4] = {};
  s16x8 hf[16];

  for (int ss = 0; ss < T_LEN; ++ss) {
    int t = d ? (T_LEN-1-ss) : ss;
    // acc = bias
    f32x4 acc[2][2];
    #pragma unroll
    for (int mt = 0; mt < 2; ++mt)
      #pragma unroll
      for (int nt = 0; nt < 2; ++nt)
        acc[mt][nt] = (f32x4){biasv[nt], biasv[nt], biasv[nt], biasv[nt]};

    // x-frag loads (plain; L2/L3)
    const char* xb = (const char*)xfrag + ((long)(t*4 + bg) << 14);
    s16x8 xf[16];
    #pragma unroll
    for (int f = 0; f < 16; ++f)
      xf[f] = *(const s16x8*)(xb + (f<<10) + (l<<4));

    // wait peers, coherent-load h_{ss-1} frag image
    if (ss > 0) {
      unsigned tgt = (unsigned)ss;
      for (;;) {
        unsigned fv = tgt;
        if (l < 32)
          fv = __hip_atomic_load(flags + fl_base + l, __ATOMIC_ACQUIRE, __HIP_MEMORY_SCOPE_AGENT);
        if (__all((int)(fv >= tgt))) break;
        __builtin_amdgcn_s_sleep(2);
      }
      const char* hb = (const char*)hx + ((long)((((ss-1)&3)*2 + d)*4 + bg) << 14);
      #pragma unroll
      for (int f = 0; f < 16; ++f) {
        unsigned long long lo = __hip_atomic_load(
            (const unsigned long long*)(hb + (f<<10) + (l<<4)), __ATOMIC_RELAXED, __HIP_MEMORY_SCOPE_AGENT);
        unsigned long long hi = __hip_atomic_load(
            (const unsigned long long*)(hb + (f<<10) + (l<<4) + 8), __ATOMIC_RELAXED, __HIP_MEMORY_SCOPE_AGENT);
        u64x2 tmp; tmp[0] = lo; tmp[1] = hi;
        hf[f] = __builtin_bit_cast(s16x8, tmp);
      }
    }

    // xg: A = x-frags, B = wih (LDS, v=0)
    #pragma unroll
    for (int nt = 0; nt < 2; ++nt)
      #pragma unroll
      for (int kt = 0; kt < 8; ++kt) {
        s16x8 B = *(const s16x8*)(wlds + ((nt*8 + kt)<<10) + (l<<4));
        acc[0][nt] = __builtin_amdgcn_mfma_f32_16x16x32_bf16(xf[kt],   B, acc[0][nt], 0,0,0);
        acc[1][nt] = __builtin_amdgcn_mfma_f32_16x16x32_bf16(xf[8+kt], B, acc[1][nt], 0,0,0);
      }

    if (ss > 0) {
      // recurrent: A = h-frags, B = whh (LDS, v=1)
      #pragma unroll
      for (int nt = 0; nt < 2; ++nt)
        #pragma unroll
        for (int kt = 0; kt < 8; ++kt) {
          s16x8 B = *(const s16x8*)(wlds + (((2 + nt)*8 + kt)<<10) + (l<<4));
          acc[0][nt] = __builtin_amdgcn_mfma_f32_16x16x32_bf16(hf[kt],   B, acc[0][nt], 0,0,0);
          acc[1][nt] = __builtin_amdgcn_mfma_f32_16x16x32_bf16(hf[8+kt], B, acc[1][nt], 0,0,0);
        }
      // emissions for h_{ss-1} (hs==0 blocks)
      if (hs == 0) {
        int mte = w & 1, nte = w >> 1;
        f32x4 ea = {0.f,0.f,0.f,0.f};
        #pragma unroll
        for (int kt = 0; kt < 8; ++kt) {
          s16x8 B = *(const s16x8*)(welds + ((nte*8 + kt)<<10) + (l<<4));
          ea = __builtin_amdgcn_mfma_f32_16x16x32_bf16(hf[mte*8 + kt], B, ea, 0,0,0);
        }
        int cc = nte*16 + lm;
        if (cc < NCLS) {
          int prev_t = d ? (T_LEN - ss) : (ss - 1);
          #pragma unroll
          for (int r = 0; r < 4; ++r)
            emis[((long)prev_t*BATCH + bg*32 + mte*16 + lg*4 + r)*NCLS + cc] = ea[r];
        }
      }
    }

    // nonlinearity: gates of hidden jj live in lanes lm / lm^8
    float hval[2][4];
    #pragma unroll
    for (int mt = 0; mt < 2; ++mt)
      #pragma unroll
      for (int r = 0; r < 4; ++r) {
        float own0 = acc[mt][0][r], own1 = acc[mt][1][r];
        float oth0 = __shfl_xor(own0, 8);
        float oth1 = __shfl_xor(own1, 8);
        bool lo = (lm & 8) == 0;
        float gi = lo ? own0 : oth0;
        float gf = lo ? oth0 : own0;
        float gg = lo ? own1 : oth1;
        float go = lo ? oth1 : own1;
        float si = 1.f/(1.f+__expf(-gi));
        float sf = 1.f/(1.f+__expf(-gf));
        float so = 1.f/(1.f+__expf(-go));
        float tg = 2.f/(1.f+__expf(-2.f*gg)) - 1.f;
        float cn = sf*c[mt][r] + si*tg;
        c[mt][r] = cn;
        float tc = 2.f/(1.f+__expf(-2.f*cn)) - 1.f;
        hval[mt][r] = so*tc;
      }

    // scatter h_new into frag image (device-scope) + release flag
    char* hdst = (char*)hx + ((long)(((ss&3)*2 + d)*4 + bg) << 14);
    #pragma unroll
    for (int mt = 0; mt < 2; ++mt)
      #pragma unroll
      for (int r = 0; r < 4; ++r) {
        float hn = __shfl_xor(hval[mt][r], 1);
        unsigned word = (unsigned)f2bf(hval[mt][r]) | ((unsigned)f2bf(hn) << 16);
        if ((lm & 9) == 0) {
          unsigned off = (unsigned)(((mt*8 + hs)<<10) + ((lg*4 + r) + 16*w)*16 + ((lm>>1)<<2));
          __hip_atomic_store((unsigned*)(hdst + off), word, __ATOMIC_RELAXED, __HIP_MEMORY_SCOPE_AGENT);
        }
      }
    if (l == 0)
      __hip_atomic_store(flags + fl_base + hs*4 + w, (unsigned)(ss + 1),
                         __ATOMIC_RELEASE, __HIP_MEMORY_SCOPE_AGENT);
  }

  // final emissions for h_{T-1}
  if (hs == 0) {
    unsigned tgt = (unsigned)T_LEN;
    for (;;) {
      unsigned fv = tgt;
      if (l < 32)
        fv = __hip_atomic_load(flags + fl_base + l, __ATOMIC_ACQUIRE, __HIP_MEMORY_SCOPE_AGENT);
      if (__all((int)(fv >= tgt))) break;
      __builtin_amdgcn_s_sleep(2);
    }
    const char* hb = (const char*)hx + ((long)((((T_LEN-1)&3)*2 + d)*4 + bg) << 14);
    int mte = w & 1, nte = w >> 1;
    #pragma unroll
    for (int kt = 0; kt < 8; ++kt) {
      int f = mte*8 + kt;
      unsigned long long lo = __hip_atomic_load(
          (const unsigned long long*)(hb + (f<<10) + (l<<4)), __ATOMIC_RELAXED, __HIP_MEMORY_SCOPE_AGENT);
      unsigned long long hi = __hip_atomic_load(
          (const unsigned long long*)(hb + (f<<10) + (l<<4) + 8), __ATOMIC_RELAXED, __HIP_MEMORY_SCOPE_AGENT);
      u64x2 tmp; tmp[0] = lo; tmp[1] = hi;
      hf[f] = __builtin_bit_cast(s16x8, tmp);
    }
    f32x4 ea = {0.f,0.f,0.f,0.f};
    #pragma unroll
    for (int kt = 0; kt < 8; ++kt) {
      s16x8 B = *(const s16x8*)(welds + ((nte*8 + kt)<<10) + (l<<4));
      ea = __builtin_amdgcn_mfma_f32_16x16x32_bf16(hf[mte*8 + kt], B, ea, 0,0,0);
    }
    int cc = nte*16 + lm;
    if (cc < NCLS) {
      int tf = d ? 0 : (T_LEN - 1);
      #pragma unroll
      for (int r = 0; r < 4; ++r)
        emis[((long)tf*BATCH + bg*32 + mte*16 + lg*4 + r)*NCLS + cc] = ea[r];
    }
  }
}

// ---------------- CRF numerator -------------------------------------------
__global__ void num_kernel(const int* sent, const int* tags, const float* emis_f,
    const float* emis_b, const float* b_e, const float* start_t, const float* end_t,
    const float* trans, float* num_buf)
{
  int b = blockIdx.x, l = threadIdx.x;   // 64 threads = 1 wave
  float acc = 0.f; int cnt = 0;
  for (int t = l; t < T_LEN; t += 64) {
    int tag = tags[t*BATCH + b];
    float E = emis_f[((long)t*BATCH+b)*NCLS + tag] + emis_b[((long)t*BATCH+b)*NCLS + tag] + b_e[tag];
    int m = (sent[t*BATCH+b] != PADTOK) ? 1 : 0;
    cnt += m;
    if (t == 0) acc += start_t[tag] + E;
    else if (m) acc += trans[tags[(t-1)*BATCH + b]*NCLS + tag] + E;
  }
  #pragma unroll
  for (int off = 32; off; off >>= 1) { acc += __shfl_xor(acc, off); cnt += __shfl_xor(cnt, off); }
  if (l == 0) num_buf[b] = acc + end_t[tags[(cnt-1)*BATCH + b]];
}

// ---------------- CRF forward algorithm (denominator) ----------------------
__global__ void denom_kernel(const int* sent, const float* emis_f, const float* emis_b,
    const float* b_e, const float* start_t, const float* end_t, const float* trans,
    const float* num_buf, float* llh)
{
  __shared__ float tr[NCLS][32];
  __shared__ float sc[2][32];
  __shared__ float be_s[32];
  int l = threadIdx.x, j = l & 31, h = l >> 5;
  int b = blockIdx.x*2 + h;
  for (int i = l; i < NCLS*32; i += 64) { int r = i >> 5, cj = i & 31; tr[r][cj] = (cj<NCLS)? trans[r*NCLS+cj] : 0.f; }
  if (l < 32) be_s[l] = (l < NCLS) ? b_e[l] : 0.f;
  __syncthreads();
  float score = -1e30f;
  if (j < NCLS) score = start_t[j] + emis_f[(long)b*NCLS+j] + emis_b[(long)b*NCLS+j] + be_s[j];
  for (int t = 1; t < T_LEN; ++t) {
    sc[h][j] = score;
    __syncthreads();
    bool m = sent[t*BATCH + b] != PADTOK;
    float mx = -1e30f;
    for (int i = 0; i < NCLS; ++i) mx = fmaxf(mx, sc[h][i] + tr[i][j]);
    float ssum = 0.f;
    for (int i = 0; i < NCLS; ++i) ssum += __expf(sc[h][i] + tr[i][j] - mx);
    float e = (j < NCLS) ? (emis_f[((long)t*BATCH+b)*NCLS+j] + emis_b[((long)t*BATCH+b)*NCLS+j] + be_s[j]) : 0.f;
    float nxt = mx + __logf(ssum) + e;
    if (m && j < NCLS) score = nxt;
    __syncthreads();
  }
  float v = (j < NCLS) ? score + end_t[j] : -1e30f;
  float mx = v;
  #pragma unroll
  for (int off = 16; off; off >>= 1) mx = fmaxf(mx, __shfl_xor(mx, off));
  float ssum = (j < NCLS) ? __expf(v - mx) : 0.f;
  #pragma unroll
  for (int off = 16; off; off >>= 1) ssum += __shfl_xor(ssum, off);
  if (j == 0) llh[b] = num_buf[b] - (mx + __logf(ssum));
}

__global__ void final_kernel(const float* llh, float* out) {
  __shared__ float red[2];
  int l = threadIdx.x;   // 128
  float v = llh[l];
  #pragma unroll
  for (int off = 32; off; off >>= 1) v += __shfl_xor(v, off);
  if ((l & 63) == 0) red[l >> 6] = v;
  __syncthreads();
  if (l == 0) out[0] = -(red[0] + red[1]);
}

extern "C" void kernel_launch(void* const* d_in, const int* in_sizes, int n_in,
                              void* d_out, int out_size, void* d_ws, size_t ws_size,
                              hipStream_t stream) {
  const int*   sent  = (const int*)d_in[0];
  const int*   tags  = (const int*)d_in[1];
  const float* emb   = (const float*)d_in[2];
  const float* wih_f = (const float*)d_in[3];
  const float* whh_f = (const float*)d_in[4];
  const float* bih_f = (const float*)d_in[5];
  const float* bhh_f = (const float*)d_in[6];
  const float* wih_b = (const float*)d_in[7];
  const float* whh_b = (const float*)d_in[8];
  const float* bih_b = (const float*)d_in[9];
  const float* bhh_b = (const float*)d_in[10];
  const float* W_e   = (const float*)d_in[11];
  const float* b_e   = (const float*)d_in[12];
  const float* st    = (const float*)d_in[13];
  const float* et    = (const float*)d_in[14];
  const float* tr    = (const float*)d_in[15];
  (void)in_sizes; (void)n_in; (void)out_size; (void)ws_size;

  char* ws = (char*)d_ws;
  unsigned short* emb_bf = (unsigned short*)ws; ws += (long)N_EMB*2;        // 16.4 MB
  unsigned short* wpp    = (unsigned short*)ws; ws += (long)N_WPP*2;        // 4 MB
  unsigned short* wepp   = (unsigned short*)ws; ws += (long)N_WE*2;         // 32 KB
  float*          bias   = (float*)ws;          ws += (long)N_BIAS*4;       // 8 KB
  unsigned short* xfrag  = (unsigned short*)ws; ws += (long)2048*16384;     // 32 MB (bytes)
  unsigned short* hx     = (unsigned short*)ws; ws += (long)512*1024;       // 512 KB (bytes)
  unsigned int*   flags  = (unsigned int*)ws;   ws += 1024;
  float*          emis_f = (float*)ws;          ws += (long)T_LEN*BATCH*NCLS*4;
  float*          emis_b = (float*)ws;          ws += (long)T_LEN*BATCH*NCLS*4;
  float*          numb   = (float*)ws;          ws += 512;
  float*          llh    = (float*)ws;          ws += 512;
  // total ~67 MB

  hipFuncSetAttribute(reinterpret_cast<const void*>(lstm_kernel),
                      hipFuncAttributeMaxDynamicSharedMemorySize, LDS_BYTES);

  prep_kernel<<<8192, 256, 0, stream>>>(emb, wih_f, whh_f, bih_f, bhh_f,
                                        wih_b, whh_b, bih_b, bhh_b, W_e,
                                        emb_bf, wpp, wepp, bias);
  xfrag_kernel<<<2048, 256, 0, stream>>>(sent, emb_bf, xfrag);
  hipMemsetAsync(flags, 0, 256*sizeof(unsigned int), stream);
  lstm_kernel<<<64, 256, LDS_BYTES, stream>>>(wpp, wepp, bias, xfrag, hx, flags,
                                              emis_f, emis_b);
  num_kernel<<<128, 64, 0, stream>>>(sent, tags, emis_f, emis_b, b_e, st, et, tr, numb);
  denom_kernel<<<64, 64, 0, stream>>>(sent, emis_f, emis_b, b_e, st, et, tr, numb, llh);
  final_kernel<<<1, 128, 0, stream>>>(llh, (float*)d_out);
}

// Round 7
// 4451.897 us; speedup vs baseline: 1.9266x; 1.9266x over previous
//
#include <hip/hip_runtime.h>
#include <hip/hip_bf16.h>
#include <cstdint>

#define T_LEN 512
#define BATCH 128
#define EMBD 256
#define NCLS 25
#define PADTOK 1
#define CHUNK 64
#define NCHUNK 8

#define N_WPERM (2*4*16*8*64*8)   /* 524288 elements each for wih/whh */
#define N_WE (2*2*8*64*8)         /* 16384 */
#define N_BIAS (2*1024)

// LDS: 8 KB h + 8 waves * (2 ring slots * 4 KB + 4 KB xg slot) = 104 KB
#define LDS_BYTES (8192 + 8*12288)

typedef float f32x4 __attribute__((ext_vector_type(4)));
typedef short s16x8 __attribute__((ext_vector_type(8)));
typedef unsigned int u32x4 __attribute__((ext_vector_type(4)));

__device__ __forceinline__ unsigned short f2bf(float f) {
  unsigned int u = __builtin_bit_cast(unsigned int, f);
  unsigned int r = (u + 0x7FFFu + ((u >> 16) & 1u)) >> 16;
  return (unsigned short)r;
}
__device__ __forceinline__ float bf2f(unsigned short h) {
  unsigned int u = ((unsigned int)h) << 16;
  return __builtin_bit_cast(float, u);
}
// async global->LDS, 16 B per lane; LDS dest is wave-uniform base (+lane*16 by HW)
__device__ __forceinline__ void gll16(const void* g, void* l) {
  __builtin_amdgcn_global_load_lds(
      (const __attribute__((address_space(1))) unsigned int*)g,
      (__attribute__((address_space(3))) unsigned int*)l, 16, 0, 0);
}

// ---------------- prep: fragment-order weight permutes + bias sum ----------
// wih layout (for xg_kernel, 4-wave): o = ((((d*4+w)*8+kt)*16+s)*64+l)*8+e
// whh layout (for lstm, 8-wave):      o = ((((d*8+w)*8+kt)*8+s)*64+l)*8+e
__global__ void prep_kernel(const float* wih_f, const float* whh_f,
                            const float* bih_f, const float* bhh_f,
                            const float* wih_b, const float* whh_b,
                            const float* bih_b, const float* bhh_b,
                            const float* W_e,
                            unsigned short* wih_p, unsigned short* whh_p,
                            unsigned short* we_p, float* bias)
{
  long total = 2L*N_WPERM + N_WE + N_BIAS;
  for (long i = (long)blockIdx.x*blockDim.x + threadIdx.x; i < total;
       i += (long)gridDim.x*blockDim.x) {
    long j = i;
    if (j < N_WPERM) {           // wih, 4-wave layout
      int o = (int)j;
      int e = o & 7, l = (o>>3)&63, s = (o>>9)&15, kt = (o>>13)&7, w = (o>>16)&3, d = (o>>18)&1;
      int n = (s>>2)*256 + w*64 + (s&3)*16 + (l & 15);
      int kk = kt*32 + (l>>4)*8 + e;
      const float* src = d ? wih_b : wih_f;
      wih_p[o] = f2bf(src[n*256 + kk]);
      continue;
    }
    j -= N_WPERM;
    if (j < N_WPERM) {           // whh, 8-wave layout
      int o = (int)j;
      int e = o & 7, l = (o>>3)&63, s = (o>>9)&7, kt = (o>>12)&7, w = (o>>15)&7, d = (o>>18)&1;
      int n = (s>>1)*256 + w*32 + (s&1)*16 + (l & 15);
      int kk = kt*32 + (l>>4)*8 + e;
      const float* src = d ? whh_b : whh_f;
      whh_p[o] = f2bf(src[n*256 + kk]);
      continue;
    }
    j -= N_WPERM;
    if (j < N_WE) {
      int o = (int)j;
      int e = o&7, l = (o>>3)&63, kt = (o>>9)&7, nt = (o>>12)&1, dp = (o>>13)&1;
      int n = nt*16 + (l&15);
      int kk = dp*256 + kt*32 + (l>>4)*8 + e;
      we_p[o] = (n < NCLS) ? f2bf(W_e[n*512 + kk]) : (unsigned short)0;
      continue;
    }
    j -= N_WE;
    { int o = (int)j; int d = o>>10; int g = o & 1023;
      bias[o] = d ? (bih_b[g]+bhh_b[g]) : (bih_f[g]+bhh_f[g]); }
  }
}

// ------- xg chunk: emb[sent] @ W_ih^T + biases, stored permuted bf16 -------
__global__ __launch_bounds__(256) void xg_kernel(const int* sent, const float* emb,
    const unsigned short* wih_p, const float* bias, unsigned short* xg, int k)
{
  int d = blockIdx.y;
  int blk = blockIdx.x;            // 0..255
  int u = blk >> 2, q = blk & 3;   // u = local step, batch rows 32q..32q+31
  int ss = k*CHUNK + u;
  int t = d ? (T_LEN-1-ss) : ss;
  int w = threadIdx.x >> 6, l = threadIdx.x & 63, lg = l >> 4, lm = l & 15;

  int tok0 = sent[t*BATCH + q*32 + lm];
  int tok1 = sent[t*BATCH + q*32 + 16 + lm];

  const char* wbase = (const char*)wih_p + ((long)(d*4 + w) << 17);

  f32x4 acc[2][16] = {};
  for (int kt = 0; kt < 8; ++kt) {
    const float* p0 = emb + (long)tok0*256 + kt*32 + lg*8;
    const float* p1 = emb + (long)tok1*256 + kt*32 + lg*8;
    f32x4 q00 = *(const f32x4*)p0, q01 = *(const f32x4*)(p0+4);
    f32x4 q10 = *(const f32x4*)p1, q11 = *(const f32x4*)(p1+4);
    s16x8 a0, a1;
    #pragma unroll
    for (int e = 0; e < 4; ++e) {
      a0[e]   = (short)f2bf(q00[e]); a0[4+e] = (short)f2bf(q01[e]);
      a1[e]   = (short)f2bf(q10[e]); a1[4+e] = (short)f2bf(q11[e]);
    }
    #pragma unroll
    for (int s = 0; s < 16; ++s) {
      s16x8 bf = *(const s16x8*)(wbase + (((kt*16 + s) << 10) + (l << 4)));
      acc[0][s] = __builtin_amdgcn_mfma_f32_16x16x32_bf16(a0, bf, acc[0][s], 0,0,0);
      acc[1][s] = __builtin_amdgcn_mfma_f32_16x16x32_bf16(a1, bf, acc[1][s], 0,0,0);
    }
  }
  float bsv[16];
  #pragma unroll
  for (int s = 0; s < 16; ++s) {
    int n = (s>>2)*256 + w*64 + (s&3)*16 + lm;
    bsv[s] = bias[d*1024 + n];
  }
  #pragma unroll
  for (int mt = 0; mt < 2; ++mt) {
    int nb = q*2 + mt;
    char* base = (char*)xg + (((((long)d*CHUNK + u)*8 + nb)*4 + w)*64 + l)*128;
    #pragma unroll
    for (int qq = 0; qq < 8; ++qq) {
      u32x4 pk;
      #pragma unroll
      for (int h2 = 0; h2 < 4; ++h2) {
        int j0 = qq*8 + h2*2;
        unsigned short v0 = f2bf(acc[mt][j0>>2][j0&3] + bsv[j0>>2]);
        unsigned short v1 = f2bf(acc[mt][(j0+1)>>2][(j0+1)&3] + bsv[(j0+1)>>2]);
        pk[h2] = (unsigned)v0 | ((unsigned)v1 << 16);
      }
      *(u32x4*)(base + qq*16) = pk;
    }
  }
}

// ---------------- LSTM chunk: free-running weight ring ---------------------
// 8 waves; wave owns 32 hidden units (all 4 gates = 8 s-tiles). Weight stream
// is periodic -> ring never drains: raw barriers + counted vmcnt only.
__global__ __launch_bounds__(512, 1) void lstm_kernel(const unsigned short* xg,
    const unsigned short* whh_p, const unsigned short* we_p,
    float* emis_f, float* emis_b, unsigned short* hsave, float* csave, int k)
{
  extern __shared__ char smem[];
  unsigned short* h_lds = (unsigned short*)smem;          // 8 KB, XOR-swizzled
  char* wring = smem + 8192 + (threadIdx.x >> 6)*12288;   // 2 x 4 KB ring slots
  char* xslot = wring + 8192;                             // 4 KB xg slot

  int id = blockIdx.x, d = id >> 3, nb = id & 7, bbase = nb*16;
  int w = threadIdx.x >> 6, l = threadIdx.x & 63, lg = l >> 4, lm = l & 15;
  float* emis = d ? emis_b : emis_f;
  const char* wbase = (const char*)whh_p + ((long)(d*8 + w) << 16);

  // emissions weights hoisted; waves 0,1 own nt = w
  s16x8 ewreg[8];
  if (w < 2) {
    #pragma unroll
    for (int kt = 0; kt < 8; ++kt)
      ewreg[kt] = *(const s16x8*)((const char*)we_p + ((((long)d*2 + w)*8 + kt)*64 + l)*16);
  }

  float c[8];
  if (k == 0) {
    for (int i = threadIdx.x; i < 2048; i += 512) ((unsigned*)h_lds)[i] = 0u;
    #pragma unroll
    for (int i = 0; i < 8; ++i) c[i] = 0.f;
  } else {
    u32x4* hl = (u32x4*)h_lds;
    const u32x4* hs = (const u32x4*)(hsave + (long)id*4096);
    if (threadIdx.x < 512) hl[threadIdx.x] = hs[threadIdx.x];
    const float* cs = csave + ((long)id*512 + threadIdx.x)*8;
    #pragma unroll
    for (int i = 0; i < 8; ++i) c[i] = cs[i];
  }
  asm volatile("s_waitcnt vmcnt(0)" ::: "memory");  // resolve ewreg/restore pre-loop
  __syncthreads();

  // batch b (0..15): 4 KB = frags kt=b>>1, s=(b&1)*4..+4, into slot b&1
  #define ISSUE_BATCH(b) { \
    const char* gsrc = wbase + ((b) << 12); \
    char* ldst = wring + (((b) & 1) << 12); \
    _Pragma("unroll") \
    for (int s2 = 0; s2 < 4; ++s2) \
      gll16(gsrc + (s2 << 10) + (l << 4), ldst + (s2 << 10)); }

  ISSUE_BATCH(0) ISSUE_BATCH(1)   // prologue: 8 outstanding

  int prev_t = (k == 0) ? -1 : (d ? (T_LEN - k*CHUNK) : (k*CHUNK - 1));

  for (int u = 0; u < CHUNK; ++u) {
    int ss = k*CHUNK + u;
    int t = d ? (T_LEN-1-ss) : ss;
    // barrier 1: prev step's h writes visible (lgkm only; ring stays in flight)
    asm volatile("s_waitcnt lgkmcnt(0)" ::: "memory");
    __builtin_amdgcn_s_barrier();
    // A-frags of h_{t-1}
    s16x8 a[8];
    #pragma unroll
    for (int kt = 0; kt < 8; ++kt) {
      int off = lm*512 + ((kt*64 + lg*16) ^ ((lm&7)<<4));
      a[kt] = *(const s16x8*)((const char*)h_lds + off);
    }
    asm volatile("s_waitcnt lgkmcnt(0)" ::: "memory");
    __builtin_amdgcn_s_barrier();   // barrier 2: h_lds free for this step's writes

    // stage xg (4 KB/wave) into the FIFO right behind B0,B1
    const char* xb = (const char*)xg
        + (((((long)d*CHUNK + u)*8 + nb)*4 + (w>>1))*64 + l)*128 + ((w&1)*16);
    #pragma unroll
    for (int i = 0; i < 4; ++i)
      gll16(xb + i*32, xslot + (i<<10));

    // waves 0,1: emissions for previous h (reg-only MFMA; stores only over-wait)
    if (w < 2 && prev_t >= 0) {
      f32x4 ea = {0.f,0.f,0.f,0.f};
      #pragma unroll
      for (int kt = 0; kt < 8; ++kt)
        ea = __builtin_amdgcn_mfma_f32_16x16x32_bf16(a[kt], ewreg[kt], ea, 0,0,0);
      int cc = w*16 + lm;
      if (cc < NCLS) {
        #pragma unroll
        for (int r = 0; r < 4; ++r)
          emis[((long)prev_t*BATCH + bbase + lg*4 + r)*NCLS + cc] = ea[r];
      }
    }

    // consume 16 batches; counted FIFO waits (never drain to 0)
    f32x4 acc[8];
    #pragma unroll
    for (int s = 0; s < 8; ++s) acc[s] = (f32x4){0.f,0.f,0.f,0.f};
    #pragma unroll
    for (int j = 0; j < 16; ++j) {
      if (j < 2) asm volatile("s_waitcnt vmcnt(8)" ::: "memory");
      else       asm volatile("s_waitcnt vmcnt(4)" ::: "memory");
      __builtin_amdgcn_sched_barrier(0);
      const char* slot = wring + ((j & 1) << 12);
      #pragma unroll
      for (int s2 = 0; s2 < 4; ++s2) {
        s16x8 wf = *(const s16x8*)(slot + (s2 << 10) + (l << 4));
        acc[(j&1)*4 + s2] =
            __builtin_amdgcn_mfma_f32_16x16x32_bf16(a[j>>1], wf, acc[(j&1)*4 + s2], 0,0,0);
      }
      __builtin_amdgcn_sched_barrier(0);
      ISSUE_BATCH((j+2)&15)
      __builtin_amdgcn_sched_barrier(0);
    }

    // xg add (xg retired at j=2's wait; reads via LDS)
    u32x4 xv[4];
    #pragma unroll
    for (int i = 0; i < 4; ++i)
      xv[i] = *(const u32x4*)(xslot + (i<<10) + (l<<4));
    #pragma unroll
    for (int s = 0; s < 8; ++s)
      #pragma unroll
      for (int r = 0; r < 4; ++r) {
        unsigned wd = xv[s>>1][(s&1)*2 + (r>>1)];
        unsigned short us = (r&1) ? (unsigned short)(wd>>16) : (unsigned short)(wd & 0xffff);
        acc[s][r] += bf2f(us);
      }

    // nonlinearities: i,f,g,o at s = q, 2+q, 4+q, 6+q; h write swizzled
    #pragma unroll
    for (int q = 0; q < 2; ++q)
      #pragma unroll
      for (int r = 0; r < 4; ++r) {
        float gi = acc[q][r],   gf = acc[2+q][r];
        float gg = acc[4+q][r], go = acc[6+q][r];
        float si = 1.f/(1.f+__expf(-gi));
        float sf = 1.f/(1.f+__expf(-gf));
        float so = 1.f/(1.f+__expf(-go));
        float tg = 2.f/(1.f+__expf(-2.f*gg)) - 1.f;
        float cn = sf*c[q*4+r] + si*tg;
        c[q*4+r] = cn;
        float tc = 2.f/(1.f+__expf(-2.f*cn)) - 1.f;
        int m = lg*4 + r;
        int jj = w*32 + q*16 + lm;
        int off = (m*512 + jj*2) ^ ((m&7)<<4);
        *(unsigned short*)((char*)h_lds + off) = f2bf(so*tc);
      }
    prev_t = t;
  }

  asm volatile("s_waitcnt lgkmcnt(0)" ::: "memory");
  __builtin_amdgcn_s_barrier();

  if (k == NCHUNK-1) {
    if (w < 2) {
      s16x8 a[8];
      #pragma unroll
      for (int kt = 0; kt < 8; ++kt) {
        int off = lm*512 + ((kt*64 + lg*16) ^ ((lm&7)<<4));
        a[kt] = *(const s16x8*)((const char*)h_lds + off);
      }
      f32x4 ea = {0.f,0.f,0.f,0.f};
      #pragma unroll
      for (int kt = 0; kt < 8; ++kt)
        ea = __builtin_amdgcn_mfma_f32_16x16x32_bf16(a[kt], ewreg[kt], ea, 0,0,0);
      int cc = w*16 + lm;
      if (cc < NCLS) {
        #pragma unroll
        for (int r = 0; r < 4; ++r)
          emis[((long)prev_t*BATCH + bbase + lg*4 + r)*NCLS + cc] = ea[r];
      }
    }
  } else {
    u32x4* hl = (u32x4*)h_lds;
    u32x4* hs = (u32x4*)(hsave + (long)id*4096);
    if (threadIdx.x < 512) hs[threadIdx.x] = hl[threadIdx.x];
    float* cs = csave + ((long)id*512 + threadIdx.x)*8;
    #pragma unroll
    for (int i = 0; i < 8; ++i) cs[i] = c[i];
  }
  #undef ISSUE_BATCH
}

// ---------------- CRF numerator -------------------------------------------
__global__ void num_kernel(const int* sent, const int* tags, const float* emis_f,
    const float* emis_b, const float* b_e, const float* start_t, const float* end_t,
    const float* trans, float* num_buf)
{
  int b = blockIdx.x, l = threadIdx.x;   // 64 threads = 1 wave
  float acc = 0.f; int cnt = 0;
  for (int t = l; t < T_LEN; t += 64) {
    int tag = tags[t*BATCH + b];
    float E = emis_f[((long)t*BATCH+b)*NCLS + tag] + emis_b[((long)t*BATCH+b)*NCLS + tag] + b_e[tag];
    int m = (sent[t*BATCH+b] != PADTOK) ? 1 : 0;
    cnt += m;
    if (t == 0) acc += start_t[tag] + E;
    else if (m) acc += trans[tags[(t-1)*BATCH + b]*NCLS + tag] + E;
  }
  #pragma unroll
  for (int off = 32; off; off >>= 1) { acc += __shfl_xor(acc, off); cnt += __shfl_xor(cnt, off); }
  if (l == 0) num_buf[b] = acc + end_t[tags[(cnt-1)*BATCH + b]];
}

// ---------------- CRF forward algorithm (denominator) ----------------------
__global__ void denom_kernel(const int* sent, const float* emis_f, const float* emis_b,
    const float* b_e, const float* start_t, const float* end_t, const float* trans,
    const float* num_buf, float* llh)
{
  __shared__ float tr[NCLS][32];
  __shared__ float sc[2][32];
  __shared__ float be_s[32];
  int l = threadIdx.x, j = l & 31, h = l >> 5;
  int b = blockIdx.x*2 + h;
  for (int i = l; i < NCLS*32; i += 64) { int r = i >> 5, cj = i & 31; tr[r][cj] = (cj<NCLS)? trans[r*NCLS+cj] : 0.f; }
  if (l < 32) be_s[l] = (l < NCLS) ? b_e[l] : 0.f;
  __syncthreads();
  float score = -1e30f;
  if (j < NCLS) score = start_t[j] + emis_f[(long)b*NCLS+j] + emis_b[(long)b*NCLS+j] + be_s[j];
  for (int t = 1; t < T_LEN; ++t) {
    sc[h][j] = score;
    __syncthreads();
    bool m = sent[t*BATCH + b] != PADTOK;
    float mx = -1e30f;
    for (int i = 0; i < NCLS; ++i) mx = fmaxf(mx, sc[h][i] + tr[i][j]);
    float ssum = 0.f;
    for (int i = 0; i < NCLS; ++i) ssum += __expf(sc[h][i] + tr[i][j] - mx);
    float e = (j < NCLS) ? (emis_f[((long)t*BATCH+b)*NCLS+j] + emis_b[((long)t*BATCH+b)*NCLS+j] + be_s[j]) : 0.f;
    float nxt = mx + __logf(ssum) + e;
    if (m && j < NCLS) score = nxt;
    __syncthreads();
  }
  float v = (j < NCLS) ? score + end_t[j] : -1e30f;
  float mx = v;
  #pragma unroll
  for (int off = 16; off; off >>= 1) mx = fmaxf(mx, __shfl_xor(mx, off));
  float ssum = (j < NCLS) ? __expf(v - mx) : 0.f;
  #pragma unroll
  for (int off = 16; off; off >>= 1) ssum += __shfl_xor(ssum, off);
  if (j == 0) llh[b] = num_buf[b] - (mx + __logf(ssum));
}

__global__ void final_kernel(const float* llh, float* out) {
  __shared__ float red[2];
  int l = threadIdx.x;   // 128
  float v = llh[l];
  #pragma unroll
  for (int off = 32; off; off >>= 1) v += __shfl_xor(v, off);
  if ((l & 63) == 0) red[l >> 6] = v;
  __syncthreads();
  if (l == 0) out[0] = -(red[0] + red[1]);
}

extern "C" void kernel_launch(void* const* d_in, const int* in_sizes, int n_in,
                              void* d_out, int out_size, void* d_ws, size_t ws_size,
                              hipStream_t stream) {
  const int*   sent  = (const int*)d_in[0];
  const int*   tags  = (const int*)d_in[1];
  const float* emb   = (const float*)d_in[2];
  const float* wih_f = (const float*)d_in[3];
  const float* whh_f = (const float*)d_in[4];
  const float* bih_f = (const float*)d_in[5];
  const float* bhh_f = (const float*)d_in[6];
  const float* wih_b = (const float*)d_in[7];
  const float* whh_b = (const float*)d_in[8];
  const float* bih_b = (const float*)d_in[9];
  const float* bhh_b = (const float*)d_in[10];
  const float* W_e   = (const float*)d_in[11];
  const float* b_e   = (const float*)d_in[12];
  const float* st    = (const float*)d_in[13];
  const float* et    = (const float*)d_in[14];
  const float* tr    = (const float*)d_in[15];
  (void)in_sizes; (void)n_in; (void)out_size; (void)ws_size;

  char* ws = (char*)d_ws;
  unsigned short* wih_p  = (unsigned short*)ws; ws += (long)N_WPERM*2;      // 1 MiB
  unsigned short* whh_p  = (unsigned short*)ws; ws += (long)N_WPERM*2;      // 1 MiB
  unsigned short* we_p   = (unsigned short*)ws; ws += (long)N_WE*2;         // 32 KiB
  float*          bias   = (float*)ws;          ws += (long)N_BIAS*4;       // 8 KiB
  unsigned short* xgr    = (unsigned short*)ws; ws += (long)2*CHUNK*BATCH*1024*2; // 32 MiB ring
  float*          emis_f = (float*)ws;          ws += (long)T_LEN*BATCH*NCLS*4;   // 6.25 MiB
  float*          emis_b = (float*)ws;          ws += (long)T_LEN*BATCH*NCLS*4;   // 6.25 MiB
  unsigned short* hsave  = (unsigned short*)ws; ws += (long)16*4096*2;      // 128 KiB
  float*          csave  = (float*)ws;          ws += (long)16*512*8*4;     // 256 KiB
  float*          numb   = (float*)ws;          ws += 512;
  float*          llh    = (float*)ws;          ws += 512;
  // total ~47 MiB

  hipFuncSetAttribute(reinterpret_cast<const void*>(lstm_kernel),
                      hipFuncAttributeMaxDynamicSharedMemorySize, LDS_BYTES);

  prep_kernel<<<4168, 256, 0, stream>>>(wih_f, whh_f, bih_f, bhh_f,
                                        wih_b, whh_b, bih_b, bhh_b, W_e,
                                        wih_p, whh_p, we_p, bias);
  for (int k = 0; k < NCHUNK; ++k) {
    dim3 g1(256, 2);
    xg_kernel<<<g1, 256, 0, stream>>>(sent, emb, wih_p, bias, xgr, k);
    lstm_kernel<<<16, 512, LDS_BYTES, stream>>>(xgr, whh_p, we_p, emis_f, emis_b, hsave, csave, k);
  }
  num_kernel<<<128, 64, 0, stream>>>(sent, tags, emis_f, emis_b, b_e, st, et, tr, numb);
  denom_kernel<<<64, 64, 0, stream>>>(sent, emis_f, emis_b, b_e, st, et, tr, numb, llh);
  final_kernel<<<1, 128, 0, stream>>>(llh, (float*)d_out);
}

// Round 8
// 3517.366 us; speedup vs baseline: 2.4384x; 1.2657x over previous
//
#include <hip/hip_runtime.h>
#include <hip/hip_bf16.h>
#include <cstdint>

#define T_LEN 512
#define BATCH 128
#define EMBD 256
#define NCLS 25
#define PADTOK 1
#define CHUNK 64
#define NCHUNK 8

#define N_WPERM (2*4*16*8*64*8)   /* 524288: wih bf16 elems / whh fp8 bytes */
#define N_WE (2*2*8*64*8)         /* 16384 fp8 bytes */
#define N_BIAS (2*1024)

// LDS: 4 KB h(fp8) + 8 waves * (4 ring slots * 2 KB + 4 KB xg) = 100 KB
#define LDS_BYTES (4096 + 8*12288)

typedef float f32x4 __attribute__((ext_vector_type(4)));
typedef short s16x8 __attribute__((ext_vector_type(8)));
typedef unsigned int u32x4 __attribute__((ext_vector_type(4)));

#define INV1024 (0.0009765625f)

__device__ __forceinline__ unsigned short f2bf(float f) {
  unsigned int u = __builtin_bit_cast(unsigned int, f);
  unsigned int r = (u + 0x7FFFu + ((u >> 16) & 1u)) >> 16;
  return (unsigned short)r;
}
__device__ __forceinline__ float bf2f(unsigned short h) {
  unsigned int u = ((unsigned int)h) << 16;
  return __builtin_bit_cast(float, u);
}
__device__ __forceinline__ unsigned char f2fp8(float v) {
  int pk = __builtin_amdgcn_cvt_pk_fp8_f32(v, v, 0, false);
  return (unsigned char)(pk & 0xFF);
}
// async global->LDS, 16 B per lane; LDS dest is wave-uniform base (+lane*16 by HW)
__device__ __forceinline__ void gll16(const void* g, void* l) {
  __builtin_amdgcn_global_load_lds(
      (const __attribute__((address_space(1))) unsigned int*)g,
      (__attribute__((address_space(3))) unsigned int*)l, 16, 0, 0);
}

// ---------------- prep: fragment-order weight permutes + bias sum ----------
// wih (bf16, xg_kernel 4-wave): o = ((((d*4+w)*8+kt)*16+s)*64+l)*8+e
// whh (fp8 x64, lstm 8-wave):   o = ((((d*8+w)*8+kt)*8+s)*64+l)*8+e
// we  (fp8 x64):                o = (((dp*2+nt)*8+kt)*64+l)*8+e
__global__ void prep_kernel(const float* wih_f, const float* whh_f,
                            const float* bih_f, const float* bhh_f,
                            const float* wih_b, const float* whh_b,
                            const float* bih_b, const float* bhh_b,
                            const float* W_e,
                            unsigned short* wih_p, unsigned char* whh_p,
                            unsigned char* we_p, float* bias)
{
  long total = 2L*N_WPERM + N_WE + N_BIAS;
  for (long i = (long)blockIdx.x*blockDim.x + threadIdx.x; i < total;
       i += (long)gridDim.x*blockDim.x) {
    long j = i;
    if (j < N_WPERM) {           // wih, bf16, 4-wave layout
      int o = (int)j;
      int e = o & 7, l = (o>>3)&63, s = (o>>9)&15, kt = (o>>13)&7, w = (o>>16)&3, d = (o>>18)&1;
      int n = (s>>2)*256 + w*64 + (s&3)*16 + (l & 15);
      int kk = kt*32 + (l>>4)*8 + e;
      const float* src = d ? wih_b : wih_f;
      wih_p[o] = f2bf(src[n*256 + kk]);
      continue;
    }
    j -= N_WPERM;
    if (j < N_WPERM) {           // whh, fp8 scale 64, 8-wave layout
      int o = (int)j;
      int e = o & 7, l = (o>>3)&63, s = (o>>9)&7, kt = (o>>12)&7, w = (o>>15)&7, d = (o>>18)&1;
      int n = (s>>1)*256 + w*32 + (s&1)*16 + (l & 15);
      int kk = kt*32 + (l>>4)*8 + e;
      const float* src = d ? whh_b : whh_f;
      whh_p[o] = f2fp8(src[n*256 + kk] * 64.f);
      continue;
    }
    j -= N_WPERM;
    if (j < N_WE) {              // W_e, fp8 scale 64
      int o = (int)j;
      int e = o&7, l = (o>>3)&63, kt = (o>>9)&7, nt = (o>>12)&1, dp = (o>>13)&1;
      int cc = nt*16 + (l&15);
      int kk = dp*256 + kt*32 + (l>>4)*8 + e;
      we_p[o] = (cc < NCLS) ? f2fp8(W_e[cc*512 + kk] * 64.f) : (unsigned char)0;
      continue;
    }
    j -= N_WE;
    { int o = (int)j; int d = o>>10; int g = o & 1023;
      bias[o] = d ? (bih_b[g]+bhh_b[g]) : (bih_f[g]+bhh_f[g]); }
  }
}

// ------- xg chunk: emb[sent] @ W_ih^T + biases, stored permuted bf16 -------
__global__ __launch_bounds__(256) void xg_kernel(const int* sent, const float* emb,
    const unsigned short* wih_p, const float* bias, unsigned short* xg, int k)
{
  int d = blockIdx.y;
  int blk = blockIdx.x;            // 0..255
  int u = blk >> 2, q = blk & 3;   // u = local step, batch rows 32q..32q+31
  int ss = k*CHUNK + u;
  int t = d ? (T_LEN-1-ss) : ss;
  int w = threadIdx.x >> 6, l = threadIdx.x & 63, lg = l >> 4, lm = l & 15;

  int tok0 = sent[t*BATCH + q*32 + lm];
  int tok1 = sent[t*BATCH + q*32 + 16 + lm];

  const char* wbase = (const char*)wih_p + ((long)(d*4 + w) << 17);

  f32x4 acc[2][16] = {};
  for (int kt = 0; kt < 8; ++kt) {
    const float* p0 = emb + (long)tok0*256 + kt*32 + lg*8;
    const float* p1 = emb + (long)tok1*256 + kt*32 + lg*8;
    f32x4 q00 = *(const f32x4*)p0, q01 = *(const f32x4*)(p0+4);
    f32x4 q10 = *(const f32x4*)p1, q11 = *(const f32x4*)(p1+4);
    s16x8 a0, a1;
    #pragma unroll
    for (int e = 0; e < 4; ++e) {
      a0[e]   = (short)f2bf(q00[e]); a0[4+e] = (short)f2bf(q01[e]);
      a1[e]   = (short)f2bf(q10[e]); a1[4+e] = (short)f2bf(q11[e]);
    }
    #pragma unroll
    for (int s = 0; s < 16; ++s) {
      s16x8 bf = *(const s16x8*)(wbase + (((kt*16 + s) << 10) + (l << 4)));
      acc[0][s] = __builtin_amdgcn_mfma_f32_16x16x32_bf16(a0, bf, acc[0][s], 0,0,0);
      acc[1][s] = __builtin_amdgcn_mfma_f32_16x16x32_bf16(a1, bf, acc[1][s], 0,0,0);
    }
  }
  float bsv[16];
  #pragma unroll
  for (int s = 0; s < 16; ++s) {
    int n = (s>>2)*256 + w*64 + (s&3)*16 + lm;
    bsv[s] = bias[d*1024 + n];
  }
  #pragma unroll
  for (int mt = 0; mt < 2; ++mt) {
    int nb = q*2 + mt;
    char* base = (char*)xg + (((((long)d*CHUNK + u)*8 + nb)*4 + w)*64 + l)*128;
    #pragma unroll
    for (int qq = 0; qq < 8; ++qq) {
      u32x4 pk;
      #pragma unroll
      for (int h2 = 0; h2 < 4; ++h2) {
        int j0 = qq*8 + h2*2;
        unsigned short v0 = f2bf(acc[mt][j0>>2][j0&3] + bsv[j0>>2]);
        unsigned short v1 = f2bf(acc[mt][(j0+1)>>2][(j0+1)&3] + bsv[(j0+1)>>2]);
        pk[h2] = (unsigned)v0 | ((unsigned)v1 << 16);
      }
      *(u32x4*)(base + qq*16) = pk;
    }
  }
}

// ---------------- LSTM chunk: fp8 weights, free-running 4-slot ring --------
// 8 waves; wave owns 32 hidden units (all 4 gates). Weight stream fp8 (x64),
// h stored fp8 (x16) in LDS; recurrent+emission MFMAs are fp8_fp8; acc/1024.
__global__ __launch_bounds__(512, 1) void lstm_kernel(const unsigned short* xg,
    const unsigned char* whh_p, const unsigned char* we_p,
    float* emis_f, float* emis_b, unsigned char* hsave, float* csave, int k)
{
  extern __shared__ char smem[];
  char* h_lds = smem;                                     // 4 KB fp8, XOR-swizzled
  char* wring = smem + 4096 + (threadIdx.x >> 6)*12288;   // 4 x 2 KB ring slots
  char* xslot = wring + 8192;                             // 4 KB xg slot (bf16)

  int id = blockIdx.x, d = id >> 3, nb = id & 7, bbase = nb*16;
  int w = threadIdx.x >> 6, l = threadIdx.x & 63, lg = l >> 4, lm = l & 15;
  float* emis = d ? emis_b : emis_f;
  const char* wbase = (const char*)whh_p + ((long)(d*8 + w) << 15);

  // emissions weights hoisted (fp8 u64 frags); waves 0,1 own nt = w
  long ewreg[8];
  if (w < 2) {
    #pragma unroll
    for (int kt = 0; kt < 8; ++kt)
      ewreg[kt] = *(const long*)((const char*)we_p + (((d*2 + w)*8 + kt)*512 + l*8));
  }

  float c[8];
  if (k == 0) {
    for (int i = threadIdx.x; i < 1024; i += 512) ((unsigned*)h_lds)[i] = 0u;
    #pragma unroll
    for (int i = 0; i < 8; ++i) c[i] = 0.f;
  } else {
    u32x4* hl = (u32x4*)h_lds;
    const u32x4* hs = (const u32x4*)(hsave + (long)id*4096);
    if (threadIdx.x < 256) hl[threadIdx.x] = hs[threadIdx.x];
    const float* cs = csave + ((long)id*512 + threadIdx.x)*8;
    #pragma unroll
    for (int i = 0; i < 8; ++i) c[i] = cs[i];
  }
  asm volatile("s_waitcnt vmcnt(0)" ::: "memory");  // drain ewreg/restore pre-loop
  __syncthreads();

  // batch b (0..15): 2 KB = frags kt=b>>1, s=(b&1)*4..+4, slot b&3 (16%4==0)
  #define ISSUE_BATCH(b) { \
    const char* gsrc = wbase + ((b) << 11); \
    char* ldst = wring + (((b) & 3) << 11); \
    gll16(gsrc + (l << 4), ldst); \
    gll16(gsrc + 1024 + (l << 4), ldst + 1024); }

  ISSUE_BATCH(0) ISSUE_BATCH(1) ISSUE_BATCH(2)   // prologue: 6 outstanding

  int prev_t = (k == 0) ? -1 : (d ? (T_LEN - k*CHUNK) : (k*CHUNK - 1));

  for (int u = 0; u < CHUNK; ++u) {
    int ss = k*CHUNK + u;
    int t = d ? (T_LEN-1-ss) : ss;
    // barrier 1: prev step's h writes visible (lgkm only; ring stays in flight)
    asm volatile("s_waitcnt lgkmcnt(0)" ::: "memory");
    __builtin_amdgcn_s_barrier();
    // A-frags of h_{t-1} (fp8, u64)
    long a[8];
    #pragma unroll
    for (int kt = 0; kt < 8; ++kt) {
      int off = (lm*256 + kt*32 + lg*8) ^ ((lm&7)<<3);
      a[kt] = *(const long*)(h_lds + off);
    }
    asm volatile("s_waitcnt lgkmcnt(0)" ::: "memory");
    __builtin_amdgcn_s_barrier();   // barrier 2: h_lds free for this step's writes

    // stage xg (4 KB/wave, bf16) into the FIFO right behind B0,B1,B2
    const char* xb = (const char*)xg
        + (((((long)d*CHUNK + u)*8 + nb)*4 + (w>>1))*64 + l)*128 + ((w&1)*16);
    #pragma unroll
    for (int i = 0; i < 4; ++i)
      gll16(xb + i*32, xslot + (i<<10));

    // waves 0,1: emissions MFMA for previous h (stores deferred past consume)
    f32x4 ea = {0.f,0.f,0.f,0.f};
    if (w < 2 && prev_t >= 0) {
      #pragma unroll
      for (int kt = 0; kt < 8; ++kt)
        ea = __builtin_amdgcn_mfma_f32_16x16x32_fp8_fp8(a[kt], ewreg[kt], ea, 0,0,0);
    }

    // consume 16 batches; counted FIFO waits (never drain to 0)
    f32x4 acc[8];
    #pragma unroll
    for (int s = 0; s < 8; ++s) acc[s] = (f32x4){0.f,0.f,0.f,0.f};
    #pragma unroll
    for (int j = 0; j < 16; ++j) {
      if (j < 3) asm volatile("s_waitcnt vmcnt(8)" ::: "memory");
      else       asm volatile("s_waitcnt vmcnt(4)" ::: "memory");
      __builtin_amdgcn_sched_barrier(0);
      const char* slot = wring + ((j & 3) << 11);
      int ktg = j >> 1, sh = (j & 1) * 4;
      #pragma unroll
      for (int s2 = 0; s2 < 4; ++s2) {
        long wf = *(const long*)(slot + (s2 << 9) + (l << 3));
        acc[sh+s2] =
            __builtin_amdgcn_mfma_f32_16x16x32_fp8_fp8(a[ktg], wf, acc[sh+s2], 0,0,0);
      }
      __builtin_amdgcn_sched_barrier(0);
      ISSUE_BATCH((j+3)&15)
      __builtin_amdgcn_sched_barrier(0);
    }

    // deferred emissions store (keeps store ops out of the counted section)
    if (w < 2 && prev_t >= 0) {
      int cc = w*16 + lm;
      if (cc < NCLS) {
        #pragma unroll
        for (int r = 0; r < 4; ++r)
          emis[((long)prev_t*BATCH + bbase + lg*4 + r)*NCLS + cc] = ea[r]*INV1024;
      }
    }

    // xg add with fp8 de-scale (xg retired by the j=3 wait; reads via LDS)
    u32x4 xv[4];
    #pragma unroll
    for (int i = 0; i < 4; ++i)
      xv[i] = *(const u32x4*)(xslot + (i<<10) + (l<<4));
    #pragma unroll
    for (int s = 0; s < 8; ++s)
      #pragma unroll
      for (int r = 0; r < 4; ++r) {
        unsigned wd = xv[s>>1][(s&1)*2 + (r>>1)];
        unsigned short us = (r&1) ? (unsigned short)(wd>>16) : (unsigned short)(wd & 0xffff);
        acc[s][r] = acc[s][r]*INV1024 + bf2f(us);
      }

    // nonlinearities: i,f,g,o at s = q, 2+q, 4+q, 6+q; h write fp8 (x16) swizzled
    #pragma unroll
    for (int q = 0; q < 2; ++q)
      #pragma unroll
      for (int r = 0; r < 4; ++r) {
        float gi = acc[q][r],   gf = acc[2+q][r];
        float gg = acc[4+q][r], go = acc[6+q][r];
        float si = 1.f/(1.f+__expf(-gi));
        float sf = 1.f/(1.f+__expf(-gf));
        float so = 1.f/(1.f+__expf(-go));
        float tg = 2.f/(1.f+__expf(-2.f*gg)) - 1.f;
        float cn = sf*c[q*4+r] + si*tg;
        c[q*4+r] = cn;
        float tc = 2.f/(1.f+__expf(-2.f*cn)) - 1.f;
        int m = lg*4 + r;
        int jj = w*32 + q*16 + lm;
        int off = (m*256 + jj) ^ ((m&7)<<3);
        *(unsigned char*)(h_lds + off) = f2fp8(so*tc*16.f);
      }
    prev_t = t;
  }

  asm volatile("s_waitcnt lgkmcnt(0)" ::: "memory");
  __builtin_amdgcn_s_barrier();

  if (k == NCHUNK-1) {
    if (w < 2) {
      long a[8];
      #pragma unroll
      for (int kt = 0; kt < 8; ++kt) {
        int off = (lm*256 + kt*32 + lg*8) ^ ((lm&7)<<3);
        a[kt] = *(const long*)(h_lds + off);
      }
      f32x4 ea = {0.f,0.f,0.f,0.f};
      #pragma unroll
      for (int kt = 0; kt < 8; ++kt)
        ea = __builtin_amdgcn_mfma_f32_16x16x32_fp8_fp8(a[kt], ewreg[kt], ea, 0,0,0);
      int cc = w*16 + lm;
      if (cc < NCLS) {
        #pragma unroll
        for (int r = 0; r < 4; ++r)
          emis[((long)prev_t*BATCH + bbase + lg*4 + r)*NCLS + cc] = ea[r]*INV1024;
      }
    }
  } else {
    u32x4* hl = (u32x4*)h_lds;
    u32x4* hs = (u32x4*)(hsave + (long)id*4096);
    if (threadIdx.x < 256) hs[threadIdx.x] = hl[threadIdx.x];
    float* cs = csave + ((long)id*512 + threadIdx.x)*8;
    #pragma unroll
    for (int i = 0; i < 8; ++i) cs[i] = c[i];
  }
  #undef ISSUE_BATCH
}

// ---------------- CRF numerator -------------------------------------------
__global__ void num_kernel(const int* sent, const int* tags, const float* emis_f,
    const float* emis_b, const float* b_e, const float* start_t, const float* end_t,
    const float* trans, float* num_buf)
{
  int b = blockIdx.x, l = threadIdx.x;   // 64 threads = 1 wave
  float acc = 0.f; int cnt = 0;
  for (int t = l; t < T_LEN; t += 64) {
    int tag = tags[t*BATCH + b];
    float E = emis_f[((long)t*BATCH+b)*NCLS + tag] + emis_b[((long)t*BATCH+b)*NCLS + tag] + b_e[tag];
    int m = (sent[t*BATCH+b] != PADTOK) ? 1 : 0;
    cnt += m;
    if (t == 0) acc += start_t[tag] + E;
    else if (m) acc += trans[tags[(t-1)*BATCH + b]*NCLS + tag] + E;
  }
  #pragma unroll
  for (int off = 32; off; off >>= 1) { acc += __shfl_xor(acc, off); cnt += __shfl_xor(cnt, off); }
  if (l == 0) num_buf[b] = acc + end_t[tags[(cnt-1)*BATCH + b]];
}

// ---------------- CRF forward algorithm (denominator) ----------------------
__global__ void denom_kernel(const int* sent, const float* emis_f, const float* emis_b,
    const float* b_e, const float* start_t, const float* end_t, const float* trans,
    const float* num_buf, float* llh)
{
  __shared__ float tr[NCLS][32];
  __shared__ float sc[2][32];
  __shared__ float be_s[32];
  int l = threadIdx.x, j = l & 31, h = l >> 5;
  int b = blockIdx.x*2 + h;
  for (int i = l; i < NCLS*32; i += 64) { int r = i >> 5, cj = i & 31; tr[r][cj] = (cj<NCLS)? trans[r*NCLS+cj] : 0.f; }
  if (l < 32) be_s[l] = (l < NCLS) ? b_e[l] : 0.f;
  __syncthreads();
  float score = -1e30f;
  if (j < NCLS) score = start_t[j] + emis_f[(long)b*NCLS+j] + emis_b[(long)b*NCLS+j] + be_s[j];
  for (int t = 1; t < T_LEN; ++t) {
    sc[h][j] = score;
    __syncthreads();
    bool m = sent[t*BATCH + b] != PADTOK;
    float mx = -1e30f;
    for (int i = 0; i < NCLS; ++i) mx = fmaxf(mx, sc[h][i] + tr[i][j]);
    float ssum = 0.f;
    for (int i = 0; i < NCLS; ++i) ssum += __expf(sc[h][i] + tr[i][j] - mx);
    float e = (j < NCLS) ? (emis_f[((long)t*BATCH+b)*NCLS+j] + emis_b[((long)t*BATCH+b)*NCLS+j] + be_s[j]) : 0.f;
    float nxt = mx + __logf(ssum) + e;
    if (m && j < NCLS) score = nxt;
    __syncthreads();
  }
  float v = (j < NCLS) ? score + end_t[j] : -1e30f;
  float mx = v;
  #pragma unroll
  for (int off = 16; off; off >>= 1) mx = fmaxf(mx, __shfl_xor(mx, off));
  float ssum = (j < NCLS) ? __expf(v - mx) : 0.f;
  #pragma unroll
  for (int off = 16; off; off >>= 1) ssum += __shfl_xor(ssum, off);
  if (j == 0) llh[b] = num_buf[b] - (mx + __logf(ssum));
}

__global__ void final_kernel(const float* llh, float* out) {
  __shared__ float red[2];
  int l = threadIdx.x;   // 128
  float v = llh[l];
  #pragma unroll
  for (int off = 32; off; off >>= 1) v += __shfl_xor(v, off);
  if ((l & 63) == 0) red[l >> 6] = v;
  __syncthreads();
  if (l == 0) out[0] = -(red[0] + red[1]);
}

extern "C" void kernel_launch(void* const* d_in, const int* in_sizes, int n_in,
                              void* d_out, int out_size, void* d_ws, size_t ws_size,
                              hipStream_t stream) {
  const int*   sent  = (const int*)d_in[0];
  const int*   tags  = (const int*)d_in[1];
  const float* emb   = (const float*)d_in[2];
  const float* wih_f = (const float*)d_in[3];
  const float* whh_f = (const float*)d_in[4];
  const float* bih_f = (const float*)d_in[5];
  const float* bhh_f = (const float*)d_in[6];
  const float* wih_b = (const float*)d_in[7];
  const float* whh_b = (const float*)d_in[8];
  const float* bih_b = (const float*)d_in[9];
  const float* bhh_b = (const float*)d_in[10];
  const float* W_e   = (const float*)d_in[11];
  const float* b_e   = (const float*)d_in[12];
  const float* st    = (const float*)d_in[13];
  const float* et    = (const float*)d_in[14];
  const float* tr    = (const float*)d_in[15];
  (void)in_sizes; (void)n_in; (void)out_size; (void)ws_size;

  char* ws = (char*)d_ws;
  unsigned short* wih_p  = (unsigned short*)ws; ws += (long)N_WPERM*2;      // 1 MiB
  unsigned char*  whh_p  = (unsigned char*)ws;  ws += (long)N_WPERM;        // 512 KiB
  unsigned char*  we_p   = (unsigned char*)ws;  ws += (long)N_WE;           // 16 KiB
  float*          bias   = (float*)ws;          ws += (long)N_BIAS*4;       // 8 KiB
  unsigned short* xgr    = (unsigned short*)ws; ws += (long)2*CHUNK*BATCH*1024*2; // 32 MiB ring
  float*          emis_f = (float*)ws;          ws += (long)T_LEN*BATCH*NCLS*4;   // 6.25 MiB
  float*          emis_b = (float*)ws;          ws += (long)T_LEN*BATCH*NCLS*4;   // 6.25 MiB
  unsigned char*  hsave  = (unsigned char*)ws;  ws += (long)16*4096;        // 64 KiB
  float*          csave  = (float*)ws;          ws += (long)16*512*8*4;     // 256 KiB
  float*          numb   = (float*)ws;          ws += 512;
  float*          llh    = (float*)ws;          ws += 512;
  // total ~46 MiB

  hipFuncSetAttribute(reinterpret_cast<const void*>(lstm_kernel),
                      hipFuncAttributeMaxDynamicSharedMemorySize, LDS_BYTES);

  prep_kernel<<<4168, 256, 0, stream>>>(wih_f, whh_f, bih_f, bhh_f,
                                        wih_b, whh_b, bih_b, bhh_b, W_e,
                                        wih_p, whh_p, we_p, bias);
  for (int k = 0; k < NCHUNK; ++k) {
    dim3 g1(256, 2);
    xg_kernel<<<g1, 256, 0, stream>>>(sent, emb, wih_p, bias, xgr, k);
    lstm_kernel<<<16, 512, LDS_BYTES, stream>>>(xgr, whh_p, we_p, emis_f, emis_b, hsave, csave, k);
  }
  num_kernel<<<128, 64, 0, stream>>>(sent, tags, emis_f, emis_b, b_e, st, et, tr, numb);
  denom_kernel<<<64, 64, 0, stream>>>(sent, emis_f, emis_b, b_e, st, et, tr, numb, llh);
  final_kernel<<<1, 128, 0, stream>>>(llh, (float*)d_out);
}

// Round 9
// 3419.877 us; speedup vs baseline: 2.5079x; 1.0285x over previous
//
#include <hip/hip_runtime.h>
#include <hip/hip_bf16.h>
#include <cstdint>

#define T_LEN 512
#define BATCH 128
#define EMBD 256
#define NCLS 25
#define PADTOK 1
#define CHUNK 64
#define NCHUNK 8

#define N_WPERM (2*4*16*8*64*8)   /* 524288: wih bf16 elems / whh fp8 bytes */
#define N_WE (2*2*8*64*8)         /* 16384 fp8 bytes */
#define N_BIAS (2*1024)

// LDS: 4 KB h(fp8) + 8 waves * (4 ring slots * 2 KB + 4 KB xg) = 100 KB
#define LDS_BYTES (4096 + 8*12288)

typedef float f32x4 __attribute__((ext_vector_type(4)));
typedef short s16x8 __attribute__((ext_vector_type(8)));
typedef unsigned int u32x4 __attribute__((ext_vector_type(4)));

#define INV1024 (0.0009765625f)

__device__ __forceinline__ unsigned short f2bf(float f) {
  unsigned int u = __builtin_bit_cast(unsigned int, f);
  unsigned int r = (u + 0x7FFFu + ((u >> 16) & 1u)) >> 16;
  return (unsigned short)r;
}
__device__ __forceinline__ float bf2f(unsigned short h) {
  unsigned int u = ((unsigned int)h) << 16;
  return __builtin_bit_cast(float, u);
}
__device__ __forceinline__ unsigned char f2fp8(float v) {
  int pk = __builtin_amdgcn_cvt_pk_fp8_f32(v, v, 0, false);
  return (unsigned char)(pk & 0xFF);
}
// async global->LDS, 16 B per lane; LDS dest is wave-uniform base (+lane*16 by HW)
__device__ __forceinline__ void gll16(const void* g, void* l) {
  __builtin_amdgcn_global_load_lds(
      (const __attribute__((address_space(1))) unsigned int*)g,
      (__attribute__((address_space(3))) unsigned int*)l, 16, 0, 0);
}

// ---------------- prep: fragment-order weight permutes + bias sum ----------
// wih (bf16, xg_kernel 4-wave): o = ((((d*4+w)*8+kt)*16+s)*64+l)*8+e
// whh (fp8 x64, lstm 8-wave):   o = ((((d*8+w)*8+kt)*8+s)*64+l)*8+e
// we  (fp8 x64):                o = (((dp*2+nt)*8+kt)*64+l)*8+e
__global__ void prep_kernel(const float* wih_f, const float* whh_f,
                            const float* bih_f, const float* bhh_f,
                            const float* wih_b, const float* whh_b,
                            const float* bih_b, const float* bhh_b,
                            const float* W_e,
                            unsigned short* wih_p, unsigned char* whh_p,
                            unsigned char* we_p, float* bias)
{
  long total = 2L*N_WPERM + N_WE + N_BIAS;
  for (long i = (long)blockIdx.x*blockDim.x + threadIdx.x; i < total;
       i += (long)gridDim.x*blockDim.x) {
    long j = i;
    if (j < N_WPERM) {           // wih, bf16, 4-wave layout
      int o = (int)j;
      int e = o & 7, l = (o>>3)&63, s = (o>>9)&15, kt = (o>>13)&7, w = (o>>16)&3, d = (o>>18)&1;
      int n = (s>>2)*256 + w*64 + (s&3)*16 + (l & 15);
      int kk = kt*32 + (l>>4)*8 + e;
      const float* src = d ? wih_b : wih_f;
      wih_p[o] = f2bf(src[n*256 + kk]);
      continue;
    }
    j -= N_WPERM;
    if (j < N_WPERM) {           // whh, fp8 scale 64, 8-wave layout
      int o = (int)j;
      int e = o & 7, l = (o>>3)&63, s = (o>>9)&7, kt = (o>>12)&7, w = (o>>15)&7, d = (o>>18)&1;
      int n = (s>>1)*256 + w*32 + (s&1)*16 + (l & 15);
      int kk = kt*32 + (l>>4)*8 + e;
      const float* src = d ? whh_b : whh_f;
      whh_p[o] = f2fp8(src[n*256 + kk] * 64.f);
      continue;
    }
    j -= N_WPERM;
    if (j < N_WE) {              // W_e, fp8 scale 64
      int o = (int)j;
      int e = o&7, l = (o>>3)&63, kt = (o>>9)&7, nt = (o>>12)&1, dp = (o>>13)&1;
      int cc = nt*16 + (l&15);
      int kk = dp*256 + kt*32 + (l>>4)*8 + e;
      we_p[o] = (cc < NCLS) ? f2fp8(W_e[cc*512 + kk] * 64.f) : (unsigned char)0;
      continue;
    }
    j -= N_WE;
    { int o = (int)j; int d = o>>10; int g = o & 1023;
      bias[o] = d ? (bih_b[g]+bhh_b[g]) : (bih_f[g]+bhh_f[g]); }
  }
}

// ------- xg chunk: emb[sent] @ W_ih^T + biases, stored permuted bf16 -------
__global__ __launch_bounds__(256) void xg_kernel(const int* sent, const float* emb,
    const unsigned short* wih_p, const float* bias, unsigned short* xg, int k)
{
  int d = blockIdx.y;
  int blk = blockIdx.x;            // 0..255
  int u = blk >> 2, q = blk & 3;   // u = local step, batch rows 32q..32q+31
  int ss = k*CHUNK + u;
  int t = d ? (T_LEN-1-ss) : ss;
  int w = threadIdx.x >> 6, l = threadIdx.x & 63, lg = l >> 4, lm = l & 15;

  int tok0 = sent[t*BATCH + q*32 + lm];
  int tok1 = sent[t*BATCH + q*32 + 16 + lm];

  const char* wbase = (const char*)wih_p + ((long)(d*4 + w) << 17);

  f32x4 acc[2][16] = {};
  for (int kt = 0; kt < 8; ++kt) {
    const float* p0 = emb + (long)tok0*256 + kt*32 + lg*8;
    const float* p1 = emb + (long)tok1*256 + kt*32 + lg*8;
    f32x4 q00 = *(const f32x4*)p0, q01 = *(const f32x4*)(p0+4);
    f32x4 q10 = *(const f32x4*)p1, q11 = *(const f32x4*)(p1+4);
    s16x8 a0, a1;
    #pragma unroll
    for (int e = 0; e < 4; ++e) {
      a0[e]   = (short)f2bf(q00[e]); a0[4+e] = (short)f2bf(q01[e]);
      a1[e]   = (short)f2bf(q10[e]); a1[4+e] = (short)f2bf(q11[e]);
    }
    #pragma unroll
    for (int s = 0; s < 16; ++s) {
      s16x8 bf = *(const s16x8*)(wbase + (((kt*16 + s) << 10) + (l << 4)));
      acc[0][s] = __builtin_amdgcn_mfma_f32_16x16x32_bf16(a0, bf, acc[0][s], 0,0,0);
      acc[1][s] = __builtin_amdgcn_mfma_f32_16x16x32_bf16(a1, bf, acc[1][s], 0,0,0);
    }
  }
  float bsv[16];
  #pragma unroll
  for (int s = 0; s < 16; ++s) {
    int n = (s>>2)*256 + w*64 + (s&3)*16 + lm;
    bsv[s] = bias[d*1024 + n];
  }
  #pragma unroll
  for (int mt = 0; mt < 2; ++mt) {
    int nb = q*2 + mt;
    char* base = (char*)xg + (((((long)d*CHUNK + u)*8 + nb)*4 + w)*64 + l)*128;
    #pragma unroll
    for (int qq = 0; qq < 8; ++qq) {
      u32x4 pk;
      #pragma unroll
      for (int h2 = 0; h2 < 4; ++h2) {
        int j0 = qq*8 + h2*2;
        unsigned short v0 = f2bf(acc[mt][j0>>2][j0&3] + bsv[j0>>2]);
        unsigned short v1 = f2bf(acc[mt][(j0+1)>>2][(j0+1)&3] + bsv[(j0+1)>>2]);
        pk[h2] = (unsigned)v0 | ((unsigned)v1 << 16);
      }
      *(u32x4*)(base + qq*16) = pk;
    }
  }
}

// ---------------- LSTM chunk: fp8 weights, free-running 4-slot ring --------
__global__ __launch_bounds__(512, 1) void lstm_kernel(const unsigned short* xg,
    const unsigned char* whh_p, const unsigned char* we_p,
    float* emis_f, float* emis_b, unsigned char* hsave, float* csave, int k)
{
  extern __shared__ char smem[];
  char* h_lds = smem;                                     // 4 KB fp8, XOR-swizzled
  char* wring = smem + 4096 + (threadIdx.x >> 6)*12288;   // 4 x 2 KB ring slots
  char* xslot = wring + 8192;                             // 4 KB xg slot (bf16)

  int id = blockIdx.x, d = id >> 3, nb = id & 7, bbase = nb*16;
  int w = threadIdx.x >> 6, l = threadIdx.x & 63, lg = l >> 4, lm = l & 15;
  float* emis = d ? emis_b : emis_f;
  const char* wbase = (const char*)whh_p + ((long)(d*8 + w) << 15);

  // emissions weights hoisted (fp8 u64 frags); waves 0,1 own nt = w
  long ewreg[8];
  if (w < 2) {
    #pragma unroll
    for (int kt = 0; kt < 8; ++kt)
      ewreg[kt] = *(const long*)((const char*)we_p + (((d*2 + w)*8 + kt)*512 + l*8));
  }

  float c[8];
  if (k == 0) {
    for (int i = threadIdx.x; i < 1024; i += 512) ((unsigned*)h_lds)[i] = 0u;
    #pragma unroll
    for (int i = 0; i < 8; ++i) c[i] = 0.f;
  } else {
    u32x4* hl = (u32x4*)h_lds;
    const u32x4* hs = (const u32x4*)(hsave + (long)id*4096);
    if (threadIdx.x < 256) hl[threadIdx.x] = hs[threadIdx.x];
    const float* cs = csave + ((long)id*512 + threadIdx.x)*8;
    #pragma unroll
    for (int i = 0; i < 8; ++i) c[i] = cs[i];
  }
  asm volatile("s_waitcnt vmcnt(0)" ::: "memory");  // drain ewreg/restore pre-loop
  __syncthreads();

  // batch b (0..15): 2 KB = frags kt=b>>1, s=(b&1)*4..+4, slot b&3 (16%4==0)
  #define ISSUE_BATCH(b) { \
    const char* gsrc = wbase + ((b) << 11); \
    char* ldst = wring + (((b) & 3) << 11); \
    gll16(gsrc + (l << 4), ldst); \
    gll16(gsrc + 1024 + (l << 4), ldst + 1024); }

  ISSUE_BATCH(0) ISSUE_BATCH(1) ISSUE_BATCH(2)   // prologue: 6 outstanding

  int prev_t = (k == 0) ? -1 : (d ? (T_LEN - k*CHUNK) : (k*CHUNK - 1));

  for (int u = 0; u < CHUNK; ++u) {
    int ss = k*CHUNK + u;
    int t = d ? (T_LEN-1-ss) : ss;
    // barrier 1: prev step's h writes visible (lgkm only; ring stays in flight)
    asm volatile("s_waitcnt lgkmcnt(0)" ::: "memory");
    __builtin_amdgcn_s_barrier();
    // A-frags of h_{t-1} (fp8, u64)
    long a[8];
    #pragma unroll
    for (int kt = 0; kt < 8; ++kt) {
      int off = (lm*256 + kt*32 + lg*8) ^ ((lm&7)<<3);
      a[kt] = *(const long*)(h_lds + off);
    }
    asm volatile("s_waitcnt lgkmcnt(0)" ::: "memory");
    __builtin_amdgcn_s_barrier();   // barrier 2: h_lds free for this step's writes

    // stage xg (4 KB/wave, bf16) into the FIFO right behind B0,B1,B2
    const char* xb = (const char*)xg
        + (((((long)d*CHUNK + u)*8 + nb)*4 + (w>>1))*64 + l)*128 + ((w&1)*16);
    #pragma unroll
    for (int i = 0; i < 4; ++i)
      gll16(xb + i*32, xslot + (i<<10));

    // waves 0,1: emissions MFMA for previous h (stores deferred past consume)
    f32x4 ea = {0.f,0.f,0.f,0.f};
    if (w < 2 && prev_t >= 0) {
      #pragma unroll
      for (int kt = 0; kt < 8; ++kt)
        ea = __builtin_amdgcn_mfma_f32_16x16x32_fp8_fp8(a[kt], ewreg[kt], ea, 0,0,0);
    }

    // consume 16 batches; counted FIFO waits (never drain to 0)
    f32x4 acc[8];
    #pragma unroll
    for (int s = 0; s < 8; ++s) acc[s] = (f32x4){0.f,0.f,0.f,0.f};
    #pragma unroll
    for (int j = 0; j < 16; ++j) {
      if (j < 3) asm volatile("s_waitcnt vmcnt(8)" ::: "memory");
      else       asm volatile("s_waitcnt vmcnt(4)" ::: "memory");
      __builtin_amdgcn_sched_barrier(0);
      const char* slot = wring + ((j & 3) << 11);
      int ktg = j >> 1, sh = (j & 1) * 4;
      #pragma unroll
      for (int s2 = 0; s2 < 4; ++s2) {
        long wf = *(const long*)(slot + (s2 << 9) + (l << 3));
        acc[sh+s2] =
            __builtin_amdgcn_mfma_f32_16x16x32_fp8_fp8(a[ktg], wf, acc[sh+s2], 0,0,0);
      }
      __builtin_amdgcn_sched_barrier(0);
      ISSUE_BATCH((j+3)&15)
      __builtin_amdgcn_sched_barrier(0);
    }

    // deferred emissions store (keeps store ops out of the counted section)
    if (w < 2 && prev_t >= 0) {
      int cc = w*16 + lm;
      if (cc < NCLS) {
        #pragma unroll
        for (int r = 0; r < 4; ++r)
          emis[((long)prev_t*BATCH + bbase + lg*4 + r)*NCLS + cc] = ea[r]*INV1024;
      }
    }

    // xg add with fp8 de-scale (xg retired by the j=3 wait; reads via LDS)
    u32x4 xv[4];
    #pragma unroll
    for (int i = 0; i < 4; ++i)
      xv[i] = *(const u32x4*)(xslot + (i<<10) + (l<<4));
    #pragma unroll
    for (int s = 0; s < 8; ++s)
      #pragma unroll
      for (int r = 0; r < 4; ++r) {
        unsigned wd = xv[s>>1][(s&1)*2 + (r>>1)];
        unsigned short us = (r&1) ? (unsigned short)(wd>>16) : (unsigned short)(wd & 0xffff);
        acc[s][r] = acc[s][r]*INV1024 + bf2f(us);
      }

    // nonlinearities: i,f,g,o at s = q, 2+q, 4+q, 6+q; h write fp8 (x16) swizzled
    #pragma unroll
    for (int q = 0; q < 2; ++q)
      #pragma unroll
      for (int r = 0; r < 4; ++r) {
        float gi = acc[q][r],   gf = acc[2+q][r];
        float gg = acc[4+q][r], go = acc[6+q][r];
        float si = 1.f/(1.f+__expf(-gi));
        float sf = 1.f/(1.f+__expf(-gf));
        float so = 1.f/(1.f+__expf(-go));
        float tg = 2.f/(1.f+__expf(-2.f*gg)) - 1.f;
        float cn = sf*c[q*4+r] + si*tg;
        c[q*4+r] = cn;
        float tc = 2.f/(1.f+__expf(-2.f*cn)) - 1.f;
        int m = lg*4 + r;
        int jj = w*32 + q*16 + lm;
        int off = (m*256 + jj) ^ ((m&7)<<3);
        *(unsigned char*)(h_lds + off) = f2fp8(so*tc*16.f);
      }
    prev_t = t;
  }

  asm volatile("s_waitcnt lgkmcnt(0)" ::: "memory");
  __builtin_amdgcn_s_barrier();

  if (k == NCHUNK-1) {
    if (w < 2) {
      long a[8];
      #pragma unroll
      for (int kt = 0; kt < 8; ++kt) {
        int off = (lm*256 + kt*32 + lg*8) ^ ((lm&7)<<3);
        a[kt] = *(const long*)(h_lds + off);
      }
      f32x4 ea = {0.f,0.f,0.f,0.f};
      #pragma unroll
      for (int kt = 0; kt < 8; ++kt)
        ea = __builtin_amdgcn_mfma_f32_16x16x32_fp8_fp8(a[kt], ewreg[kt], ea, 0,0,0);
      int cc = w*16 + lm;
      if (cc < NCLS) {
        #pragma unroll
        for (int r = 0; r < 4; ++r)
          emis[((long)prev_t*BATCH + bbase + lg*4 + r)*NCLS + cc] = ea[r]*INV1024;
      }
    }
  } else {
    u32x4* hl = (u32x4*)h_lds;
    u32x4* hs = (u32x4*)(hsave + (long)id*4096);
    if (threadIdx.x < 256) hs[threadIdx.x] = hl[threadIdx.x];
    float* cs = csave + ((long)id*512 + threadIdx.x)*8;
    #pragma unroll
    for (int i = 0; i < 8; ++i) cs[i] = c[i];
  }
  #undef ISSUE_BATCH
}

// ---------------- emissions fuse: emis_c = emis_f + emis_b + b_e ------------
__global__ __launch_bounds__(256) void efuse_kernel(const float* emis_f,
    const float* emis_b, const float* b_e, float* emis_c)
{
  int i = blockIdx.x*256 + threadIdx.x;
  if (i < T_LEN*BATCH*NCLS)
    emis_c[i] = emis_f[i] + emis_b[i] + b_e[i % NCLS];
}

// ---------------- CRF numerator -------------------------------------------
__global__ void num_kernel(const int* sent, const int* tags, const float* emis_c,
    const float* start_t, const float* end_t, const float* trans, float* num_buf)
{
  int b = blockIdx.x, l = threadIdx.x;   // 64 threads = 1 wave
  float acc = 0.f; int cnt = 0;
  for (int t = l; t < T_LEN; t += 64) {
    int tag = tags[t*BATCH + b];
    float E = emis_c[((long)t*BATCH+b)*NCLS + tag];
    int m = (sent[t*BATCH+b] != PADTOK) ? 1 : 0;
    cnt += m;
    if (t == 0) acc += start_t[tag] + E;
    else if (m) acc += trans[tags[(t-1)*BATCH + b]*NCLS + tag] + E;
  }
  #pragma unroll
  for (int off = 32; off; off >>= 1) { acc += __shfl_xor(acc, off); cnt += __shfl_xor(cnt, off); }
  if (l == 0) num_buf[b] = acc + end_t[tags[(cnt-1)*BATCH + b]];
}

// ---------------- CRF forward (denominator): 1 row per wave, readlane bcast -
// No LDS, no barriers on the 511-step chain; emissions prefetched 2 deep.
__global__ __launch_bounds__(64) void denom_kernel(const int* sent, const float* emis_c,
    const float* start_t, const float* end_t, const float* trans,
    const float* num_buf, float* llh)
{
  int b = blockIdx.x, l = threadIdx.x;   // 128 blocks, 1 wave each
  int j = (l < NCLS) ? l : 0;            // lanes 0..24 carry score

  float trc[NCLS];
  #pragma unroll
  for (int i = 0; i < NCLS; ++i) trc[i] = trans[i*NCLS + j];

  float score = start_t[j] + emis_c[(long)b*NCLS + j];

  // depth-2 prefetch pipeline
  float e1 = emis_c[((long)1*BATCH + b)*NCLS + j];
  float e2 = emis_c[((long)2*BATCH + b)*NCLS + j];
  int   m1 = sent[1*BATCH + b];
  int   m2 = sent[2*BATCH + b];

  for (int t = 1; t < T_LEN; ++t) {
    float e0 = e1; int m0 = m1;
    e1 = e2; m1 = m2;
    if (t + 2 < T_LEN) {
      e2 = emis_c[((long)(t+2)*BATCH + b)*NCLS + j];
      m2 = sent[(t+2)*BATCH + b];
    }
    float v[NCLS];
    #pragma unroll
    for (int i = 0; i < NCLS; ++i) {
      int si = __builtin_amdgcn_readlane(__builtin_bit_cast(int, score), i);
      v[i] = __builtin_bit_cast(float, si) + trc[i];
    }
    float mx = v[0];
    #pragma unroll
    for (int i = 1; i < NCLS; ++i) mx = fmaxf(mx, v[i]);
    float ssum = 0.f;
    #pragma unroll
    for (int i = 0; i < NCLS; ++i) ssum += __expf(v[i] - mx);
    float nxt = mx + __logf(ssum) + e0;
    if (m0 != PADTOK) score = nxt;
  }

  float vfin = (l < NCLS) ? score + end_t[l] : -1e30f;
  float mx = vfin;
  #pragma unroll
  for (int off = 32; off; off >>= 1) mx = fmaxf(mx, __shfl_xor(mx, off));
  float ssum = (l < NCLS) ? __expf(vfin - mx) : 0.f;
  #pragma unroll
  for (int off = 32; off; off >>= 1) ssum += __shfl_xor(ssum, off);
  if (l == 0) llh[b] = num_buf[b] - (mx + __logf(ssum));
}

__global__ void final_kernel(const float* llh, float* out) {
  __shared__ float red[2];
  int l = threadIdx.x;   // 128
  float v = llh[l];
  #pragma unroll
  for (int off = 32; off; off >>= 1) v += __shfl_xor(v, off);
  if ((l & 63) == 0) red[l >> 6] = v;
  __syncthreads();
  if (l == 0) out[0] = -(red[0] + red[1]);
}

extern "C" void kernel_launch(void* const* d_in, const int* in_sizes, int n_in,
                              void* d_out, int out_size, void* d_ws, size_t ws_size,
                              hipStream_t stream) {
  const int*   sent  = (const int*)d_in[0];
  const int*   tags  = (const int*)d_in[1];
  const float* emb   = (const float*)d_in[2];
  const float* wih_f = (const float*)d_in[3];
  const float* whh_f = (const float*)d_in[4];
  const float* bih_f = (const float*)d_in[5];
  const float* bhh_f = (const float*)d_in[6];
  const float* wih_b = (const float*)d_in[7];
  const float* whh_b = (const float*)d_in[8];
  const float* bih_b = (const float*)d_in[9];
  const float* bhh_b = (const float*)d_in[10];
  const float* W_e   = (const float*)d_in[11];
  const float* b_e   = (const float*)d_in[12];
  const float* st    = (const float*)d_in[13];
  const float* et    = (const float*)d_in[14];
  const float* tr    = (const float*)d_in[15];
  (void)in_sizes; (void)n_in; (void)out_size; (void)ws_size;

  char* ws = (char*)d_ws;
  unsigned short* wih_p  = (unsigned short*)ws; ws += (long)N_WPERM*2;      // 1 MiB
  unsigned char*  whh_p  = (unsigned char*)ws;  ws += (long)N_WPERM;        // 512 KiB
  unsigned char*  we_p   = (unsigned char*)ws;  ws += (long)N_WE;           // 16 KiB
  float*          bias   = (float*)ws;          ws += (long)N_BIAS*4;       // 8 KiB
  unsigned short* xgr    = (unsigned short*)ws; ws += (long)2*CHUNK*BATCH*1024*2; // 32 MiB ring
  float*          emis_f = (float*)ws;          ws += (long)T_LEN*BATCH*NCLS*4;   // 6.25 MiB
  float*          emis_b = (float*)ws;          ws += (long)T_LEN*BATCH*NCLS*4;   // 6.25 MiB
  unsigned char*  hsave  = (unsigned char*)ws;  ws += (long)16*4096;        // 64 KiB
  float*          csave  = (float*)ws;          ws += (long)16*512*8*4;     // 256 KiB
  float*          numb   = (float*)ws;          ws += 512;
  float*          llh    = (float*)ws;          ws += 512;
  float*          emis_c = (float*)xgr;   // alias: xgr is dead after last lstm
  // total ~46 MiB

  hipFuncSetAttribute(reinterpret_cast<const void*>(lstm_kernel),
                      hipFuncAttributeMaxDynamicSharedMemorySize, LDS_BYTES);

  prep_kernel<<<4168, 256, 0, stream>>>(wih_f, whh_f, bih_f, bhh_f,
                                        wih_b, whh_b, bih_b, bhh_b, W_e,
                                        wih_p, whh_p, we_p, bias);
  for (int k = 0; k < NCHUNK; ++k) {
    dim3 g1(256, 2);
    xg_kernel<<<g1, 256, 0, stream>>>(sent, emb, wih_p, bias, xgr, k);
    lstm_kernel<<<16, 512, LDS_BYTES, stream>>>(xgr, whh_p, we_p, emis_f, emis_b, hsave, csave, k);
  }
  efuse_kernel<<<(T_LEN*BATCH*NCLS + 255)/256, 256, 0, stream>>>(emis_f, emis_b, b_e, emis_c);
  num_kernel<<<128, 64, 0, stream>>>(sent, tags, emis_c, st, et, tr, numb);
  denom_kernel<<<128, 64, 0, stream>>>(sent, emis_c, st, et, tr, numb, llh);
  final_kernel<<<1, 128, 0, stream>>>(llh, (float*)d_out);
}

// Round 10
// 2457.756 us; speedup vs baseline: 3.4897x; 1.3915x over previous
//
#include <hip/hip_runtime.h>
#include <hip/hip_bf16.h>
#include <cstdint>

#define T_LEN 512
#define BATCH 128
#define EMBD 256
#define NCLS 25
#define PADTOK 1
#define CHUNK 64
#define NCHUNK 8

#define N_WPERM (2*4*16*8*64*8)   /* 524288: wih bf16 elems / whh fp8 bytes */
#define N_WE (2*2*8*64*8)         /* 16384 fp8 bytes */
#define N_BIAS (2*1024)

typedef float f32x4 __attribute__((ext_vector_type(4)));
typedef short s16x8 __attribute__((ext_vector_type(8)));
typedef unsigned int u32x4 __attribute__((ext_vector_type(4)));

#define INV1024 (0.0009765625f)

__device__ __forceinline__ unsigned short f2bf(float f) {
  unsigned int u = __builtin_bit_cast(unsigned int, f);
  unsigned int r = (u + 0x7FFFu + ((u >> 16) & 1u)) >> 16;
  return (unsigned short)r;
}
__device__ __forceinline__ float bf2f(unsigned short h) {
  unsigned int u = ((unsigned int)h) << 16;
  return __builtin_bit_cast(float, u);
}
__device__ __forceinline__ unsigned char f2fp8(float v) {
  int pk = __builtin_amdgcn_cvt_pk_fp8_f32(v, v, 0, false);
  return (unsigned char)(pk & 0xFF);
}

// ---------------- prep: fragment-order weight permutes + bias sum ----------
// wih (bf16, xg_kernel 4-wave): o = ((((d*4+w)*8+kt)*16+s)*64+l)*8+e
// whh (fp8 x64, lstm 8-wave):   o = ((((d*8+w)*8+kt)*8+s)*64+l)*8+e
// we  (fp8 x64):                o = (((dp*2+nt)*8+kt)*64+l)*8+e
__global__ void prep_kernel(const float* wih_f, const float* whh_f,
                            const float* bih_f, const float* bhh_f,
                            const float* wih_b, const float* whh_b,
                            const float* bih_b, const float* bhh_b,
                            const float* W_e,
                            unsigned short* wih_p, unsigned char* whh_p,
                            unsigned char* we_p, float* bias)
{
  long total = 2L*N_WPERM + N_WE + N_BIAS;
  for (long i = (long)blockIdx.x*blockDim.x + threadIdx.x; i < total;
       i += (long)gridDim.x*blockDim.x) {
    long j = i;
    if (j < N_WPERM) {           // wih, bf16, 4-wave layout
      int o = (int)j;
      int e = o & 7, l = (o>>3)&63, s = (o>>9)&15, kt = (o>>13)&7, w = (o>>16)&3, d = (o>>18)&1;
      int n = (s>>2)*256 + w*64 + (s&3)*16 + (l & 15);
      int kk = kt*32 + (l>>4)*8 + e;
      const float* src = d ? wih_b : wih_f;
      wih_p[o] = f2bf(src[n*256 + kk]);
      continue;
    }
    j -= N_WPERM;
    if (j < N_WPERM) {           // whh, fp8 scale 64, 8-wave layout
      int o = (int)j;
      int e = o & 7, l = (o>>3)&63, s = (o>>9)&7, kt = (o>>12)&7, w = (o>>15)&7, d = (o>>18)&1;
      int n = (s>>1)*256 + w*32 + (s&1)*16 + (l & 15);
      int kk = kt*32 + (l>>4)*8 + e;
      const float* src = d ? whh_b : whh_f;
      whh_p[o] = f2fp8(src[n*256 + kk] * 64.f);
      continue;
    }
    j -= N_WPERM;
    if (j < N_WE) {              // W_e, fp8 scale 64
      int o = (int)j;
      int e = o&7, l = (o>>3)&63, kt = (o>>9)&7, nt = (o>>12)&1, dp = (o>>13)&1;
      int cc = nt*16 + (l&15);
      int kk = dp*256 + kt*32 + (l>>4)*8 + e;
      we_p[o] = (cc < NCLS) ? f2fp8(W_e[cc*512 + kk] * 64.f) : (unsigned char)0;
      continue;
    }
    j -= N_WE;
    { int o = (int)j; int d = o>>10; int g = o & 1023;
      bias[o] = d ? (bih_b[g]+bhh_b[g]) : (bih_f[g]+bhh_f[g]); }
  }
}

// ------- xg chunk: emb[sent] @ W_ih^T + biases, stored permuted bf16 -------
__global__ __launch_bounds__(256) void xg_kernel(const int* sent, const float* emb,
    const unsigned short* wih_p, const float* bias, unsigned short* xg, int k)
{
  int d = blockIdx.y;
  int blk = blockIdx.x;            // 0..255
  int u = blk >> 2, q = blk & 3;   // u = local step, batch rows 32q..32q+31
  int ss = k*CHUNK + u;
  int t = d ? (T_LEN-1-ss) : ss;
  int w = threadIdx.x >> 6, l = threadIdx.x & 63, lg = l >> 4, lm = l & 15;

  int tok0 = sent[t*BATCH + q*32 + lm];
  int tok1 = sent[t*BATCH + q*32 + 16 + lm];

  const char* wbase = (const char*)wih_p + ((long)(d*4 + w) << 17);

  f32x4 acc[2][16] = {};
  for (int kt = 0; kt < 8; ++kt) {
    const float* p0 = emb + (long)tok0*256 + kt*32 + lg*8;
    const float* p1 = emb + (long)tok1*256 + kt*32 + lg*8;
    f32x4 q00 = *(const f32x4*)p0, q01 = *(const f32x4*)(p0+4);
    f32x4 q10 = *(const f32x4*)p1, q11 = *(const f32x4*)(p1+4);
    s16x8 a0, a1;
    #pragma unroll
    for (int e = 0; e < 4; ++e) {
      a0[e]   = (short)f2bf(q00[e]); a0[4+e] = (short)f2bf(q01[e]);
      a1[e]   = (short)f2bf(q10[e]); a1[4+e] = (short)f2bf(q11[e]);
    }
    #pragma unroll
    for (int s = 0; s < 16; ++s) {
      s16x8 bf = *(const s16x8*)(wbase + (((kt*16 + s) << 10) + (l << 4)));
      acc[0][s] = __builtin_amdgcn_mfma_f32_16x16x32_bf16(a0, bf, acc[0][s], 0,0,0);
      acc[1][s] = __builtin_amdgcn_mfma_f32_16x16x32_bf16(a1, bf, acc[1][s], 0,0,0);
    }
  }
  float bsv[16];
  #pragma unroll
  for (int s = 0; s < 16; ++s) {
    int n = (s>>2)*256 + w*64 + (s&3)*16 + lm;
    bsv[s] = bias[d*1024 + n];
  }
  #pragma unroll
  for (int mt = 0; mt < 2; ++mt) {
    int nb = q*2 + mt;
    char* base = (char*)xg + (((((long)d*CHUNK + u)*8 + nb)*4 + w)*64 + l)*128;
    #pragma unroll
    for (int qq = 0; qq < 8; ++qq) {
      u32x4 pk;
      #pragma unroll
      for (int h2 = 0; h2 < 4; ++h2) {
        int j0 = qq*8 + h2*2;
        unsigned short v0 = f2bf(acc[mt][j0>>2][j0&3] + bsv[j0>>2]);
        unsigned short v1 = f2bf(acc[mt][(j0+1)>>2][(j0+1)&3] + bsv[(j0+1)>>2]);
        pk[h2] = (unsigned)v0 | ((unsigned)v1 << 16);
      }
      *(u32x4*)(base + qq*16) = pk;
    }
  }
}

// ---------------- LSTM chunk: W_hh fully register-resident (fp8) ----------
// 8 waves; wave owns 32 hidden units (all 4 gates). Whole W_hh slice = 64
// fp8-u64 frags = 128 VGPRs. No weight streaming in the step loop.
__global__ __launch_bounds__(512, 1) void lstm_kernel(const unsigned short* xg,
    const unsigned char* whh_p, const unsigned char* we_p,
    float* emis_f, float* emis_b, unsigned char* hsave, float* csave, int k)
{
  __shared__ char h_lds[4096];     // fp8 h, XOR-swizzled
  __shared__ char we_lds[8192];    // emission weights for this direction

  int id = blockIdx.x, d = id >> 3, nb = id & 7, bbase = nb*16;
  int w = threadIdx.x >> 6, l = threadIdx.x & 63, lg = l >> 4, lm = l & 15;
  float* emis = d ? emis_b : emis_f;

  // stage emission weights (8 KB, once)
  ((u32x4*)we_lds)[threadIdx.x] = ((const u32x4*)we_p)[d*512 + threadIdx.x];

  // whole W_hh slice in registers: 64 frags x (8 fp8) = 128 VGPRs
  long wreg[64];
  const char* wbase = (const char*)whh_p + ((long)(d*8 + w) << 15);
  #pragma unroll
  for (int i = 0; i < 64; ++i)
    wreg[i] = *(const long*)(wbase + (i << 9) + (l << 3));

  float c[8];
  if (k == 0) {
    for (int i = threadIdx.x; i < 1024; i += 512) ((unsigned*)h_lds)[i] = 0u;
    #pragma unroll
    for (int i = 0; i < 8; ++i) c[i] = 0.f;
  } else {
    u32x4* hl = (u32x4*)h_lds;
    const u32x4* hs = (const u32x4*)(hsave + (long)id*4096);
    if (threadIdx.x < 256) hl[threadIdx.x] = hs[threadIdx.x];
    const float* cs = csave + ((long)id*512 + threadIdx.x)*8;
    #pragma unroll
    for (int i = 0; i < 8; ++i) c[i] = cs[i];
  }
  __syncthreads();

  int prev_t = (k == 0) ? -1 : (d ? (T_LEN - k*CHUNK) : (k*CHUNK - 1));

  for (int u = 0; u < CHUNK; ++u) {
    int ss = k*CHUNK + u;
    int t = d ? (T_LEN-1-ss) : ss;

    // xg loads issued early; compiler-tracked (raw barriers don't drain them)
    const char* xb = (const char*)xg
        + (((((long)d*CHUNK + u)*8 + nb)*4 + (w>>1))*64 + l)*128 + ((w&1)*16);
    u32x4 xv[4];
    #pragma unroll
    for (int i = 0; i < 4; ++i)
      xv[i] = *(const u32x4*)(xb + i*32);

    asm volatile("s_waitcnt lgkmcnt(0)" ::: "memory");
    __builtin_amdgcn_s_barrier();               // B1: prev h writes visible
    long a[8];
    #pragma unroll
    for (int kt = 0; kt < 8; ++kt) {
      int off = (lm*256 + kt*32 + lg*8) ^ ((lm&7)<<3);
      a[kt] = *(const long*)(h_lds + off);
    }
    asm volatile("s_waitcnt lgkmcnt(0)" ::: "memory");
    __builtin_amdgcn_s_barrier();               // B2: h_lds free for writes

    // emissions MFMA for previous h (waves 0,1; weights from LDS)
    f32x4 ea = {0.f,0.f,0.f,0.f};
    if (w < 2 && prev_t >= 0) {
      #pragma unroll
      for (int kt = 0; kt < 8; ++kt) {
        long ew = *(const long*)(we_lds + ((w*8 + kt) << 9) + (l << 3));
        ea = __builtin_amdgcn_mfma_f32_16x16x32_fp8_fp8(a[kt], ew, ea, 0,0,0);
      }
    }

    // main matvec: all weights in registers
    f32x4 acc[8];
    #pragma unroll
    for (int s = 0; s < 8; ++s) acc[s] = (f32x4){0.f,0.f,0.f,0.f};
    #pragma unroll
    for (int kt = 0; kt < 8; ++kt)
      #pragma unroll
      for (int s = 0; s < 8; ++s)
        acc[s] = __builtin_amdgcn_mfma_f32_16x16x32_fp8_fp8(a[kt], wreg[kt*8+s], acc[s], 0,0,0);

    // emissions store
    if (w < 2 && prev_t >= 0) {
      int cc = w*16 + lm;
      if (cc < NCLS) {
        #pragma unroll
        for (int r = 0; r < 4; ++r)
          emis[((long)prev_t*BATCH + bbase + lg*4 + r)*NCLS + cc] = ea[r]*INV1024;
      }
    }

    // xg add with fp8 de-scale
    #pragma unroll
    for (int s = 0; s < 8; ++s)
      #pragma unroll
      for (int r = 0; r < 4; ++r) {
        unsigned wd = xv[s>>1][(s&1)*2 + (r>>1)];
        unsigned short us = (r&1) ? (unsigned short)(wd>>16) : (unsigned short)(wd & 0xffff);
        acc[s][r] = acc[s][r]*INV1024 + bf2f(us);
      }

    // nonlinearities: i,f,g,o at s = q, 2+q, 4+q, 6+q; h write fp8 (x16)
    #pragma unroll
    for (int q = 0; q < 2; ++q)
      #pragma unroll
      for (int r = 0; r < 4; ++r) {
        float gi = acc[q][r],   gf = acc[2+q][r];
        float gg = acc[4+q][r], go = acc[6+q][r];
        float si = 1.f/(1.f+__expf(-gi));
        float sf = 1.f/(1.f+__expf(-gf));
        float so = 1.f/(1.f+__expf(-go));
        float tg = 2.f/(1.f+__expf(-2.f*gg)) - 1.f;
        float cn = sf*c[q*4+r] + si*tg;
        c[q*4+r] = cn;
        float tc = 2.f/(1.f+__expf(-2.f*cn)) - 1.f;
        int m = lg*4 + r;
        int jj = w*32 + q*16 + lm;
        int off = (m*256 + jj) ^ ((m&7)<<3);
        *(unsigned char*)(h_lds + off) = f2fp8(so*tc*16.f);
      }
    prev_t = t;
  }

  asm volatile("s_waitcnt lgkmcnt(0)" ::: "memory");
  __builtin_amdgcn_s_barrier();

  if (k == NCHUNK-1) {
    if (w < 2) {
      long a[8];
      #pragma unroll
      for (int kt = 0; kt < 8; ++kt) {
        int off = (lm*256 + kt*32 + lg*8) ^ ((lm&7)<<3);
        a[kt] = *(const long*)(h_lds + off);
      }
      f32x4 ea = {0.f,0.f,0.f,0.f};
      #pragma unroll
      for (int kt = 0; kt < 8; ++kt) {
        long ew = *(const long*)(we_lds + ((w*8 + kt) << 9) + (l << 3));
        ea = __builtin_amdgcn_mfma_f32_16x16x32_fp8_fp8(a[kt], ew, ea, 0,0,0);
      }
      int cc = w*16 + lm;
      if (cc < NCLS) {
        #pragma unroll
        for (int r = 0; r < 4; ++r)
          emis[((long)prev_t*BATCH + bbase + lg*4 + r)*NCLS + cc] = ea[r]*INV1024;
      }
    }
  } else {
    u32x4* hl = (u32x4*)h_lds;
    u32x4* hs = (u32x4*)(hsave + (long)id*4096);
    if (threadIdx.x < 256) hs[threadIdx.x] = hl[threadIdx.x];
    float* cs = csave + ((long)id*512 + threadIdx.x)*8;
    #pragma unroll
    for (int i = 0; i < 8; ++i) cs[i] = c[i];
  }
}

// ---------------- emissions fuse: emis_c = emis_f + emis_b + b_e ------------
__global__ __launch_bounds__(256) void efuse_kernel(const float* emis_f,
    const float* emis_b, const float* b_e, float* emis_c)
{
  int i = blockIdx.x*256 + threadIdx.x;
  if (i < T_LEN*BATCH*NCLS)
    emis_c[i] = emis_f[i] + emis_b[i] + b_e[i % NCLS];
}

// ---------------- CRF numerator -------------------------------------------
__global__ void num_kernel(const int* sent, const int* tags, const float* emis_c,
    const float* start_t, const float* end_t, const float* trans, float* num_buf)
{
  int b = blockIdx.x, l = threadIdx.x;   // 64 threads = 1 wave
  float acc = 0.f; int cnt = 0;
  for (int t = l; t < T_LEN; t += 64) {
    int tag = tags[t*BATCH + b];
    float E = emis_c[((long)t*BATCH+b)*NCLS + tag];
    int m = (sent[t*BATCH+b] != PADTOK) ? 1 : 0;
    cnt += m;
    if (t == 0) acc += start_t[tag] + E;
    else if (m) acc += trans[tags[(t-1)*BATCH + b]*NCLS + tag] + E;
  }
  #pragma unroll
  for (int off = 32; off; off >>= 1) { acc += __shfl_xor(acc, off); cnt += __shfl_xor(cnt, off); }
  if (l == 0) num_buf[b] = acc + end_t[tags[(cnt-1)*BATCH + b]];
}

// ---------------- CRF forward (denominator): 1 row per wave, readlane bcast -
__global__ __launch_bounds__(64) void denom_kernel(const int* sent, const float* emis_c,
    const float* start_t, const float* end_t, const float* trans,
    const float* num_buf, float* llh)
{
  int b = blockIdx.x, l = threadIdx.x;   // 128 blocks, 1 wave each
  int j = (l < NCLS) ? l : 0;            // lanes 0..24 carry score

  float trc[NCLS];
  #pragma unroll
  for (int i = 0; i < NCLS; ++i) trc[i] = trans[i*NCLS + j];

  float score = start_t[j] + emis_c[(long)b*NCLS + j];

  // depth-2 prefetch pipeline
  float e1 = emis_c[((long)1*BATCH + b)*NCLS + j];
  float e2 = emis_c[((long)2*BATCH + b)*NCLS + j];
  int   m1 = sent[1*BATCH + b];
  int   m2 = sent[2*BATCH + b];

  for (int t = 1; t < T_LEN; ++t) {
    float e0 = e1; int m0 = m1;
    e1 = e2; m1 = m2;
    if (t + 2 < T_LEN) {
      e2 = emis_c[((long)(t+2)*BATCH + b)*NCLS + j];
      m2 = sent[(t+2)*BATCH + b];
    }
    float v[NCLS];
    #pragma unroll
    for (int i = 0; i < NCLS; ++i) {
      int si = __builtin_amdgcn_readlane(__builtin_bit_cast(int, score), i);
      v[i] = __builtin_bit_cast(float, si) + trc[i];
    }
    float mx = v[0];
    #pragma unroll
    for (int i = 1; i < NCLS; ++i) mx = fmaxf(mx, v[i]);
    float ssum = 0.f;
    #pragma unroll
    for (int i = 0; i < NCLS; ++i) ssum += __expf(v[i] - mx);
    float nxt = mx + __logf(ssum) + e0;
    if (m0 != PADTOK) score = nxt;
  }

  float vfin = (l < NCLS) ? score + end_t[l] : -1e30f;
  float mx = vfin;
  #pragma unroll
  for (int off = 32; off; off >>= 1) mx = fmaxf(mx, __shfl_xor(mx, off));
  float ssum = (l < NCLS) ? __expf(vfin - mx) : 0.f;
  #pragma unroll
  for (int off = 32; off; off >>= 1) ssum += __shfl_xor(ssum, off);
  if (l == 0) llh[b] = num_buf[b] - (mx + __logf(ssum));
}

__global__ void final_kernel(const float* llh, float* out) {
  __shared__ float red[2];
  int l = threadIdx.x;   // 128
  float v = llh[l];
  #pragma unroll
  for (int off = 32; off; off >>= 1) v += __shfl_xor(v, off);
  if ((l & 63) == 0) red[l >> 6] = v;
  __syncthreads();
  if (l == 0) out[0] = -(red[0] + red[1]);
}

extern "C" void kernel_launch(void* const* d_in, const int* in_sizes, int n_in,
                              void* d_out, int out_size, void* d_ws, size_t ws_size,
                              hipStream_t stream) {
  const int*   sent  = (const int*)d_in[0];
  const int*   tags  = (const int*)d_in[1];
  const float* emb   = (const float*)d_in[2];
  const float* wih_f = (const float*)d_in[3];
  const float* whh_f = (const float*)d_in[4];
  const float* bih_f = (const float*)d_in[5];
  const float* bhh_f = (const float*)d_in[6];
  const float* wih_b = (const float*)d_in[7];
  const float* whh_b = (const float*)d_in[8];
  const float* bih_b = (const float*)d_in[9];
  const float* bhh_b = (const float*)d_in[10];
  const float* W_e   = (const float*)d_in[11];
  const float* b_e   = (const float*)d_in[12];
  const float* st    = (const float*)d_in[13];
  const float* et    = (const float*)d_in[14];
  const float* tr    = (const float*)d_in[15];
  (void)in_sizes; (void)n_in; (void)out_size; (void)ws_size;

  char* ws = (char*)d_ws;
  unsigned short* wih_p  = (unsigned short*)ws; ws += (long)N_WPERM*2;      // 1 MiB
  unsigned char*  whh_p  = (unsigned char*)ws;  ws += (long)N_WPERM;        // 512 KiB
  unsigned char*  we_p   = (unsigned char*)ws;  ws += (long)N_WE;           // 16 KiB
  float*          bias   = (float*)ws;          ws += (long)N_BIAS*4;       // 8 KiB
  unsigned short* xgr    = (unsigned short*)ws; ws += (long)2*CHUNK*BATCH*1024*2; // 32 MiB ring
  float*          emis_f = (float*)ws;          ws += (long)T_LEN*BATCH*NCLS*4;   // 6.25 MiB
  float*          emis_b = (float*)ws;          ws += (long)T_LEN*BATCH*NCLS*4;   // 6.25 MiB
  unsigned char*  hsave  = (unsigned char*)ws;  ws += (long)16*4096;        // 64 KiB
  float*          csave  = (float*)ws;          ws += (long)16*512*8*4;     // 256 KiB
  float*          numb   = (float*)ws;          ws += 512;
  float*          llh    = (float*)ws;          ws += 512;
  float*          emis_c = (float*)xgr;   // alias: xgr is dead after last lstm
  // total ~46 MiB

  prep_kernel<<<4168, 256, 0, stream>>>(wih_f, whh_f, bih_f, bhh_f,
                                        wih_b, whh_b, bih_b, bhh_b, W_e,
                                        wih_p, whh_p, we_p, bias);
  for (int k = 0; k < NCHUNK; ++k) {
    dim3 g1(256, 2);
    xg_kernel<<<g1, 256, 0, stream>>>(sent, emb, wih_p, bias, xgr, k);
    lstm_kernel<<<16, 512, 0, stream>>>(xgr, whh_p, we_p, emis_f, emis_b, hsave, csave, k);
  }
  efuse_kernel<<<(T_LEN*BATCH*NCLS + 255)/256, 256, 0, stream>>>(emis_f, emis_b, b_e, emis_c);
  num_kernel<<<128, 64, 0, stream>>>(sent, tags, emis_c, st, et, tr, numb);
  denom_kernel<<<128, 64, 0, stream>>>(sent, emis_c, st, et, tr, numb, llh);
  final_kernel<<<1, 128, 0, stream>>>(llh, (float*)d_out);
}

// Round 11
// 2185.192 us; speedup vs baseline: 3.9250x; 1.1247x over previous
//
#include <hip/hip_runtime.h>
#include <hip/hip_bf16.h>
#include <cstdint>

#define T_LEN 512
#define BATCH 128
#define EMBD 256
#define NCLS 25
#define PADTOK 1
#define CHUNK 64
#define NCHUNK 8

#define N_WPERM (2*4*16*8*64*8)   /* 524288: wih bf16 elems / whh fp8 bytes */
#define N_WE (2*2*8*64*8)         /* 16384 fp8 bytes */
#define N_BIAS (2*1024)

typedef float f32x4 __attribute__((ext_vector_type(4)));
typedef short s16x8 __attribute__((ext_vector_type(8)));
typedef unsigned int u32x4 __attribute__((ext_vector_type(4)));

#define INV1024 (0.0009765625f)

__device__ __forceinline__ unsigned short f2bf(float f) {
  unsigned int u = __builtin_bit_cast(unsigned int, f);
  unsigned int r = (u + 0x7FFFu + ((u >> 16) & 1u)) >> 16;
  return (unsigned short)r;
}
__device__ __forceinline__ float bf2f(unsigned short h) {
  unsigned int u = ((unsigned int)h) << 16;
  return __builtin_bit_cast(float, u);
}
__device__ __forceinline__ unsigned char f2fp8(float v) {
  int pk = __builtin_amdgcn_cvt_pk_fp8_f32(v, v, 0, false);
  return (unsigned char)(pk & 0xFF);
}

// ---------------- prep: fragment-order weight permutes + bias sum ----------
__global__ void prep_kernel(const float* wih_f, const float* whh_f,
                            const float* bih_f, const float* bhh_f,
                            const float* wih_b, const float* whh_b,
                            const float* bih_b, const float* bhh_b,
                            const float* W_e,
                            unsigned short* wih_p, unsigned char* whh_p,
                            unsigned char* we_p, float* bias)
{
  long total = 2L*N_WPERM + N_WE + N_BIAS;
  for (long i = (long)blockIdx.x*blockDim.x + threadIdx.x; i < total;
       i += (long)gridDim.x*blockDim.x) {
    long j = i;
    if (j < N_WPERM) {           // wih, bf16, 4-wave layout
      int o = (int)j;
      int e = o & 7, l = (o>>3)&63, s = (o>>9)&15, kt = (o>>13)&7, w = (o>>16)&3, d = (o>>18)&1;
      int n = (s>>2)*256 + w*64 + (s&3)*16 + (l & 15);
      int kk = kt*32 + (l>>4)*8 + e;
      const float* src = d ? wih_b : wih_f;
      wih_p[o] = f2bf(src[n*256 + kk]);
      continue;
    }
    j -= N_WPERM;
    if (j < N_WPERM) {           // whh, fp8 scale 64, 8-wave layout
      int o = (int)j;
      int e = o & 7, l = (o>>3)&63, s = (o>>9)&7, kt = (o>>12)&7, w = (o>>15)&7, d = (o>>18)&1;
      int n = (s>>1)*256 + w*32 + (s&1)*16 + (l & 15);
      int kk = kt*32 + (l>>4)*8 + e;
      const float* src = d ? whh_b : whh_f;
      whh_p[o] = f2fp8(src[n*256 + kk] * 64.f);
      continue;
    }
    j -= N_WPERM;
    if (j < N_WE) {              // W_e, fp8 scale 64
      int o = (int)j;
      int e = o&7, l = (o>>3)&63, kt = (o>>9)&7, nt = (o>>12)&1, dp = (o>>13)&1;
      int cc = nt*16 + (l&15);
      int kk = dp*256 + kt*32 + (l>>4)*8 + e;
      we_p[o] = (cc < NCLS) ? f2fp8(W_e[cc*512 + kk] * 64.f) : (unsigned char)0;
      continue;
    }
    j -= N_WE;
    { int o = (int)j; int d = o>>10; int g = o & 1023;
      bias[o] = d ? (bih_b[g]+bhh_b[g]) : (bih_f[g]+bhh_f[g]); }
  }
}

// ------- xg body: emb[sent] @ W_ih^T + biases, stored permuted bf16 --------
__device__ __forceinline__ void xg_body(const int* sent, const float* emb,
    const unsigned short* wih_p, const float* bias, unsigned short* xg,
    int k, int blk2, int tid)
{
  int d = blk2 >> 8;
  int blk = blk2 & 255;
  int u = blk >> 2, q = blk & 3;
  int ss = k*CHUNK + u;
  int t = d ? (T_LEN-1-ss) : ss;
  int w = tid >> 6, l = tid & 63, lg = l >> 4, lm = l & 15;

  int tok0 = sent[t*BATCH + q*32 + lm];
  int tok1 = sent[t*BATCH + q*32 + 16 + lm];

  const char* wbase = (const char*)wih_p + ((long)(d*4 + w) << 17);

  f32x4 acc[2][16] = {};
  for (int kt = 0; kt < 8; ++kt) {
    const float* p0 = emb + (long)tok0*256 + kt*32 + lg*8;
    const float* p1 = emb + (long)tok1*256 + kt*32 + lg*8;
    f32x4 q00 = *(const f32x4*)p0, q01 = *(const f32x4*)(p0+4);
    f32x4 q10 = *(const f32x4*)p1, q11 = *(const f32x4*)(p1+4);
    s16x8 a0, a1;
    #pragma unroll
    for (int e = 0; e < 4; ++e) {
      a0[e]   = (short)f2bf(q00[e]); a0[4+e] = (short)f2bf(q01[e]);
      a1[e]   = (short)f2bf(q10[e]); a1[4+e] = (short)f2bf(q11[e]);
    }
    #pragma unroll
    for (int s = 0; s < 16; ++s) {
      s16x8 bf = *(const s16x8*)(wbase + (((kt*16 + s) << 10) + (l << 4)));
      acc[0][s] = __builtin_amdgcn_mfma_f32_16x16x32_bf16(a0, bf, acc[0][s], 0,0,0);
      acc[1][s] = __builtin_amdgcn_mfma_f32_16x16x32_bf16(a1, bf, acc[1][s], 0,0,0);
    }
  }
  float bsv[16];
  #pragma unroll
  for (int s = 0; s < 16; ++s) {
    int n = (s>>2)*256 + w*64 + (s&3)*16 + lm;
    bsv[s] = bias[d*1024 + n];
  }
  #pragma unroll
  for (int mt = 0; mt < 2; ++mt) {
    int nb = q*2 + mt;
    char* base = (char*)xg + (((((long)d*CHUNK + u)*8 + nb)*4 + w)*64 + l)*128;
    #pragma unroll
    for (int qq = 0; qq < 8; ++qq) {
      u32x4 pk;
      #pragma unroll
      for (int h2 = 0; h2 < 4; ++h2) {
        int j0 = qq*8 + h2*2;
        unsigned short v0 = f2bf(acc[mt][j0>>2][j0&3] + bsv[j0>>2]);
        unsigned short v1 = f2bf(acc[mt][(j0+1)>>2][(j0+1)&3] + bsv[(j0+1)>>2]);
        pk[h2] = (unsigned)v0 | ((unsigned)v1 << 16);
      }
      *(u32x4*)(base + qq*16) = pk;
    }
  }
}

// standalone xg (prologue chunk 0 + sequential fallback)
__global__ __launch_bounds__(256) void xg_kernel(const int* sent, const float* emb,
    const unsigned short* wih_p, const float* bias, unsigned short* xg, int k)
{
  xg_body(sent, emb, wih_p, bias, xg, k, blockIdx.y*256 + blockIdx.x, threadIdx.x);
}

// ---------------- fused: lstm chunk k (blocks 0-15) + xg chunk k+1 ---------
__global__ __launch_bounds__(512, 1) void fused_kernel(
    const int* sent, const float* emb, const unsigned short* wih_p, const float* bias,
    const unsigned short* xg_rd, unsigned short* xg_wr,
    const unsigned char* whh_p, const unsigned char* we_p,
    float* emis_f, float* emis_b, unsigned char* hsave, float* csave, int k)
{
  if (blockIdx.x >= 16) {
    if (threadIdx.x < 256 && k + 1 < NCHUNK)
      xg_body(sent, emb, wih_p, bias, xg_wr, k + 1, blockIdx.x - 16, threadIdx.x);
    return;
  }

  __shared__ char h_lds[4096];     // fp8 h, XOR-swizzled
  __shared__ char we_lds[8192];    // emission weights for this direction

  int id = blockIdx.x, d = id >> 3, nb = id & 7, bbase = nb*16;
  int w = threadIdx.x >> 6, l = threadIdx.x & 63, lg = l >> 4, lm = l & 15;
  float* emis = d ? emis_b : emis_f;

  // stage emission weights (8 KB, once)
  ((u32x4*)we_lds)[threadIdx.x] = ((const u32x4*)we_p)[d*512 + threadIdx.x];

  // whole W_hh slice in registers: 64 frags x (8 fp8) = 128 VGPRs
  long wreg[64];
  const char* wbase = (const char*)whh_p + ((long)(d*8 + w) << 15);
  #pragma unroll
  for (int i = 0; i < 64; ++i)
    wreg[i] = *(const long*)(wbase + (i << 9) + (l << 3));

  float c[8];
  if (k == 0) {
    for (int i = threadIdx.x; i < 1024; i += 512) ((unsigned*)h_lds)[i] = 0u;
    #pragma unroll
    for (int i = 0; i < 8; ++i) c[i] = 0.f;
  } else {
    u32x4* hl = (u32x4*)h_lds;
    const u32x4* hs = (const u32x4*)(hsave + (long)id*4096);
    if (threadIdx.x < 256) hl[threadIdx.x] = hs[threadIdx.x];
    const float* cs = csave + ((long)id*512 + threadIdx.x)*8;
    #pragma unroll
    for (int i = 0; i < 8; ++i) c[i] = cs[i];
  }
  __syncthreads();

  int prev_t = (k == 0) ? -1 : (d ? (T_LEN - k*CHUNK) : (k*CHUNK - 1));

  for (int u = 0; u < CHUNK; ++u) {
    int ss = k*CHUNK + u;
    int t = d ? (T_LEN-1-ss) : ss;

    // xg loads issued early; compiler-tracked
    const char* xb = (const char*)xg_rd
        + (((((long)d*CHUNK + u)*8 + nb)*4 + (w>>1))*64 + l)*128 + ((w&1)*16);
    u32x4 xv[4];
    #pragma unroll
    for (int i = 0; i < 4; ++i)
      xv[i] = *(const u32x4*)(xb + i*32);

    asm volatile("s_waitcnt lgkmcnt(0)" ::: "memory");
    __builtin_amdgcn_s_barrier();               // B1: prev h writes visible
    long a[8];
    #pragma unroll
    for (int kt = 0; kt < 8; ++kt) {
      int off = (lm*256 + kt*32 + lg*8) ^ ((lm&7)<<3);
      a[kt] = *(const long*)(h_lds + off);
    }
    asm volatile("s_waitcnt lgkmcnt(0)" ::: "memory");
    __builtin_amdgcn_s_barrier();               // B2: h_lds free for writes

    // emissions MFMA for previous h (waves 0,1; weights from LDS)
    f32x4 ea = {0.f,0.f,0.f,0.f};
    if (w < 2 && prev_t >= 0) {
      #pragma unroll
      for (int kt = 0; kt < 8; ++kt) {
        long ew = *(const long*)(we_lds + ((w*8 + kt) << 9) + (l << 3));
        ea = __builtin_amdgcn_mfma_f32_16x16x32_fp8_fp8(a[kt], ew, ea, 0,0,0);
      }
    }

    // main matvec: all weights in registers
    f32x4 acc[8];
    #pragma unroll
    for (int s = 0; s < 8; ++s) acc[s] = (f32x4){0.f,0.f,0.f,0.f};
    #pragma unroll
    for (int kt = 0; kt < 8; ++kt)
      #pragma unroll
      for (int s = 0; s < 8; ++s)
        acc[s] = __builtin_amdgcn_mfma_f32_16x16x32_fp8_fp8(a[kt], wreg[kt*8+s], acc[s], 0,0,0);

    // emissions store
    if (w < 2 && prev_t >= 0) {
      int cc = w*16 + lm;
      if (cc < NCLS) {
        #pragma unroll
        for (int r = 0; r < 4; ++r)
          emis[((long)prev_t*BATCH + bbase + lg*4 + r)*NCLS + cc] = ea[r]*INV1024;
      }
    }

    // xg add with fp8 de-scale
    #pragma unroll
    for (int s = 0; s < 8; ++s)
      #pragma unroll
      for (int r = 0; r < 4; ++r) {
        unsigned wd = xv[s>>1][(s&1)*2 + (r>>1)];
        unsigned short us = (r&1) ? (unsigned short)(wd>>16) : (unsigned short)(wd & 0xffff);
        acc[s][r] = acc[s][r]*INV1024 + bf2f(us);
      }

    // nonlinearities: i,f,g,o at s = q, 2+q, 4+q, 6+q; h write fp8 (x16)
    #pragma unroll
    for (int q = 0; q < 2; ++q)
      #pragma unroll
      for (int r = 0; r < 4; ++r) {
        float gi = acc[q][r],   gf = acc[2+q][r];
        float gg = acc[4+q][r], go = acc[6+q][r];
        float si = 1.f/(1.f+__expf(-gi));
        float sf = 1.f/(1.f+__expf(-gf));
        float so = 1.f/(1.f+__expf(-go));
        float tg = 2.f/(1.f+__expf(-2.f*gg)) - 1.f;
        float cn = sf*c[q*4+r] + si*tg;
        c[q*4+r] = cn;
        float tc = 2.f/(1.f+__expf(-2.f*cn)) - 1.f;
        int m = lg*4 + r;
        int jj = w*32 + q*16 + lm;
        int off = (m*256 + jj) ^ ((m&7)<<3);
        *(unsigned char*)(h_lds + off) = f2fp8(so*tc*16.f);
      }
    prev_t = t;
  }

  asm volatile("s_waitcnt lgkmcnt(0)" ::: "memory");
  __builtin_amdgcn_s_barrier();

  if (k == NCHUNK-1) {
    if (w < 2) {
      long a[8];
      #pragma unroll
      for (int kt = 0; kt < 8; ++kt) {
        int off = (lm*256 + kt*32 + lg*8) ^ ((lm&7)<<3);
        a[kt] = *(const long*)(h_lds + off);
      }
      f32x4 ea = {0.f,0.f,0.f,0.f};
      #pragma unroll
      for (int kt = 0; kt < 8; ++kt) {
        long ew = *(const long*)(we_lds + ((w*8 + kt) << 9) + (l << 3));
        ea = __builtin_amdgcn_mfma_f32_16x16x32_fp8_fp8(a[kt], ew, ea, 0,0,0);
      }
      int cc = w*16 + lm;
      if (cc < NCLS) {
        #pragma unroll
        for (int r = 0; r < 4; ++r)
          emis[((long)prev_t*BATCH + bbase + lg*4 + r)*NCLS + cc] = ea[r]*INV1024;
      }
    }
  } else {
    u32x4* hl = (u32x4*)h_lds;
    u32x4* hs = (u32x4*)(hsave + (long)id*4096);
    if (threadIdx.x < 256) hs[threadIdx.x] = hl[threadIdx.x];
    float* cs = csave + ((long)id*512 + threadIdx.x)*8;
    #pragma unroll
    for (int i = 0; i < 8; ++i) cs[i] = c[i];
  }
}

// ---------------- emissions fuse: emis_c = emis_f + emis_b + b_e ------------
__global__ __launch_bounds__(256) void efuse_kernel(const float* emis_f,
    const float* emis_b, const float* b_e, float* emis_c)
{
  int i = blockIdx.x*256 + threadIdx.x;
  if (i < T_LEN*BATCH*NCLS)
    emis_c[i] = emis_f[i] + emis_b[i] + b_e[i % NCLS];
}

// ---------------- CRF numerator -------------------------------------------
__global__ void num_kernel(const int* sent, const int* tags, const float* emis_c,
    const float* start_t, const float* end_t, const float* trans, float* num_buf)
{
  int b = blockIdx.x, l = threadIdx.x;   // 64 threads = 1 wave
  float acc = 0.f; int cnt = 0;
  for (int t = l; t < T_LEN; t += 64) {
    int tag = tags[t*BATCH + b];
    float E = emis_c[((long)t*BATCH+b)*NCLS + tag];
    int m = (sent[t*BATCH+b] != PADTOK) ? 1 : 0;
    cnt += m;
    if (t == 0) acc += start_t[tag] + E;
    else if (m) acc += trans[tags[(t-1)*BATCH + b]*NCLS + tag] + E;
  }
  #pragma unroll
  for (int off = 32; off; off >>= 1) { acc += __shfl_xor(acc, off); cnt += __shfl_xor(cnt, off); }
  if (l == 0) num_buf[b] = acc + end_t[tags[(cnt-1)*BATCH + b]];
}

// ---- CRF forward (denominator): 2 rows/wave, log2 domain, tree reductions -
__global__ __launch_bounds__(64) void denom_kernel(const int* sent, const float* emis_c,
    const float* start_t, const float* end_t, const float* trans,
    const float* num_buf, float* llh)
{
  const float INVLN2 = 1.4426950408889634f;
  const float LN2 = 0.6931471805599453f;
  int l = threadIdx.x;
  int jq = l & 31;
  int j = (jq < NCLS) ? jq : 0;
  int b = blockIdx.x*2 + (l >> 5);        // 64 blocks, 2 rows/wave
  int laneBase = (l & 32) << 2;           // bpermute source half

  float trc[NCLS];
  #pragma unroll
  for (int i = 0; i < NCLS; ++i) trc[i] = trans[i*NCLS + j] * INVLN2;

  float S = (start_t[j] + emis_c[(long)b*NCLS + j]) * INVLN2;

  float e1 = emis_c[((long)1*BATCH + b)*NCLS + j];
  float e2 = emis_c[((long)2*BATCH + b)*NCLS + j];
  int m1 = sent[1*BATCH + b], m2 = sent[2*BATCH + b];

  for (int t = 1; t < T_LEN; ++t) {
    float e0 = e1; int m0 = m1;
    e1 = e2; m1 = m2;
    if (t + 2 < T_LEN) {
      e2 = emis_c[((long)(t+2)*BATCH + b)*NCLS + j];
      m2 = sent[(t+2)*BATCH + b];
    }
    int Sb = __builtin_bit_cast(int, S);
    float v[NCLS];
    #pragma unroll
    for (int i = 0; i < NCLS; ++i) {
      int sv = __builtin_amdgcn_ds_bpermute(laneBase + i*4, Sb);
      v[i] = __builtin_bit_cast(float, sv) + trc[i];
    }
    // max tree
    float m8[9];
    #pragma unroll
    for (int g = 0; g < 8; ++g) m8[g] = fmaxf(fmaxf(v[3*g], v[3*g+1]), v[3*g+2]);
    m8[8] = v[24];
    float ma = fmaxf(fmaxf(m8[0], m8[1]), m8[2]);
    float mb = fmaxf(fmaxf(m8[3], m8[4]), m8[5]);
    float mc = fmaxf(fmaxf(m8[6], m8[7]), m8[8]);
    float mx = fmaxf(fmaxf(ma, mb), mc);
    // exp2 + sum tree
    float p[NCLS];
    #pragma unroll
    for (int i = 0; i < NCLS; ++i) p[i] = __builtin_amdgcn_exp2f(v[i] - mx);
    #pragma unroll
    for (int i = 0; i < 12; ++i) p[i] += p[i+13];
    #pragma unroll
    for (int i = 0; i < 6; ++i) p[i] += p[i+7];
    #pragma unroll
    for (int i = 0; i < 3; ++i) p[i] += p[i+4];
    p[0] += p[2]; p[1] += p[3];
    p[0] += p[1];
    float nxt = mx + __builtin_amdgcn_logf(p[0]) + e0 * INVLN2;
    if (m0 != PADTOK) S = nxt;
  }

  bool valid = jq < NCLS;
  float vf = valid ? (S + end_t[j] * INVLN2) : -1e30f;
  float mx = vf;
  #pragma unroll
  for (int off = 16; off; off >>= 1) mx = fmaxf(mx, __shfl_xor(mx, off));
  float ss = valid ? __builtin_amdgcn_exp2f(vf - mx) : 0.f;
  #pragma unroll
  for (int off = 16; off; off >>= 1) ss += __shfl_xor(ss, off);
  if (jq == 0) llh[b] = num_buf[b] - (mx + __builtin_amdgcn_logf(ss)) * LN2;
}

__global__ void final_kernel(const float* llh, float* out) {
  __shared__ float red[2];
  int l = threadIdx.x;   // 128
  float v = llh[l];
  #pragma unroll
  for (int off = 32; off; off >>= 1) v += __shfl_xor(v, off);
  if ((l & 63) == 0) red[l >> 6] = v;
  __syncthreads();
  if (l == 0) out[0] = -(red[0] + red[1]);
}

extern "C" void kernel_launch(void* const* d_in, const int* in_sizes, int n_in,
                              void* d_out, int out_size, void* d_ws, size_t ws_size,
                              hipStream_t stream) {
  const int*   sent  = (const int*)d_in[0];
  const int*   tags  = (const int*)d_in[1];
  const float* emb   = (const float*)d_in[2];
  const float* wih_f = (const float*)d_in[3];
  const float* whh_f = (const float*)d_in[4];
  const float* bih_f = (const float*)d_in[5];
  const float* bhh_f = (const float*)d_in[6];
  const float* wih_b = (const float*)d_in[7];
  const float* whh_b = (const float*)d_in[8];
  const float* bih_b = (const float*)d_in[9];
  const float* bhh_b = (const float*)d_in[10];
  const float* W_e   = (const float*)d_in[11];
  const float* b_e   = (const float*)d_in[12];
  const float* st    = (const float*)d_in[13];
  const float* et    = (const float*)d_in[14];
  const float* tr    = (const float*)d_in[15];
  (void)in_sizes; (void)n_in; (void)out_size;

  const long SLOT = (long)2*CHUNK*BATCH*1024*2;   // 32 MiB per xg slot

  char* ws = (char*)d_ws;
  unsigned short* wih_p  = (unsigned short*)ws; ws += (long)N_WPERM*2;      // 1 MiB
  unsigned char*  whh_p  = (unsigned char*)ws;  ws += (long)N_WPERM;        // 512 KiB
  unsigned char*  we_p   = (unsigned char*)ws;  ws += (long)N_WE;           // 16 KiB
  float*          bias   = (float*)ws;          ws += (long)N_BIAS*4;       // 8 KiB
  unsigned short* xgr0   = (unsigned short*)ws; ws += SLOT;                 // 32 MiB
  float*          emis_f = (float*)ws;          ws += (long)T_LEN*BATCH*NCLS*4;
  float*          emis_b = (float*)ws;          ws += (long)T_LEN*BATCH*NCLS*4;
  unsigned char*  hsave  = (unsigned char*)ws;  ws += (long)16*4096;
  float*          csave  = (float*)ws;          ws += (long)16*512*8*4;
  float*          numb   = (float*)ws;          ws += 512;
  float*          llh    = (float*)ws;          ws += 512;
  unsigned short* xgr1   = (unsigned short*)ws; ws += SLOT;                 // 32 MiB (pipelined only)
  float*          emis_c = (float*)xgr0;        // alias: slots dead after last lstm

  bool pipelined = ws_size >= (size_t)((char*)ws - (char*)d_ws);

  prep_kernel<<<4168, 256, 0, stream>>>(wih_f, whh_f, bih_f, bhh_f,
                                        wih_b, whh_b, bih_b, bhh_b, W_e,
                                        wih_p, whh_p, we_p, bias);
  if (pipelined) {
    dim3 g1(256, 2);
    xg_kernel<<<g1, 256, 0, stream>>>(sent, emb, wih_p, bias, xgr0, 0);
    for (int k = 0; k < NCHUNK; ++k) {
      unsigned short* rd = (k & 1) ? xgr1 : xgr0;
      unsigned short* wr = (k & 1) ? xgr0 : xgr1;
      int grid = (k + 1 < NCHUNK) ? 528 : 16;
      fused_kernel<<<grid, 512, 0, stream>>>(sent, emb, wih_p, bias, rd, wr,
                                             whh_p, we_p, emis_f, emis_b, hsave, csave, k);
    }
  } else {
    for (int k = 0; k < NCHUNK; ++k) {
      dim3 g1(256, 2);
      xg_kernel<<<g1, 256, 0, stream>>>(sent, emb, wih_p, bias, xgr0, k);
      fused_kernel<<<16, 512, 0, stream>>>(sent, emb, wih_p, bias, xgr0, xgr0,
                                           whh_p, we_p, emis_f, emis_b, hsave, csave, k);
    }
  }
  efuse_kernel<<<(T_LEN*BATCH*NCLS + 255)/256, 256, 0, stream>>>(emis_f, emis_b, b_e, emis_c);
  num_kernel<<<128, 64, 0, stream>>>(sent, tags, emis_c, st, et, tr, numb);
  denom_kernel<<<64, 64, 0, stream>>>(sent, emis_c, st, et, tr, numb, llh);
  final_kernel<<<1, 128, 0, stream>>>(llh, (float*)d_out);
}

// Round 12
// 1494.058 us; speedup vs baseline: 5.7406x; 1.4626x over previous
//
#include <hip/hip_runtime.h>
#include <hip/hip_bf16.h>
#include <cstdint>

#define T_LEN 512
#define BATCH 128
#define EMBD 256
#define NCLS 25
#define PADTOK 1
#define CHUNK 64
#define NCHUNK 8

#define N_WPERM (2*4*16*8*64*8)   /* 524288: wih bf16 elems / whh fp8 bytes */
#define N_WE (2*2*8*64*8)         /* 16384 fp8 bytes */
#define N_BIAS (2*1024)

typedef float f32x4 __attribute__((ext_vector_type(4)));
typedef short s16x8 __attribute__((ext_vector_type(8)));
typedef unsigned int u32x4 __attribute__((ext_vector_type(4)));

#define INV1024 (0.0009765625f)
#define LOG2E 1.4426950408889634f
#define INV1024_LOG2E (1.4426950408889634f/1024.f)
#define NEG2LOG2E (-2.8853900817779268f)

__device__ __forceinline__ unsigned short f2bf(float f) {
  unsigned int u = __builtin_bit_cast(unsigned int, f);
  unsigned int r = (u + 0x7FFFu + ((u >> 16) & 1u)) >> 16;
  return (unsigned short)r;
}
__device__ __forceinline__ float bf2f(unsigned short h) {
  unsigned int u = ((unsigned int)h) << 16;
  return __builtin_bit_cast(float, u);
}
__device__ __forceinline__ unsigned char f2fp8(float v) {
  int pk = __builtin_amdgcn_cvt_pk_fp8_f32(v, v, 0, false);
  return (unsigned char)(pk & 0xFF);
}
// fast sigmoid/tanh helpers: input already in log2 domain (x2 = x*log2e)
__device__ __forceinline__ float sig2(float x2) {
  return __builtin_amdgcn_rcpf(1.f + __builtin_amdgcn_exp2f(-x2));
}
__device__ __forceinline__ float tanh2(float x2) {   // tanh(x) from x2=x*log2e
  return 2.f*__builtin_amdgcn_rcpf(1.f + __builtin_amdgcn_exp2f(-2.f*x2)) - 1.f;
}

// ---------------- prep: fragment-order weight permutes + bias sum ----------
__global__ void prep_kernel(const float* wih_f, const float* whh_f,
                            const float* bih_f, const float* bhh_f,
                            const float* wih_b, const float* whh_b,
                            const float* bih_b, const float* bhh_b,
                            const float* W_e,
                            unsigned short* wih_p, unsigned char* whh_p,
                            unsigned char* we_p, float* bias)
{
  long total = 2L*N_WPERM + N_WE + N_BIAS;
  for (long i = (long)blockIdx.x*blockDim.x + threadIdx.x; i < total;
       i += (long)gridDim.x*blockDim.x) {
    long j = i;
    if (j < N_WPERM) {           // wih, bf16, 4-wave layout
      int o = (int)j;
      int e = o & 7, l = (o>>3)&63, s = (o>>9)&15, kt = (o>>13)&7, w = (o>>16)&3, d = (o>>18)&1;
      int n = (s>>2)*256 + w*64 + (s&3)*16 + (l & 15);
      int kk = kt*32 + (l>>4)*8 + e;
      const float* src = d ? wih_b : wih_f;
      wih_p[o] = f2bf(src[n*256 + kk]);
      continue;
    }
    j -= N_WPERM;
    if (j < N_WPERM) {           // whh, fp8 scale 64, 8-wave layout
      int o = (int)j;
      int e = o & 7, l = (o>>3)&63, s = (o>>9)&7, kt = (o>>12)&7, w = (o>>15)&7, d = (o>>18)&1;
      int n = (s>>1)*256 + w*32 + (s&1)*16 + (l & 15);
      int kk = kt*32 + (l>>4)*8 + e;
      const float* src = d ? whh_b : whh_f;
      whh_p[o] = f2fp8(src[n*256 + kk] * 64.f);
      continue;
    }
    j -= N_WPERM;
    if (j < N_WE) {              // W_e, fp8 scale 64
      int o = (int)j;
      int e = o&7, l = (o>>3)&63, kt = (o>>9)&7, nt = (o>>12)&1, dp = (o>>13)&1;
      int cc = nt*16 + (l&15);
      int kk = dp*256 + kt*32 + (l>>4)*8 + e;
      we_p[o] = (cc < NCLS) ? f2fp8(W_e[cc*512 + kk] * 64.f) : (unsigned char)0;
      continue;
    }
    j -= N_WE;
    { int o = (int)j; int d = o>>10; int g = o & 1023;
      bias[o] = d ? (bih_b[g]+bhh_b[g]) : (bih_f[g]+bhh_f[g]); }
  }
}

// ------- xg body: (emb[sent] @ W_ih^T + biases) * log2e, permuted bf16 -----
__device__ __forceinline__ void xg_body(const int* sent, const float* emb,
    const unsigned short* wih_p, const float* bias, unsigned short* xg,
    int k, int blk2, int tid)
{
  int d = blk2 >> 8;
  int blk = blk2 & 255;
  int u = blk >> 2, q = blk & 3;
  int ss = k*CHUNK + u;
  int t = d ? (T_LEN-1-ss) : ss;
  int w = tid >> 6, l = tid & 63, lg = l >> 4, lm = l & 15;

  int tok0 = sent[t*BATCH + q*32 + lm];
  int tok1 = sent[t*BATCH + q*32 + 16 + lm];

  const char* wbase = (const char*)wih_p + ((long)(d*4 + w) << 17);

  f32x4 acc[2][16] = {};
  for (int kt = 0; kt < 8; ++kt) {
    const float* p0 = emb + (long)tok0*256 + kt*32 + lg*8;
    const float* p1 = emb + (long)tok1*256 + kt*32 + lg*8;
    f32x4 q00 = *(const f32x4*)p0, q01 = *(const f32x4*)(p0+4);
    f32x4 q10 = *(const f32x4*)p1, q11 = *(const f32x4*)(p1+4);
    s16x8 a0, a1;
    #pragma unroll
    for (int e = 0; e < 4; ++e) {
      a0[e]   = (short)f2bf(q00[e]); a0[4+e] = (short)f2bf(q01[e]);
      a1[e]   = (short)f2bf(q10[e]); a1[4+e] = (short)f2bf(q11[e]);
    }
    #pragma unroll
    for (int s = 0; s < 16; ++s) {
      s16x8 bf = *(const s16x8*)(wbase + (((kt*16 + s) << 10) + (l << 4)));
      acc[0][s] = __builtin_amdgcn_mfma_f32_16x16x32_bf16(a0, bf, acc[0][s], 0,0,0);
      acc[1][s] = __builtin_amdgcn_mfma_f32_16x16x32_bf16(a1, bf, acc[1][s], 0,0,0);
    }
  }
  float bsv[16];
  #pragma unroll
  for (int s = 0; s < 16; ++s) {
    int n = (s>>2)*256 + w*64 + (s&3)*16 + lm;
    bsv[s] = bias[d*1024 + n];
  }
  #pragma unroll
  for (int mt = 0; mt < 2; ++mt) {
    int nb = q*2 + mt;
    char* base = (char*)xg + (((((long)d*CHUNK + u)*8 + nb)*4 + w)*64 + l)*128;
    #pragma unroll
    for (int qq = 0; qq < 8; ++qq) {
      u32x4 pk;
      #pragma unroll
      for (int h2 = 0; h2 < 4; ++h2) {
        int j0 = qq*8 + h2*2;
        unsigned short v0 = f2bf((acc[mt][j0>>2][j0&3] + bsv[j0>>2]) * LOG2E);
        unsigned short v1 = f2bf((acc[mt][(j0+1)>>2][(j0+1)&3] + bsv[(j0+1)>>2]) * LOG2E);
        pk[h2] = (unsigned)v0 | ((unsigned)v1 << 16);
      }
      *(u32x4*)(base + qq*16) = pk;
    }
  }
}

// standalone xg (prologue chunk 0 + sequential fallback)
__global__ __launch_bounds__(256) void xg_kernel(const int* sent, const float* emb,
    const unsigned short* wih_p, const float* bias, unsigned short* xg, int k)
{
  xg_body(sent, emb, wih_p, bias, xg, k, blockIdx.y*256 + blockIdx.x, threadIdx.x);
}

// ---------------- fused: lstm chunk k (blocks 0-15) + xg chunk k+1 ---------
__global__ __launch_bounds__(512, 1) void fused_kernel(
    const int* sent, const float* emb, const unsigned short* wih_p, const float* bias,
    const unsigned short* xg_rd, unsigned short* xg_wr,
    const unsigned char* whh_p, const unsigned char* we_p,
    float* emis_f, float* emis_b, unsigned char* hsave, float* csave, int k)
{
  if (blockIdx.x >= 16) {
    if (threadIdx.x < 256 && k + 1 < NCHUNK)
      xg_body(sent, emb, wih_p, bias, xg_wr, k + 1, blockIdx.x - 16, threadIdx.x);
    return;
  }

  __shared__ char h_lds[4096];     // fp8 h, XOR-swizzled
  __shared__ char we_lds[8192];    // emission weights for this direction

  int id = blockIdx.x, d = id >> 3, nb = id & 7, bbase = nb*16;
  int w = threadIdx.x >> 6, l = threadIdx.x & 63, lg = l >> 4, lm = l & 15;
  float* emis = d ? emis_b : emis_f;
  bool ewave = (w == 0) || (w == 2);   // emission on SIMD0 and SIMD2
  int nt = w >> 1;

  // stage emission weights (8 KB, once)
  ((u32x4*)we_lds)[threadIdx.x] = ((const u32x4*)we_p)[d*512 + threadIdx.x];

  // whole W_hh slice in registers: 64 frags x (8 fp8) = 128 VGPRs
  long wreg[64];
  const char* wbase = (const char*)whh_p + ((long)(d*8 + w) << 15);
  #pragma unroll
  for (int i = 0; i < 64; ++i)
    wreg[i] = *(const long*)(wbase + (i << 9) + (l << 3));

  float c[8];
  if (k == 0) {
    for (int i = threadIdx.x; i < 1024; i += 512) ((unsigned*)h_lds)[i] = 0u;
    #pragma unroll
    for (int i = 0; i < 8; ++i) c[i] = 0.f;
  } else {
    u32x4* hl = (u32x4*)h_lds;
    const u32x4* hs = (const u32x4*)(hsave + (long)id*4096);
    if (threadIdx.x < 256) hl[threadIdx.x] = hs[threadIdx.x];
    const float* cs = csave + ((long)id*512 + threadIdx.x)*8;
    #pragma unroll
    for (int i = 0; i < 8; ++i) c[i] = cs[i];
  }
  __syncthreads();

  int prev_t = (k == 0) ? -1 : (d ? (T_LEN - k*CHUNK) : (k*CHUNK - 1));

  for (int u = 0; u < CHUNK; ++u) {
    int ss = k*CHUNK + u;
    int t = d ? (T_LEN-1-ss) : ss;

    // xg loads issued early; compiler-tracked
    const char* xb = (const char*)xg_rd
        + (((((long)d*CHUNK + u)*8 + nb)*4 + (w>>1))*64 + l)*128 + ((w&1)*16);
    u32x4 xv[4];
    #pragma unroll
    for (int i = 0; i < 4; ++i)
      xv[i] = *(const u32x4*)(xb + i*32);

    asm volatile("s_waitcnt lgkmcnt(0)" ::: "memory");
    __builtin_amdgcn_s_barrier();               // B1: prev h writes visible
    long a[8];
    #pragma unroll
    for (int kt = 0; kt < 8; ++kt) {
      int off = (lm*256 + kt*32 + lg*8) ^ ((lm&7)<<3);
      a[kt] = *(const long*)(h_lds + off);
    }
    asm volatile("s_waitcnt lgkmcnt(0)" ::: "memory");
    __builtin_amdgcn_s_barrier();               // B2: h_lds free for writes

    // emissions MFMA for previous h (waves 0,2 -> SIMD0,SIMD2)
    f32x4 ea = {0.f,0.f,0.f,0.f};
    if (ewave && prev_t >= 0) {
      #pragma unroll
      for (int kt = 0; kt < 8; ++kt) {
        long ew = *(const long*)(we_lds + ((nt*8 + kt) << 9) + (l << 3));
        ea = __builtin_amdgcn_mfma_f32_16x16x32_fp8_fp8(a[kt], ew, ea, 0,0,0);
      }
    }

    // main matvec: all weights in registers
    f32x4 acc[8];
    #pragma unroll
    for (int s = 0; s < 8; ++s) acc[s] = (f32x4){0.f,0.f,0.f,0.f};
    #pragma unroll
    for (int kt = 0; kt < 8; ++kt)
      #pragma unroll
      for (int s = 0; s < 8; ++s)
        acc[s] = __builtin_amdgcn_mfma_f32_16x16x32_fp8_fp8(a[kt], wreg[kt*8+s], acc[s], 0,0,0);

    // emissions store
    if (ewave && prev_t >= 0) {
      int cc = nt*16 + lm;
      if (cc < NCLS) {
        #pragma unroll
        for (int r = 0; r < 4; ++r)
          emis[((long)prev_t*BATCH + bbase + lg*4 + r)*NCLS + cc] = ea[r]*INV1024;
      }
    }

    // xg add; gates emerge in log2 domain (xg pre-scaled by log2e)
    #pragma unroll
    for (int s = 0; s < 8; ++s)
      #pragma unroll
      for (int r = 0; r < 4; ++r) {
        unsigned wd = xv[s>>1][(s&1)*2 + (r>>1)];
        unsigned short us = (r&1) ? (unsigned short)(wd>>16) : (unsigned short)(wd & 0xffff);
        acc[s][r] = acc[s][r]*INV1024_LOG2E + bf2f(us);
      }

    // nonlinearities (log2-domain, hw rcp/exp2): i,f,g,o at s = q,2+q,4+q,6+q
    #pragma unroll
    for (int q = 0; q < 2; ++q)
      #pragma unroll
      for (int r = 0; r < 4; ++r) {
        float si = sig2(acc[q][r]);
        float sf = sig2(acc[2+q][r]);
        float tg = tanh2(acc[4+q][r]);
        float so = sig2(acc[6+q][r]);
        float cn = sf*c[q*4+r] + si*tg;
        c[q*4+r] = cn;
        float tc = 2.f*__builtin_amdgcn_rcpf(1.f + __builtin_amdgcn_exp2f(cn*NEG2LOG2E)) - 1.f;
        int m = lg*4 + r;
        int jj = w*32 + q*16 + lm;
        int off = (m*256 + jj) ^ ((m&7)<<3);
        *(unsigned char*)(h_lds + off) = f2fp8((so*16.f)*tc);
      }
    prev_t = t;
  }

  asm volatile("s_waitcnt lgkmcnt(0)" ::: "memory");
  __builtin_amdgcn_s_barrier();

  if (k == NCHUNK-1) {
    if (ewave) {
      long a[8];
      #pragma unroll
      for (int kt = 0; kt < 8; ++kt) {
        int off = (lm*256 + kt*32 + lg*8) ^ ((lm&7)<<3);
        a[kt] = *(const long*)(h_lds + off);
      }
      f32x4 ea = {0.f,0.f,0.f,0.f};
      #pragma unroll
      for (int kt = 0; kt < 8; ++kt) {
        long ew = *(const long*)(we_lds + ((nt*8 + kt) << 9) + (l << 3));
        ea = __builtin_amdgcn_mfma_f32_16x16x32_fp8_fp8(a[kt], ew, ea, 0,0,0);
      }
      int cc = nt*16 + lm;
      if (cc < NCLS) {
        #pragma unroll
        for (int r = 0; r < 4; ++r)
          emis[((long)prev_t*BATCH + bbase + lg*4 + r)*NCLS + cc] = ea[r]*INV1024;
      }
    }
  } else {
    u32x4* hl = (u32x4*)h_lds;
    u32x4* hs = (u32x4*)(hsave + (long)id*4096);
    if (threadIdx.x < 256) hs[threadIdx.x] = hl[threadIdx.x];
    float* cs = csave + ((long)id*512 + threadIdx.x)*8;
    #pragma unroll
    for (int i = 0; i < 8; ++i) cs[i] = c[i];
  }
}

// ---------------- emissions fuse: emis_c = emis_f + emis_b + b_e ------------
__global__ __launch_bounds__(256) void efuse_kernel(const float* emis_f,
    const float* emis_b, const float* b_e, float* emis_c)
{
  int i = blockIdx.x*256 + threadIdx.x;
  if (i < T_LEN*BATCH*NCLS)
    emis_c[i] = emis_f[i] + emis_b[i] + b_e[i % NCLS];
}

// ---------------- CRF numerator -------------------------------------------
__global__ void num_kernel(const int* sent, const int* tags, const float* emis_c,
    const float* start_t, const float* end_t, const float* trans, float* num_buf)
{
  int b = blockIdx.x, l = threadIdx.x;   // 64 threads = 1 wave
  float acc = 0.f; int cnt = 0;
  for (int t = l; t < T_LEN; t += 64) {
    int tag = tags[t*BATCH + b];
    float E = emis_c[((long)t*BATCH+b)*NCLS + tag];
    int m = (sent[t*BATCH+b] != PADTOK) ? 1 : 0;
    cnt += m;
    if (t == 0) acc += start_t[tag] + E;
    else if (m) acc += trans[tags[(t-1)*BATCH + b]*NCLS + tag] + E;
  }
  #pragma unroll
  for (int off = 32; off; off >>= 1) { acc += __shfl_xor(acc, off); cnt += __shfl_xor(cnt, off); }
  if (l == 0) num_buf[b] = acc + end_t[tags[(cnt-1)*BATCH + b]];
}

// ---- CRF forward (denominator): 2 rows/wave, log2 domain, tree reductions -
__global__ __launch_bounds__(64) void denom_kernel(const int* sent, const float* emis_c,
    const float* start_t, const float* end_t, const float* trans,
    const float* num_buf, float* llh)
{
  const float INVLN2 = 1.4426950408889634f;
  const float LN2 = 0.6931471805599453f;
  int l = threadIdx.x;
  int jq = l & 31;
  int j = (jq < NCLS) ? jq : 0;
  int b = blockIdx.x*2 + (l >> 5);        // 64 blocks, 2 rows/wave
  int laneBase = (l & 32) << 2;           // bpermute source half

  float trc[NCLS];
  #pragma unroll
  for (int i = 0; i < NCLS; ++i) trc[i] = trans[i*NCLS + j] * INVLN2;

  float S = (start_t[j] + emis_c[(long)b*NCLS + j]) * INVLN2;

  float e1 = emis_c[((long)1*BATCH + b)*NCLS + j];
  float e2 = emis_c[((long)2*BATCH + b)*NCLS + j];
  int m1 = sent[1*BATCH + b], m2 = sent[2*BATCH + b];

  for (int t = 1; t < T_LEN; ++t) {
    float e0 = e1; int m0 = m1;
    e1 = e2; m1 = m2;
    if (t + 2 < T_LEN) {
      e2 = emis_c[((long)(t+2)*BATCH + b)*NCLS + j];
      m2 = sent[(t+2)*BATCH + b];
    }
    int Sb = __builtin_bit_cast(int, S);
    float v[NCLS];
    #pragma unroll
    for (int i = 0; i < NCLS; ++i) {
      int sv = __builtin_amdgcn_ds_bpermute(laneBase + i*4, Sb);
      v[i] = __builtin_bit_cast(float, sv) + trc[i];
    }
    // max tree
    float m8[9];
    #pragma unroll
    for (int g = 0; g < 8; ++g) m8[g] = fmaxf(fmaxf(v[3*g], v[3*g+1]), v[3*g+2]);
    m8[8] = v[24];
    float ma = fmaxf(fmaxf(m8[0], m8[1]), m8[2]);
    float mb = fmaxf(fmaxf(m8[3], m8[4]), m8[5]);
    float mc = fmaxf(fmaxf(m8[6], m8[7]), m8[8]);
    float mx = fmaxf(fmaxf(ma, mb), mc);
    // exp2 + sum tree
    float p[NCLS];
    #pragma unroll
    for (int i = 0; i < NCLS; ++i) p[i] = __builtin_amdgcn_exp2f(v[i] - mx);
    #pragma unroll
    for (int i = 0; i < 12; ++i) p[i] += p[i+13];
    #pragma unroll
    for (int i = 0; i < 6; ++i) p[i] += p[i+7];
    #pragma unroll
    for (int i = 0; i < 3; ++i) p[i] += p[i+4];
    p[0] += p[2]; p[1] += p[3];
    p[0] += p[1];
    float nxt = mx + __builtin_amdgcn_logf(p[0]) + e0 * INVLN2;
    if (m0 != PADTOK) S = nxt;
  }

  bool valid = jq < NCLS;
  float vf = valid ? (S + end_t[j] * INVLN2) : -1e30f;
  float mx = vf;
  #pragma unroll
  for (int off = 16; off; off >>= 1) mx = fmaxf(mx, __shfl_xor(mx, off));
  float ss = valid ? __builtin_amdgcn_exp2f(vf - mx) : 0.f;
  #pragma unroll
  for (int off = 16; off; off >>= 1) ss += __shfl_xor(ss, off);
  if (jq == 0) llh[b] = num_buf[b] - (mx + __builtin_amdgcn_logf(ss)) * LN2;
}

__global__ void final_kernel(const float* llh, float* out) {
  __shared__ float red[2];
  int l = threadIdx.x;   // 128
  float v = llh[l];
  #pragma unroll
  for (int off = 32; off; off >>= 1) v += __shfl_xor(v, off);
  if ((l & 63) == 0) red[l >> 6] = v;
  __syncthreads();
  if (l == 0) out[0] = -(red[0] + red[1]);
}

extern "C" void kernel_launch(void* const* d_in, const int* in_sizes, int n_in,
                              void* d_out, int out_size, void* d_ws, size_t ws_size,
                              hipStream_t stream) {
  const int*   sent  = (const int*)d_in[0];
  const int*   tags  = (const int*)d_in[1];
  const float* emb   = (const float*)d_in[2];
  const float* wih_f = (const float*)d_in[3];
  const float* whh_f = (const float*)d_in[4];
  const float* bih_f = (const float*)d_in[5];
  const float* bhh_f = (const float*)d_in[6];
  const float* wih_b = (const float*)d_in[7];
  const float* whh_b = (const float*)d_in[8];
  const float* bih_b = (const float*)d_in[9];
  const float* bhh_b = (const float*)d_in[10];
  const float* W_e   = (const float*)d_in[11];
  const float* b_e   = (const float*)d_in[12];
  const float* st    = (const float*)d_in[13];
  const float* et    = (const float*)d_in[14];
  const float* tr    = (const float*)d_in[15];
  (void)in_sizes; (void)n_in; (void)out_size;

  const long SLOT = (long)2*CHUNK*BATCH*1024*2;   // 32 MiB per xg slot

  char* ws = (char*)d_ws;
  unsigned short* wih_p  = (unsigned short*)ws; ws += (long)N_WPERM*2;      // 1 MiB
  unsigned char*  whh_p  = (unsigned char*)ws;  ws += (long)N_WPERM;        // 512 KiB
  unsigned char*  we_p   = (unsigned char*)ws;  ws += (long)N_WE;           // 16 KiB
  float*          bias   = (float*)ws;          ws += (long)N_BIAS*4;       // 8 KiB
  unsigned short* xgr0   = (unsigned short*)ws; ws += SLOT;                 // 32 MiB
  float*          emis_f = (float*)ws;          ws += (long)T_LEN*BATCH*NCLS*4;
  float*          emis_b = (float*)ws;          ws += (long)T_LEN*BATCH*NCLS*4;
  unsigned char*  hsave  = (unsigned char*)ws;  ws += (long)16*4096;
  float*          csave  = (float*)ws;          ws += (long)16*512*8*4;
  float*          numb   = (float*)ws;          ws += 512;
  float*          llh    = (float*)ws;          ws += 512;
  unsigned short* xgr1   = (unsigned short*)ws; ws += SLOT;                 // 32 MiB (pipelined only)
  float*          emis_c = (float*)xgr0;        // alias: slots dead after last lstm

  bool pipelined = ws_size >= (size_t)((char*)ws - (char*)d_ws);

  prep_kernel<<<4168, 256, 0, stream>>>(wih_f, whh_f, bih_f, bhh_f,
                                        wih_b, whh_b, bih_b, bhh_b, W_e,
                                        wih_p, whh_p, we_p, bias);
  if (pipelined) {
    dim3 g1(256, 2);
    xg_kernel<<<g1, 256, 0, stream>>>(sent, emb, wih_p, bias, xgr0, 0);
    for (int k = 0; k < NCHUNK; ++k) {
      unsigned short* rd = (k & 1) ? xgr1 : xgr0;
      unsigned short* wr = (k & 1) ? xgr0 : xgr1;
      int grid = (k + 1 < NCHUNK) ? 528 : 16;
      fused_kernel<<<grid, 512, 0, stream>>>(sent, emb, wih_p, bias, rd, wr,
                                             whh_p, we_p, emis_f, emis_b, hsave, csave, k);
    }
  } else {
    for (int k = 0; k < NCHUNK; ++k) {
      dim3 g1(256, 2);
      xg_kernel<<<g1, 256, 0, stream>>>(sent, emb, wih_p, bias, xgr0, k);
      fused_kernel<<<16, 512, 0, stream>>>(sent, emb, wih_p, bias, xgr0, xgr0,
                                           whh_p, we_p, emis_f, emis_b, hsave, csave, k);
    }
  }
  efuse_kernel<<<(T_LEN*BATCH*NCLS + 255)/256, 256, 0, stream>>>(emis_f, emis_b, b_e, emis_c);
  num_kernel<<<128, 64, 0, stream>>>(sent, tags, emis_c, st, et, tr, numb);
  denom_kernel<<<64, 64, 0, stream>>>(sent, emis_c, st, et, tr, numb, llh);
  final_kernel<<<1, 128, 0, stream>>>(llh, (float*)d_out);
}

// Round 13
// 1455.060 us; speedup vs baseline: 5.8945x; 1.0268x over previous
//
#include <hip/hip_runtime.h>
#include <hip/hip_bf16.h>
#include <cstdint>

#define T_LEN 512
#define BATCH 128
#define EMBD 256
#define NCLS 25
#define PADTOK 1
#define CHUNK 64
#define NCHUNK 8

#define N_WPERM (2*4*16*8*64*8)   /* 524288: wih bf16 elems / whh fp8 bytes */
#define N_WE (2*2*8*64*8)         /* 16384 fp8 bytes */
#define N_BIAS (2*1024)

typedef float f32x4 __attribute__((ext_vector_type(4)));
typedef short s16x8 __attribute__((ext_vector_type(8)));
typedef unsigned int u32x4 __attribute__((ext_vector_type(4)));

#define INV1024 (0.0009765625f)
#define LOG2E 1.4426950408889634f
#define INV1024_LOG2E (1.4426950408889634f/1024.f)
#define NEG2LOG2E (-2.8853900817779268f)

__device__ __forceinline__ unsigned short f2bf(float f) {
  unsigned int u = __builtin_bit_cast(unsigned int, f);
  unsigned int r = (u + 0x7FFFu + ((u >> 16) & 1u)) >> 16;
  return (unsigned short)r;
}
__device__ __forceinline__ float bf2f(unsigned short h) {
  unsigned int u = ((unsigned int)h) << 16;
  return __builtin_bit_cast(float, u);
}
__device__ __forceinline__ unsigned char f2fp8(float v) {
  int pk = __builtin_amdgcn_cvt_pk_fp8_f32(v, v, 0, false);
  return (unsigned char)(pk & 0xFF);
}
// fast sigmoid/tanh helpers: input already in log2 domain (x2 = x*log2e)
__device__ __forceinline__ float sig2(float x2) {
  return __builtin_amdgcn_rcpf(1.f + __builtin_amdgcn_exp2f(-x2));
}
__device__ __forceinline__ float tanh2(float x2) {   // tanh(x) from x2=x*log2e
  return 2.f*__builtin_amdgcn_rcpf(1.f + __builtin_amdgcn_exp2f(-2.f*x2)) - 1.f;
}

// ---------------- prep: fragment-order weight permutes + bias sum ----------
__global__ void prep_kernel(const float* wih_f, const float* whh_f,
                            const float* bih_f, const float* bhh_f,
                            const float* wih_b, const float* whh_b,
                            const float* bih_b, const float* bhh_b,
                            const float* W_e,
                            unsigned short* wih_p, unsigned char* whh_p,
                            unsigned char* we_p, float* bias)
{
  long total = 2L*N_WPERM + N_WE + N_BIAS;
  for (long i = (long)blockIdx.x*blockDim.x + threadIdx.x; i < total;
       i += (long)gridDim.x*blockDim.x) {
    long j = i;
    if (j < N_WPERM) {           // wih, bf16, 4-wave layout
      int o = (int)j;
      int e = o & 7, l = (o>>3)&63, s = (o>>9)&15, kt = (o>>13)&7, w = (o>>16)&3, d = (o>>18)&1;
      int n = (s>>2)*256 + w*64 + (s&3)*16 + (l & 15);
      int kk = kt*32 + (l>>4)*8 + e;
      const float* src = d ? wih_b : wih_f;
      wih_p[o] = f2bf(src[n*256 + kk]);
      continue;
    }
    j -= N_WPERM;
    if (j < N_WPERM) {           // whh, fp8 scale 64, 8-wave layout
      int o = (int)j;
      int e = o & 7, l = (o>>3)&63, s = (o>>9)&7, kt = (o>>12)&7, w = (o>>15)&7, d = (o>>18)&1;
      int n = (s>>1)*256 + w*32 + (s&1)*16 + (l & 15);
      int kk = kt*32 + (l>>4)*8 + e;
      const float* src = d ? whh_b : whh_f;
      whh_p[o] = f2fp8(src[n*256 + kk] * 64.f);
      continue;
    }
    j -= N_WPERM;
    if (j < N_WE) {              // W_e, fp8 scale 64
      int o = (int)j;
      int e = o&7, l = (o>>3)&63, kt = (o>>9)&7, nt = (o>>12)&1, dp = (o>>13)&1;
      int cc = nt*16 + (l&15);
      int kk = dp*256 + kt*32 + (l>>4)*8 + e;
      we_p[o] = (cc < NCLS) ? f2fp8(W_e[cc*512 + kk] * 64.f) : (unsigned char)0;
      continue;
    }
    j -= N_WE;
    { int o = (int)j; int d = o>>10; int g = o & 1023;
      bias[o] = d ? (bih_b[g]+bhh_b[g]) : (bih_f[g]+bhh_f[g]); }
  }
}

// ------- xg body: (emb[sent] @ W_ih^T + biases) * log2e, permuted bf16 -----
__device__ __forceinline__ void xg_body(const int* sent, const float* emb,
    const unsigned short* wih_p, const float* bias, unsigned short* xg,
    int k, int blk2, int tid)
{
  int d = blk2 >> 8;
  int blk = blk2 & 255;
  int u = blk >> 2, q = blk & 3;
  int ss = k*CHUNK + u;
  int t = d ? (T_LEN-1-ss) : ss;
  int w = tid >> 6, l = tid & 63, lg = l >> 4, lm = l & 15;

  int tok0 = sent[t*BATCH + q*32 + lm];
  int tok1 = sent[t*BATCH + q*32 + 16 + lm];

  const char* wbase = (const char*)wih_p + ((long)(d*4 + w) << 17);

  f32x4 acc[2][16] = {};
  for (int kt = 0; kt < 8; ++kt) {
    const float* p0 = emb + (long)tok0*256 + kt*32 + lg*8;
    const float* p1 = emb + (long)tok1*256 + kt*32 + lg*8;
    f32x4 q00 = *(const f32x4*)p0, q01 = *(const f32x4*)(p0+4);
    f32x4 q10 = *(const f32x4*)p1, q11 = *(const f32x4*)(p1+4);
    s16x8 a0, a1;
    #pragma unroll
    for (int e = 0; e < 4; ++e) {
      a0[e]   = (short)f2bf(q00[e]); a0[4+e] = (short)f2bf(q01[e]);
      a1[e]   = (short)f2bf(q10[e]); a1[4+e] = (short)f2bf(q11[e]);
    }
    #pragma unroll
    for (int s = 0; s < 16; ++s) {
      s16x8 bf = *(const s16x8*)(wbase + (((kt*16 + s) << 10) + (l << 4)));
      acc[0][s] = __builtin_amdgcn_mfma_f32_16x16x32_bf16(a0, bf, acc[0][s], 0,0,0);
      acc[1][s] = __builtin_amdgcn_mfma_f32_16x16x32_bf16(a1, bf, acc[1][s], 0,0,0);
    }
  }
  float bsv[16];
  #pragma unroll
  for (int s = 0; s < 16; ++s) {
    int n = (s>>2)*256 + w*64 + (s&3)*16 + lm;
    bsv[s] = bias[d*1024 + n];
  }
  #pragma unroll
  for (int mt = 0; mt < 2; ++mt) {
    int nb = q*2 + mt;
    char* base = (char*)xg + (((((long)d*CHUNK + u)*8 + nb)*4 + w)*64 + l)*128;
    #pragma unroll
    for (int qq = 0; qq < 8; ++qq) {
      u32x4 pk;
      #pragma unroll
      for (int h2 = 0; h2 < 4; ++h2) {
        int j0 = qq*8 + h2*2;
        unsigned short v0 = f2bf((acc[mt][j0>>2][j0&3] + bsv[j0>>2]) * LOG2E);
        unsigned short v1 = f2bf((acc[mt][(j0+1)>>2][(j0+1)&3] + bsv[(j0+1)>>2]) * LOG2E);
        pk[h2] = (unsigned)v0 | ((unsigned)v1 << 16);
      }
      *(u32x4*)(base + qq*16) = pk;
    }
  }
}

// standalone xg (prologue chunk 0 + sequential fallback)
__global__ __launch_bounds__(256) void xg_kernel(const int* sent, const float* emb,
    const unsigned short* wih_p, const float* bias, unsigned short* xg, int k)
{
  xg_body(sent, emb, wih_p, bias, xg, k, blockIdx.y*256 + blockIdx.x, threadIdx.x);
}

// ---------------- fused: lstm chunk k (blocks 0-15) + xg chunk k+1 ---------
__global__ __launch_bounds__(512, 1) void fused_kernel(
    const int* sent, const float* emb, const unsigned short* wih_p, const float* bias,
    const unsigned short* xg_rd, unsigned short* xg_wr,
    const unsigned char* whh_p, const unsigned char* we_p,
    float* emis_f, float* emis_b, unsigned char* hsave, float* csave, int k)
{
  if (blockIdx.x >= 16) {
    if (threadIdx.x < 256 && k + 1 < NCHUNK)
      xg_body(sent, emb, wih_p, bias, xg_wr, k + 1, blockIdx.x - 16, threadIdx.x);
    return;
  }

  __shared__ char h_lds[4096];     // fp8 h, XOR-swizzled
  __shared__ char we_lds[8192];    // emission weights for this direction

  int id = blockIdx.x, d = id >> 3, nb = id & 7, bbase = nb*16;
  int w = threadIdx.x >> 6, l = threadIdx.x & 63, lg = l >> 4, lm = l & 15;
  float* emis = d ? emis_b : emis_f;
  bool ewave = (w == 0) || (w == 2);   // emission on SIMD0 and SIMD2
  int nt = w >> 1;

  // stage emission weights (8 KB, once)
  ((u32x4*)we_lds)[threadIdx.x] = ((const u32x4*)we_p)[d*512 + threadIdx.x];

  // whole W_hh slice in registers: 64 frags x (8 fp8) = 128 VGPRs
  long wreg[64];
  const char* wbase = (const char*)whh_p + ((long)(d*8 + w) << 15);
  #pragma unroll
  for (int i = 0; i < 64; ++i)
    wreg[i] = *(const long*)(wbase + (i << 9) + (l << 3));

  float c[8];
  if (k == 0) {
    for (int i = threadIdx.x; i < 1024; i += 512) ((unsigned*)h_lds)[i] = 0u;
    #pragma unroll
    for (int i = 0; i < 8; ++i) c[i] = 0.f;
  } else {
    u32x4* hl = (u32x4*)h_lds;
    const u32x4* hs = (const u32x4*)(hsave + (long)id*4096);
    if (threadIdx.x < 256) hl[threadIdx.x] = hs[threadIdx.x];
    const float* cs = csave + ((long)id*512 + threadIdx.x)*8;
    #pragma unroll
    for (int i = 0; i < 8; ++i) c[i] = cs[i];
  }
  __syncthreads();

  int prev_t = (k == 0) ? -1 : (d ? (T_LEN - k*CHUNK) : (k*CHUNK - 1));

  for (int u = 0; u < CHUNK; ++u) {
    int ss = k*CHUNK + u;
    int t = d ? (T_LEN-1-ss) : ss;

    // xg loads issued early; compiler-tracked
    const char* xb = (const char*)xg_rd
        + (((((long)d*CHUNK + u)*8 + nb)*4 + (w>>1))*64 + l)*128 + ((w&1)*16);
    u32x4 xv[4];
    #pragma unroll
    for (int i = 0; i < 4; ++i)
      xv[i] = *(const u32x4*)(xb + i*32);

    asm volatile("s_waitcnt lgkmcnt(0)" ::: "memory");
    __builtin_amdgcn_s_barrier();               // B1: prev h writes visible
    long a[8];
    #pragma unroll
    for (int kt = 0; kt < 8; ++kt) {
      int off = (lm*256 + kt*32 + lg*8) ^ ((lm&7)<<3);
      a[kt] = *(const long*)(h_lds + off);
    }
    asm volatile("s_waitcnt lgkmcnt(0)" ::: "memory");
    __builtin_amdgcn_s_barrier();               // B2: h_lds free for writes

    // emissions MFMA for previous h (waves 0,2 -> SIMD0,SIMD2)
    f32x4 ea = {0.f,0.f,0.f,0.f};
    if (ewave && prev_t >= 0) {
      #pragma unroll
      for (int kt = 0; kt < 8; ++kt) {
        long ew = *(const long*)(we_lds + ((nt*8 + kt) << 9) + (l << 3));
        ea = __builtin_amdgcn_mfma_f32_16x16x32_fp8_fp8(a[kt], ew, ea, 0,0,0);
      }
    }

    // main matvec: all weights in registers
    f32x4 acc[8];
    #pragma unroll
    for (int s = 0; s < 8; ++s) acc[s] = (f32x4){0.f,0.f,0.f,0.f};
    #pragma unroll
    for (int kt = 0; kt < 8; ++kt)
      #pragma unroll
      for (int s = 0; s < 8; ++s)
        acc[s] = __builtin_amdgcn_mfma_f32_16x16x32_fp8_fp8(a[kt], wreg[kt*8+s], acc[s], 0,0,0);

    // emissions store
    if (ewave && prev_t >= 0) {
      int cc = nt*16 + lm;
      if (cc < NCLS) {
        #pragma unroll
        for (int r = 0; r < 4; ++r)
          emis[((long)prev_t*BATCH + bbase + lg*4 + r)*NCLS + cc] = ea[r]*INV1024;
      }
    }

    // xg add; gates emerge in log2 domain (xg pre-scaled by log2e)
    #pragma unroll
    for (int s = 0; s < 8; ++s)
      #pragma unroll
      for (int r = 0; r < 4; ++r) {
        unsigned wd = xv[s>>1][(s&1)*2 + (r>>1)];
        unsigned short us = (r&1) ? (unsigned short)(wd>>16) : (unsigned short)(wd & 0xffff);
        acc[s][r] = acc[s][r]*INV1024_LOG2E + bf2f(us);
      }

    // nonlinearities (log2-domain, hw rcp/exp2): i,f,g,o at s = q,2+q,4+q,6+q
    #pragma unroll
    for (int q = 0; q < 2; ++q)
      #pragma unroll
      for (int r = 0; r < 4; ++r) {
        float si = sig2(acc[q][r]);
        float sf = sig2(acc[2+q][r]);
        float tg = tanh2(acc[4+q][r]);
        float so = sig2(acc[6+q][r]);
        float cn = sf*c[q*4+r] + si*tg;
        c[q*4+r] = cn;
        float tc = 2.f*__builtin_amdgcn_rcpf(1.f + __builtin_amdgcn_exp2f(cn*NEG2LOG2E)) - 1.f;
        int m = lg*4 + r;
        int jj = w*32 + q*16 + lm;
        int off = (m*256 + jj) ^ ((m&7)<<3);
        *(unsigned char*)(h_lds + off) = f2fp8((so*16.f)*tc);
      }
    prev_t = t;
  }

  asm volatile("s_waitcnt lgkmcnt(0)" ::: "memory");
  __builtin_amdgcn_s_barrier();

  if (k == NCHUNK-1) {
    if (ewave) {
      long a[8];
      #pragma unroll
      for (int kt = 0; kt < 8; ++kt) {
        int off = (lm*256 + kt*32 + lg*8) ^ ((lm&7)<<3);
        a[kt] = *(const long*)(h_lds + off);
      }
      f32x4 ea = {0.f,0.f,0.f,0.f};
      #pragma unroll
      for (int kt = 0; kt < 8; ++kt) {
        long ew = *(const long*)(we_lds + ((nt*8 + kt) << 9) + (l << 3));
        ea = __builtin_amdgcn_mfma_f32_16x16x32_fp8_fp8(a[kt], ew, ea, 0,0,0);
      }
      int cc = nt*16 + lm;
      if (cc < NCLS) {
        #pragma unroll
        for (int r = 0; r < 4; ++r)
          emis[((long)prev_t*BATCH + bbase + lg*4 + r)*NCLS + cc] = ea[r]*INV1024;
      }
    }
  } else {
    u32x4* hl = (u32x4*)h_lds;
    u32x4* hs = (u32x4*)(hsave + (long)id*4096);
    if (threadIdx.x < 256) hs[threadIdx.x] = hl[threadIdx.x];
    float* cs = csave + ((long)id*512 + threadIdx.x)*8;
    #pragma unroll
    for (int i = 0; i < 8; ++i) cs[i] = c[i];
  }
}

// ---------------- emissions fuse: emis_c = emis_f + emis_b + b_e ------------
__global__ __launch_bounds__(256) void efuse_kernel(const float* emis_f,
    const float* emis_b, const float* b_e, float* emis_c)
{
  int i = blockIdx.x*256 + threadIdx.x;
  if (i < T_LEN*BATCH*NCLS)
    emis_c[i] = emis_f[i] + emis_b[i] + b_e[i % NCLS];
}

// ---------------- CRF numerator -------------------------------------------
__global__ void num_kernel(const int* sent, const int* tags, const float* emis_c,
    const float* start_t, const float* end_t, const float* trans, float* num_buf)
{
  int b = blockIdx.x, l = threadIdx.x;   // 64 threads = 1 wave
  float acc = 0.f; int cnt = 0;
  for (int t = l; t < T_LEN; t += 64) {
    int tag = tags[t*BATCH + b];
    float E = emis_c[((long)t*BATCH+b)*NCLS + tag];
    int m = (sent[t*BATCH+b] != PADTOK) ? 1 : 0;
    cnt += m;
    if (t == 0) acc += start_t[tag] + E;
    else if (m) acc += trans[tags[(t-1)*BATCH + b]*NCLS + tag] + E;
  }
  #pragma unroll
  for (int off = 32; off; off >>= 1) { acc += __shfl_xor(acc, off); cnt += __shfl_xor(cnt, off); }
  if (l == 0) num_buf[b] = acc + end_t[tags[(cnt-1)*BATCH + b]];
}

// ---- CRF forward (denominator): q-broadcast form --------------------------
// nxt_j = Smax + log2( sum_i exp2(S_i - Smax) * E_ij ),  E_ij = exp2(T_ij*log2e)
// E held in 25 regs; one exp2 per step per lane (vs 25), then bpermute of q.
__global__ __launch_bounds__(64) void denom_kernel(const int* sent, const float* emis_c,
    const float* start_t, const float* end_t, const float* trans,
    const float* num_buf, float* llh)
{
  const float INVLN2 = 1.4426950408889634f;
  const float LN2 = 0.6931471805599453f;
  int l = threadIdx.x;
  int jq = l & 31;
  bool valid = jq < NCLS;
  int j = valid ? jq : 0;
  int b = blockIdx.x*2 + (l >> 5);        // 64 blocks, 2 rows/wave
  int laneBase = (l & 32) << 2;           // bpermute source half

  float etr[NCLS];                         // E column j, linear domain
  #pragma unroll
  for (int i = 0; i < NCLS; ++i)
    etr[i] = __builtin_amdgcn_exp2f(trans[i*NCLS + j] * INVLN2);

  float S = (start_t[j] + emis_c[(long)b*NCLS + j]) * INVLN2;

  float e1 = emis_c[((long)1*BATCH + b)*NCLS + j];
  float e2 = emis_c[((long)2*BATCH + b)*NCLS + j];
  int m1 = sent[1*BATCH + b], m2 = sent[2*BATCH + b];

  for (int t = 1; t < T_LEN; ++t) {
    float e0 = e1; int m0 = m1;
    e1 = e2; m1 = m2;
    if (t + 2 < T_LEN) {
      e2 = emis_c[((long)(t+2)*BATCH + b)*NCLS + j];
      m2 = sent[(t+2)*BATCH + b];
    }
    // Smax over the 25 valid lanes of this half (xor tree stays in half)
    float sm = valid ? S : -1e30f;
    #pragma unroll
    for (int off = 16; off; off >>= 1) sm = fmaxf(sm, __shfl_xor(sm, off));
    // q = exp2(S - Smax), broadcast, dot with E column
    float qv = __builtin_amdgcn_exp2f(S - sm);
    int qb = __builtin_bit_cast(int, qv);
    float accs[5] = {0.f, 0.f, 0.f, 0.f, 0.f};
    #pragma unroll
    for (int i = 0; i < NCLS; ++i) {
      float qi = __builtin_bit_cast(float,
          __builtin_amdgcn_ds_bpermute(laneBase + i*4, qb));
      accs[i % 5] = fmaf(qi, etr[i], accs[i % 5]);
    }
    float dot = ((accs[0] + accs[1]) + (accs[2] + accs[3])) + accs[4];
    float nxt = sm + __builtin_amdgcn_logf(dot) + e0 * INVLN2;
    if (m0 != PADTOK) S = nxt;
  }

  float vf = valid ? (S + end_t[j] * INVLN2) : -1e30f;
  float mx = vf;
  #pragma unroll
  for (int off = 16; off; off >>= 1) mx = fmaxf(mx, __shfl_xor(mx, off));
  float ss = valid ? __builtin_amdgcn_exp2f(vf - mx) : 0.f;
  #pragma unroll
  for (int off = 16; off; off >>= 1) ss += __shfl_xor(ss, off);
  if (jq == 0) llh[b] = num_buf[b] - (mx + __builtin_amdgcn_logf(ss)) * LN2;
}

__global__ void final_kernel(const float* llh, float* out) {
  __shared__ float red[2];
  int l = threadIdx.x;   // 128
  float v = llh[l];
  #pragma unroll
  for (int off = 32; off; off >>= 1) v += __shfl_xor(v, off);
  if ((l & 63) == 0) red[l >> 6] = v;
  __syncthreads();
  if (l == 0) out[0] = -(red[0] + red[1]);
}

extern "C" void kernel_launch(void* const* d_in, const int* in_sizes, int n_in,
                              void* d_out, int out_size, void* d_ws, size_t ws_size,
                              hipStream_t stream) {
  const int*   sent  = (const int*)d_in[0];
  const int*   tags  = (const int*)d_in[1];
  const float* emb   = (const float*)d_in[2];
  const float* wih_f = (const float*)d_in[3];
  const float* whh_f = (const float*)d_in[4];
  const float* bih_f = (const float*)d_in[5];
  const float* bhh_f = (const float*)d_in[6];
  const float* wih_b = (const float*)d_in[7];
  const float* whh_b = (const float*)d_in[8];
  const float* bih_b = (const float*)d_in[9];
  const float* bhh_b = (const float*)d_in[10];
  const float* W_e   = (const float*)d_in[11];
  const float* b_e   = (const float*)d_in[12];
  const float* st    = (const float*)d_in[13];
  const float* et    = (const float*)d_in[14];
  const float* tr    = (const float*)d_in[15];
  (void)in_sizes; (void)n_in; (void)out_size;

  const long SLOT = (long)2*CHUNK*BATCH*1024*2;   // 32 MiB per xg slot

  char* ws = (char*)d_ws;
  unsigned short* wih_p  = (unsigned short*)ws; ws += (long)N_WPERM*2;      // 1 MiB
  unsigned char*  whh_p  = (unsigned char*)ws;  ws += (long)N_WPERM;        // 512 KiB
  unsigned char*  we_p   = (unsigned char*)ws;  ws += (long)N_WE;           // 16 KiB
  float*          bias   = (float*)ws;          ws += (long)N_BIAS*4;       // 8 KiB
  unsigned short* xgr0   = (unsigned short*)ws; ws += SLOT;                 // 32 MiB
  float*          emis_f = (float*)ws;          ws += (long)T_LEN*BATCH*NCLS*4;
  float*          emis_b = (float*)ws;          ws += (long)T_LEN*BATCH*NCLS*4;
  unsigned char*  hsave  = (unsigned char*)ws;  ws += (long)16*4096;
  float*          csave  = (float*)ws;          ws += (long)16*512*8*4;
  float*          numb   = (float*)ws;          ws += 512;
  float*          llh    = (float*)ws;          ws += 512;
  unsigned short* xgr1   = (unsigned short*)ws; ws += SLOT;                 // 32 MiB (pipelined only)
  float*          emis_c = (float*)xgr0;        // alias: slots dead after last lstm

  bool pipelined = ws_size >= (size_t)((char*)ws - (char*)d_ws);

  prep_kernel<<<4168, 256, 0, stream>>>(wih_f, whh_f, bih_f, bhh_f,
                                        wih_b, whh_b, bih_b, bhh_b, W_e,
                                        wih_p, whh_p, we_p, bias);
  if (pipelined) {
    dim3 g1(256, 2);
    xg_kernel<<<g1, 256, 0, stream>>>(sent, emb, wih_p, bias, xgr0, 0);
    for (int k = 0; k < NCHUNK; ++k) {
      unsigned short* rd = (k & 1) ? xgr1 : xgr0;
      unsigned short* wr = (k & 1) ? xgr0 : xgr1;
      int grid = (k + 1 < NCHUNK) ? 528 : 16;
      fused_kernel<<<grid, 512, 0, stream>>>(sent, emb, wih_p, bias, rd, wr,
                                             whh_p, we_p, emis_f, emis_b, hsave, csave, k);
    }
  } else {
    for (int k = 0; k < NCHUNK; ++k) {
      dim3 g1(256, 2);
      xg_kernel<<<g1, 256, 0, stream>>>(sent, emb, wih_p, bias, xgr0, k);
      fused_kernel<<<16, 512, 0, stream>>>(sent, emb, wih_p, bias, xgr0, xgr0,
                                           whh_p, we_p, emis_f, emis_b, hsave, csave, k);
    }
  }
  efuse_kernel<<<(T_LEN*BATCH*NCLS + 255)/256, 256, 0, stream>>>(emis_f, emis_b, b_e, emis_c);
  num_kernel<<<128, 64, 0, stream>>>(sent, tags, emis_c, st, et, tr, numb);
  denom_kernel<<<64, 64, 0, stream>>>(sent, emis_c, st, et, tr, numb, llh);
  final_kernel<<<1, 128, 0, stream>>>(llh, (float*)d_out);
}

// Round 14
// 1395.800 us; speedup vs baseline: 6.1447x; 1.0425x over previous
//
#include <hip/hip_runtime.h>
#include <hip/hip_bf16.h>
#include <cstdint>

#define T_LEN 512
#define BATCH 128
#define EMBD 256
#define NCLS 25
#define PADTOK 1
#define CHUNK 64
#define NCHUNK 8

#define N_WPERM (2*4*16*8*64*8)   /* 524288: wih bf16 elems / whh fp8 bytes */
#define N_WE (2*2*8*64*8)         /* 16384 fp8 bytes */
#define N_BIAS (2*1024)

typedef float f32x4 __attribute__((ext_vector_type(4)));
typedef short s16x8 __attribute__((ext_vector_type(8)));
typedef unsigned int u32x4 __attribute__((ext_vector_type(4)));

#define INV1024 (0.0009765625f)
#define LOG2E 1.4426950408889634f
#define INV1024_LOG2E (1.4426950408889634f/1024.f)
#define NEG2LOG2E (-2.8853900817779268f)

__device__ __forceinline__ unsigned short f2bf(float f) {
  unsigned int u = __builtin_bit_cast(unsigned int, f);
  unsigned int r = (u + 0x7FFFu + ((u >> 16) & 1u)) >> 16;
  return (unsigned short)r;
}
__device__ __forceinline__ float bf2f(unsigned short h) {
  unsigned int u = ((unsigned int)h) << 16;
  return __builtin_bit_cast(float, u);
}
__device__ __forceinline__ unsigned char f2fp8(float v) {
  int pk = __builtin_amdgcn_cvt_pk_fp8_f32(v, v, 0, false);
  return (unsigned char)(pk & 0xFF);
}
// fast sigmoid/tanh helpers: input already in log2 domain (x2 = x*log2e)
__device__ __forceinline__ float sig2(float x2) {
  return __builtin_amdgcn_rcpf(1.f + __builtin_amdgcn_exp2f(-x2));
}
__device__ __forceinline__ float tanh2(float x2) {   // tanh(x) from x2=x*log2e
  return 2.f*__builtin_amdgcn_rcpf(1.f + __builtin_amdgcn_exp2f(-2.f*x2)) - 1.f;
}

// ---------------- prep: fragment-order weight permutes + bias sum ----------
__global__ void prep_kernel(const float* wih_f, const float* whh_f,
                            const float* bih_f, const float* bhh_f,
                            const float* wih_b, const float* whh_b,
                            const float* bih_b, const float* bhh_b,
                            const float* W_e,
                            unsigned short* wih_p, unsigned char* whh_p,
                            unsigned char* we_p, float* bias)
{
  long total = 2L*N_WPERM + N_WE + N_BIAS;
  for (long i = (long)blockIdx.x*blockDim.x + threadIdx.x; i < total;
       i += (long)gridDim.x*blockDim.x) {
    long j = i;
    if (j < N_WPERM) {           // wih, bf16, 4-wave layout
      int o = (int)j;
      int e = o & 7, l = (o>>3)&63, s = (o>>9)&15, kt = (o>>13)&7, w = (o>>16)&3, d = (o>>18)&1;
      int n = (s>>2)*256 + w*64 + (s&3)*16 + (l & 15);
      int kk = kt*32 + (l>>4)*8 + e;
      const float* src = d ? wih_b : wih_f;
      wih_p[o] = f2bf(src[n*256 + kk]);
      continue;
    }
    j -= N_WPERM;
    if (j < N_WPERM) {           // whh, fp8 scale 64, 8-wave layout
      int o = (int)j;
      int e = o & 7, l = (o>>3)&63, s = (o>>9)&7, kt = (o>>12)&7, w = (o>>15)&7, d = (o>>18)&1;
      int n = (s>>1)*256 + w*32 + (s&1)*16 + (l & 15);
      int kk = kt*32 + (l>>4)*8 + e;
      const float* src = d ? whh_b : whh_f;
      whh_p[o] = f2fp8(src[n*256 + kk] * 64.f);
      continue;
    }
    j -= N_WPERM;
    if (j < N_WE) {              // W_e, fp8 scale 64
      int o = (int)j;
      int e = o&7, l = (o>>3)&63, kt = (o>>9)&7, nt = (o>>12)&1, dp = (o>>13)&1;
      int cc = nt*16 + (l&15);
      int kk = dp*256 + kt*32 + (l>>4)*8 + e;
      we_p[o] = (cc < NCLS) ? f2fp8(W_e[cc*512 + kk] * 64.f) : (unsigned char)0;
      continue;
    }
    j -= N_WE;
    { int o = (int)j; int d = o>>10; int g = o & 1023;
      bias[o] = d ? (bih_b[g]+bhh_b[g]) : (bih_f[g]+bhh_f[g]); }
  }
}

// ------- xg body: (emb[sent] @ W_ih^T + biases) * log2e, permuted bf16 -----
__device__ __forceinline__ void xg_body(const int* sent, const float* emb,
    const unsigned short* wih_p, const float* bias, unsigned short* xg,
    int k, int blk2, int tid)
{
  int d = blk2 >> 8;
  int blk = blk2 & 255;
  int u = blk >> 2, q = blk & 3;
  int ss = k*CHUNK + u;
  int t = d ? (T_LEN-1-ss) : ss;
  int w = tid >> 6, l = tid & 63, lg = l >> 4, lm = l & 15;

  int tok0 = sent[t*BATCH + q*32 + lm];
  int tok1 = sent[t*BATCH + q*32 + 16 + lm];

  const char* wbase = (const char*)wih_p + ((long)(d*4 + w) << 17);

  f32x4 acc[2][16] = {};
  for (int kt = 0; kt < 8; ++kt) {
    const float* p0 = emb + (long)tok0*256 + kt*32 + lg*8;
    const float* p1 = emb + (long)tok1*256 + kt*32 + lg*8;
    f32x4 q00 = *(const f32x4*)p0, q01 = *(const f32x4*)(p0+4);
    f32x4 q10 = *(const f32x4*)p1, q11 = *(const f32x4*)(p1+4);
    s16x8 a0, a1;
    #pragma unroll
    for (int e = 0; e < 4; ++e) {
      a0[e]   = (short)f2bf(q00[e]); a0[4+e] = (short)f2bf(q01[e]);
      a1[e]   = (short)f2bf(q10[e]); a1[4+e] = (short)f2bf(q11[e]);
    }
    #pragma unroll
    for (int s = 0; s < 16; ++s) {
      s16x8 bf = *(const s16x8*)(wbase + (((kt*16 + s) << 10) + (l << 4)));
      acc[0][s] = __builtin_amdgcn_mfma_f32_16x16x32_bf16(a0, bf, acc[0][s], 0,0,0);
      acc[1][s] = __builtin_amdgcn_mfma_f32_16x16x32_bf16(a1, bf, acc[1][s], 0,0,0);
    }
  }
  float bsv[16];
  #pragma unroll
  for (int s = 0; s < 16; ++s) {
    int n = (s>>2)*256 + w*64 + (s&3)*16 + lm;
    bsv[s] = bias[d*1024 + n];
  }
  #pragma unroll
  for (int mt = 0; mt < 2; ++mt) {
    int nb = q*2 + mt;
    char* base = (char*)xg + (((((long)d*CHUNK + u)*8 + nb)*4 + w)*64 + l)*128;
    #pragma unroll
    for (int qq = 0; qq < 8; ++qq) {
      u32x4 pk;
      #pragma unroll
      for (int h2 = 0; h2 < 4; ++h2) {
        int j0 = qq*8 + h2*2;
        unsigned short v0 = f2bf((acc[mt][j0>>2][j0&3] + bsv[j0>>2]) * LOG2E);
        unsigned short v1 = f2bf((acc[mt][(j0+1)>>2][(j0+1)&3] + bsv[(j0+1)>>2]) * LOG2E);
        pk[h2] = (unsigned)v0 | ((unsigned)v1 << 16);
      }
      *(u32x4*)(base + qq*16) = pk;
    }
  }
}

// standalone xg (prologue chunk 0 + sequential fallback)
__global__ __launch_bounds__(256) void xg_kernel(const int* sent, const float* emb,
    const unsigned short* wih_p, const float* bias, unsigned short* xg, int k)
{
  xg_body(sent, emb, wih_p, bias, xg, k, blockIdx.y*256 + blockIdx.x, threadIdx.x);
}

// ---------------- fused: lstm chunk k (blocks 0-15) + xg chunk k+1 ---------
__global__ __launch_bounds__(512, 1) void fused_kernel(
    const int* sent, const float* emb, const unsigned short* wih_p, const float* bias,
    const unsigned short* xg_rd, unsigned short* xg_wr,
    const unsigned char* whh_p, const unsigned char* we_p,
    float* emis_f, float* emis_b, unsigned char* hsave, float* csave, int k)
{
  if (blockIdx.x >= 16) {
    if (threadIdx.x < 256 && k + 1 < NCHUNK)
      xg_body(sent, emb, wih_p, bias, xg_wr, k + 1, blockIdx.x - 16, threadIdx.x);
    return;
  }

  __shared__ char h_lds[4096];     // fp8 h, XOR-swizzled
  __shared__ char we_lds[8192];    // emission weights for this direction

  int id = blockIdx.x, d = id >> 3, nb = id & 7, bbase = nb*16;
  int w = threadIdx.x >> 6, l = threadIdx.x & 63, lg = l >> 4, lm = l & 15;
  float* emis = d ? emis_b : emis_f;
  bool ewave = (w == 0) || (w == 2);   // emission on SIMD0 and SIMD2
  int nt = w >> 1;

  // stage emission weights (8 KB, once)
  ((u32x4*)we_lds)[threadIdx.x] = ((const u32x4*)we_p)[d*512 + threadIdx.x];

  // whole W_hh slice in registers: 64 frags x (8 fp8) = 128 VGPRs
  long wreg[64];
  const char* wbase = (const char*)whh_p + ((long)(d*8 + w) << 15);
  #pragma unroll
  for (int i = 0; i < 64; ++i)
    wreg[i] = *(const long*)(wbase + (i << 9) + (l << 3));

  float c[8];
  if (k == 0) {
    for (int i = threadIdx.x; i < 1024; i += 512) ((unsigned*)h_lds)[i] = 0u;
    #pragma unroll
    for (int i = 0; i < 8; ++i) c[i] = 0.f;
  } else {
    u32x4* hl = (u32x4*)h_lds;
    const u32x4* hs = (const u32x4*)(hsave + (long)id*4096);
    if (threadIdx.x < 256) hl[threadIdx.x] = hs[threadIdx.x];
    const float* cs = csave + ((long)id*512 + threadIdx.x)*8;
    #pragma unroll
    for (int i = 0; i < 8; ++i) c[i] = cs[i];
  }
  __syncthreads();

  int prev_t = (k == 0) ? -1 : (d ? (T_LEN - k*CHUNK) : (k*CHUNK - 1));

  for (int u = 0; u < CHUNK; ++u) {
    int ss = k*CHUNK + u;
    int t = d ? (T_LEN-1-ss) : ss;

    // xg loads issued early; compiler-tracked
    const char* xb = (const char*)xg_rd
        + (((((long)d*CHUNK + u)*8 + nb)*4 + (w>>1))*64 + l)*128 + ((w&1)*16);
    u32x4 xv[4];
    #pragma unroll
    for (int i = 0; i < 4; ++i)
      xv[i] = *(const u32x4*)(xb + i*32);

    asm volatile("s_waitcnt lgkmcnt(0)" ::: "memory");
    __builtin_amdgcn_s_barrier();               // B1: prev h writes visible
    long a[8];
    #pragma unroll
    for (int kt = 0; kt < 8; ++kt) {
      int off = (lm*256 + kt*32 + lg*8) ^ ((lm&7)<<3);
      a[kt] = *(const long*)(h_lds + off);
    }
    asm volatile("s_waitcnt lgkmcnt(0)" ::: "memory");
    __builtin_amdgcn_s_barrier();               // B2: h_lds free for writes

    // emissions MFMA for previous h (waves 0,2 -> SIMD0,SIMD2)
    f32x4 ea = {0.f,0.f,0.f,0.f};
    if (ewave && prev_t >= 0) {
      #pragma unroll
      for (int kt = 0; kt < 8; ++kt) {
        long ew = *(const long*)(we_lds + ((nt*8 + kt) << 9) + (l << 3));
        ea = __builtin_amdgcn_mfma_f32_16x16x32_fp8_fp8(a[kt], ew, ea, 0,0,0);
      }
    }

    // main matvec: all weights in registers
    f32x4 acc[8];
    #pragma unroll
    for (int s = 0; s < 8; ++s) acc[s] = (f32x4){0.f,0.f,0.f,0.f};
    #pragma unroll
    for (int kt = 0; kt < 8; ++kt)
      #pragma unroll
      for (int s = 0; s < 8; ++s)
        acc[s] = __builtin_amdgcn_mfma_f32_16x16x32_fp8_fp8(a[kt], wreg[kt*8+s], acc[s], 0,0,0);

    // emissions store
    if (ewave && prev_t >= 0) {
      int cc = nt*16 + lm;
      if (cc < NCLS) {
        #pragma unroll
        for (int r = 0; r < 4; ++r)
          emis[((long)prev_t*BATCH + bbase + lg*4 + r)*NCLS + cc] = ea[r]*INV1024;
      }
    }

    // xg add; gates emerge in log2 domain (xg pre-scaled by log2e)
    #pragma unroll
    for (int s = 0; s < 8; ++s)
      #pragma unroll
      for (int r = 0; r < 4; ++r) {
        unsigned wd = xv[s>>1][(s&1)*2 + (r>>1)];
        unsigned short us = (r&1) ? (unsigned short)(wd>>16) : (unsigned short)(wd & 0xffff);
        acc[s][r] = acc[s][r]*INV1024_LOG2E + bf2f(us);
      }

    // nonlinearities (log2-domain, hw rcp/exp2): i,f,g,o at s = q,2+q,4+q,6+q
    #pragma unroll
    for (int q = 0; q < 2; ++q)
      #pragma unroll
      for (int r = 0; r < 4; ++r) {
        float si = sig2(acc[q][r]);
        float sf = sig2(acc[2+q][r]);
        float tg = tanh2(acc[4+q][r]);
        float so = sig2(acc[6+q][r]);
        float cn = sf*c[q*4+r] + si*tg;
        c[q*4+r] = cn;
        float tc = 2.f*__builtin_amdgcn_rcpf(1.f + __builtin_amdgcn_exp2f(cn*NEG2LOG2E)) - 1.f;
        int m = lg*4 + r;
        int jj = w*32 + q*16 + lm;
        int off = (m*256 + jj) ^ ((m&7)<<3);
        *(unsigned char*)(h_lds + off) = f2fp8((so*16.f)*tc);
      }
    prev_t = t;
  }

  asm volatile("s_waitcnt lgkmcnt(0)" ::: "memory");
  __builtin_amdgcn_s_barrier();

  if (k == NCHUNK-1) {
    if (ewave) {
      long a[8];
      #pragma unroll
      for (int kt = 0; kt < 8; ++kt) {
        int off = (lm*256 + kt*32 + lg*8) ^ ((lm&7)<<3);
        a[kt] = *(const long*)(h_lds + off);
      }
      f32x4 ea = {0.f,0.f,0.f,0.f};
      #pragma unroll
      for (int kt = 0; kt < 8; ++kt) {
        long ew = *(const long*)(we_lds + ((nt*8 + kt) << 9) + (l << 3));
        ea = __builtin_amdgcn_mfma_f32_16x16x32_fp8_fp8(a[kt], ew, ea, 0,0,0);
      }
      int cc = nt*16 + lm;
      if (cc < NCLS) {
        #pragma unroll
        for (int r = 0; r < 4; ++r)
          emis[((long)prev_t*BATCH + bbase + lg*4 + r)*NCLS + cc] = ea[r]*INV1024;
      }
    }
  } else {
    u32x4* hl = (u32x4*)h_lds;
    u32x4* hs = (u32x4*)(hsave + (long)id*4096);
    if (threadIdx.x < 256) hs[threadIdx.x] = hl[threadIdx.x];
    float* cs = csave + ((long)id*512 + threadIdx.x)*8;
    #pragma unroll
    for (int i = 0; i < 8; ++i) cs[i] = c[i];
  }
}

// ---------------- emissions fuse: emis_c = emis_f + emis_b + b_e ------------
__global__ __launch_bounds__(256) void efuse_kernel(const float* emis_f,
    const float* emis_b, const float* b_e, float* emis_c)
{
  int i = blockIdx.x*256 + threadIdx.x;
  if (i < T_LEN*BATCH*NCLS)
    emis_c[i] = emis_f[i] + emis_b[i] + b_e[i % NCLS];
}

// ---------------- CRF numerator -------------------------------------------
__global__ void num_kernel(const int* sent, const int* tags, const float* emis_c,
    const float* start_t, const float* end_t, const float* trans, float* num_buf)
{
  int b = blockIdx.x, l = threadIdx.x;   // 64 threads = 1 wave
  float acc = 0.f; int cnt = 0;
  for (int t = l; t < T_LEN; t += 64) {
    int tag = tags[t*BATCH + b];
    float E = emis_c[((long)t*BATCH+b)*NCLS + tag];
    int m = (sent[t*BATCH+b] != PADTOK) ? 1 : 0;
    cnt += m;
    if (t == 0) acc += start_t[tag] + E;
    else if (m) acc += trans[tags[(t-1)*BATCH + b]*NCLS + tag] + E;
  }
  #pragma unroll
  for (int off = 32; off; off >>= 1) { acc += __shfl_xor(acc, off); cnt += __shfl_xor(cnt, off); }
  if (l == 0) num_buf[b] = acc + end_t[tags[(cnt-1)*BATCH + b]];
}

// ---- CRF forward (denominator): readfirstlane ref + readlane/SGPR bcast ---
// nxt_j = sref + log2( sum_i exp2(S_i - sref) * E_ij ); sref = lane0's S.
// fp32 exp2 range (±127) >> cross-class score spread (~±30) -> no max needed.
__global__ __launch_bounds__(64) void denom_kernel(const int* sent, const float* emis_c,
    const float* start_t, const float* end_t, const float* trans,
    const float* num_buf, float* llh)
{
  const float INVLN2 = 1.4426950408889634f;
  const float LN2 = 0.6931471805599453f;
  int l = threadIdx.x;
  bool valid = l < NCLS;
  int j = valid ? l : 0;
  int b = blockIdx.x;                     // 128 blocks, 1 row per wave

  float etr[NCLS];                        // E column j, linear domain
  #pragma unroll
  for (int i = 0; i < NCLS; ++i)
    etr[i] = __builtin_amdgcn_exp2f(trans[i*NCLS + j] * INVLN2);

  float S = (start_t[j] + emis_c[(long)b*NCLS + j]) * INVLN2;

  float e1 = emis_c[((long)1*BATCH + b)*NCLS + j];
  float e2 = emis_c[((long)2*BATCH + b)*NCLS + j];
  int m1 = sent[1*BATCH + b], m2 = sent[2*BATCH + b];

  for (int t = 1; t < T_LEN; ++t) {
    float e0 = e1; int m0 = m1;
    e1 = e2; m1 = m2;
    if (t + 2 < T_LEN) {
      e2 = emis_c[((long)(t+2)*BATCH + b)*NCLS + j];
      m2 = sent[(t+2)*BATCH + b];
    }
    float sref = __builtin_bit_cast(float,
        __builtin_amdgcn_readfirstlane(__builtin_bit_cast(int, S)));
    float qv = __builtin_amdgcn_exp2f(S - sref);
    // broadcast q_i via readlane -> SGPR; FMA takes the SGPR operand
    float accs[5] = {0.f, 0.f, 0.f, 0.f, 0.f};
    #pragma unroll
    for (int i = 0; i < NCLS; ++i) {
      float qi = __builtin_bit_cast(float,
          __builtin_amdgcn_readlane(__builtin_bit_cast(int, qv), i));
      accs[i % 5] = fmaf(qi, etr[i], accs[i % 5]);
    }
    float dot = ((accs[0] + accs[1]) + (accs[2] + accs[3])) + accs[4];
    float nxt = sref + __builtin_amdgcn_logf(dot) + e0 * INVLN2;
    if (m0 != PADTOK) S = nxt;
  }

  float vf = valid ? (S + end_t[j] * INVLN2) : -1e30f;
  float mx = vf;
  #pragma unroll
  for (int off = 32; off; off >>= 1) mx = fmaxf(mx, __shfl_xor(mx, off));
  float ss = valid ? __builtin_amdgcn_exp2f(vf - mx) : 0.f;
  #pragma unroll
  for (int off = 32; off; off >>= 1) ss += __shfl_xor(ss, off);
  if (l == 0) llh[b] = num_buf[b] - (mx + __builtin_amdgcn_logf(ss)) * LN2;
}

__global__ void final_kernel(const float* llh, float* out) {
  __shared__ float red[2];
  int l = threadIdx.x;   // 128
  float v = llh[l];
  #pragma unroll
  for (int off = 32; off; off >>= 1) v += __shfl_xor(v, off);
  if ((l & 63) == 0) red[l >> 6] = v;
  __syncthreads();
  if (l == 0) out[0] = -(red[0] + red[1]);
}

extern "C" void kernel_launch(void* const* d_in, const int* in_sizes, int n_in,
                              void* d_out, int out_size, void* d_ws, size_t ws_size,
                              hipStream_t stream) {
  const int*   sent  = (const int*)d_in[0];
  const int*   tags  = (const int*)d_in[1];
  const float* emb   = (const float*)d_in[2];
  const float* wih_f = (const float*)d_in[3];
  const float* whh_f = (const float*)d_in[4];
  const float* bih_f = (const float*)d_in[5];
  const float* bhh_f = (const float*)d_in[6];
  const float* wih_b = (const float*)d_in[7];
  const float* whh_b = (const float*)d_in[8];
  const float* bih_b = (const float*)d_in[9];
  const float* bhh_b = (const float*)d_in[10];
  const float* W_e   = (const float*)d_in[11];
  const float* b_e   = (const float*)d_in[12];
  const float* st    = (const float*)d_in[13];
  const float* et    = (const float*)d_in[14];
  const float* tr    = (const float*)d_in[15];
  (void)in_sizes; (void)n_in; (void)out_size;

  const long SLOT = (long)2*CHUNK*BATCH*1024*2;   // 32 MiB per xg slot

  char* ws = (char*)d_ws;
  unsigned short* wih_p  = (unsigned short*)ws; ws += (long)N_WPERM*2;      // 1 MiB
  unsigned char*  whh_p  = (unsigned char*)ws;  ws += (long)N_WPERM;        // 512 KiB
  unsigned char*  we_p   = (unsigned char*)ws;  ws += (long)N_WE;           // 16 KiB
  float*          bias   = (float*)ws;          ws += (long)N_BIAS*4;       // 8 KiB
  unsigned short* xgr0   = (unsigned short*)ws; ws += SLOT;                 // 32 MiB
  float*          emis_f = (float*)ws;          ws += (long)T_LEN*BATCH*NCLS*4;
  float*          emis_b = (float*)ws;          ws += (long)T_LEN*BATCH*NCLS*4;
  unsigned char*  hsave  = (unsigned char*)ws;  ws += (long)16*4096;
  float*          csave  = (float*)ws;          ws += (long)16*512*8*4;
  float*          numb   = (float*)ws;          ws += 512;
  float*          llh    = (float*)ws;          ws += 512;
  unsigned short* xgr1   = (unsigned short*)ws; ws += SLOT;                 // 32 MiB (pipelined only)
  float*          emis_c = (float*)xgr0;        // alias: slots dead after last lstm

  bool pipelined = ws_size >= (size_t)((char*)ws - (char*)d_ws);

  prep_kernel<<<4168, 256, 0, stream>>>(wih_f, whh_f, bih_f, bhh_f,
                                        wih_b, whh_b, bih_b, bhh_b, W_e,
                                        wih_p, whh_p, we_p, bias);
  if (pipelined) {
    dim3 g1(256, 2);
    xg_kernel<<<g1, 256, 0, stream>>>(sent, emb, wih_p, bias, xgr0, 0);
    for (int k = 0; k < NCHUNK; ++k) {
      unsigned short* rd = (k & 1) ? xgr1 : xgr0;
      unsigned short* wr = (k & 1) ? xgr0 : xgr1;
      int grid = (k + 1 < NCHUNK) ? 528 : 16;
      fused_kernel<<<grid, 512, 0, stream>>>(sent, emb, wih_p, bias, rd, wr,
                                             whh_p, we_p, emis_f, emis_b, hsave, csave, k);
    }
  } else {
    for (int k = 0; k < NCHUNK; ++k) {
      dim3 g1(256, 2);
      xg_kernel<<<g1, 256, 0, stream>>>(sent, emb, wih_p, bias, xgr0, k);
      fused_kernel<<<16, 512, 0, stream>>>(sent, emb, wih_p, bias, xgr0, xgr0,
                                           whh_p, we_p, emis_f, emis_b, hsave, csave, k);
    }
  }
  efuse_kernel<<<(T_LEN*BATCH*NCLS + 255)/256, 256, 0, stream>>>(emis_f, emis_b, b_e, emis_c);
  num_kernel<<<128, 64, 0, stream>>>(sent, tags, emis_c, st, et, tr, numb);
  denom_kernel<<<128, 64, 0, stream>>>(sent, emis_c, st, et, tr, numb, llh);
  final_kernel<<<1, 128, 0, stream>>>(llh, (float*)d_out);
}